// Round 11
// baseline (279.794 us; speedup 1.0000x reference)
//
#include <hip/hip_runtime.h>

#define NN 50000
#define EE 800000
#define FF 128
#define HH 256
#define CC 40
#define BN_EPS 1e-5f

typedef float f4 __attribute__((ext_vector_type(4)));
typedef _Float16 h8 __attribute__((ext_vector_type(8)));
typedef _Float16 h4 __attribute__((ext_vector_type(4)));

#define OFF_NODE 0            // 4*16 units  (holds Wcomb = Wn@(I+Wc2), K=128)
#define OFF_C1   32768        // 8*16 units  (I+Wc1, K=256)
#define OFF_C2   98304        // 8*16 units  (unused by GEMMs now, kept for layout)
#define OFF_F1   163840       // 8*16 units  (W_f1, K=256)
#define PW_HALVES 229376

#define SWZ(row, c2) ((c2) ^ (((row) & 7) << 4))

// ---------------- prep2: W_edge->fp16 + histogram (blocks<2048) ; weight pack (blocks>=2048) ----------------
__global__ __launch_bounds__(256)
void k_prep2(const float* __restrict__ W, _Float16* __restrict__ W16,
             const int* __restrict__ ei, int* __restrict__ deg,
             const float* __restrict__ W_node, const float* __restrict__ W_c1,
             const float* __restrict__ W_c2, const float* __restrict__ W_f1,
             const float* __restrict__ b_node, const float* __restrict__ b_c1,
             const float* __restrict__ b_c2, _Float16* __restrict__ pW,
             float* __restrict__ bB) {
    const int tid = threadIdx.x;
    if (blockIdx.x < 2048) {
        const int gsz = 2048 * 256;
        const int i0 = blockIdx.x * 256 + tid;
        for (int j = i0; j < NN * HH / 8; j += gsz) {
            f4 v0 = ((const f4*)W)[j * 2];
            f4 v1 = ((const f4*)W)[j * 2 + 1];
            h8 h;
            h[0] = (_Float16)v0[0]; h[1] = (_Float16)v0[1];
            h[2] = (_Float16)v0[2]; h[3] = (_Float16)v0[3];
            h[4] = (_Float16)v1[0]; h[5] = (_Float16)v1[1];
            h[6] = (_Float16)v1[2]; h[7] = (_Float16)v1[3];
            ((h8*)W16)[j] = h;
        }
        for (int e = i0; e < EE; e += gsz) atomicAdd(&deg[ei[EE + e]], 1);
        return;
    }
    const int pb = blockIdx.x - 2048;
    if (pb == 112) {  // combined phase-B bias: b_c1+b_c2+b_node@(I+W_c2)
        int c = tid;
        if (c < HH) {
            float a = 0.f;
            for (int k = 0; k < HH; ++k) a += b_node[k] * W_c2[k * HH + c];
            bB[c] = a + b_node[c] + b_c1[c] + b_c2[c];
        }
        return;
    }
    const int unit = pb * 4 + (tid >> 6);
    const int lane = tid & 63, lm = lane & 15, lg = lane >> 4;
    int u = unit;
    if (u < 64) {
        // Wcomb fragment: Wcomb[kr][col] = Wn[kr][col] + sum_k Wn[kr][k]*Wc2[k][col]
        const int kb = u >> 4, nb = u & 15;
        h8 hv;
#pragma unroll
        for (int j = 0; j < 8; ++j) {
            int kr = kb * 32 + lg * 8 + j;     // 0..127
            int col = nb * 16 + lm;
            float a = W_node[kr * HH + col];
            for (int k = 0; k < HH; ++k)
                a += W_node[kr * HH + k] * W_c2[k * HH + col];
            hv[j] = (_Float16)a;
        }
        *(h8*)(pW + (size_t)unit * 512 + lane * 8) = hv;
        return;
    }
    const float* Ws;
    bool addI;
    if (u < 192)      { Ws = W_c1; addI = true;  u -= 64; }
    else if (u < 320) { Ws = W_c2; addI = true;  u -= 192; }
    else              { Ws = W_f1; addI = false; u -= 320; }
    const int kb = u >> 4, nb = u & 15;
    h8 hv;
#pragma unroll
    for (int j = 0; j < 8; ++j) {
        int kr = kb * 32 + lg * 8 + j;
        int col = nb * 16 + lm;
        float v = Ws[kr * HH + col];
        if (addI && kr == col) v += 1.f;
        hv[j] = (_Float16)v;
    }
    *(h8*)(pW + (size_t)unit * 512 + lane * 8) = hv;
}

// ---------------- two-level scan ----------------
__global__ __launch_bounds__(256)
void k_scan1(const int* __restrict__ deg, int* __restrict__ rowptr, int* __restrict__ bsums) {
    __shared__ int t[256];
    const int tid = threadIdx.x;
    int i = blockIdx.x * 256 + tid;
    int v = (i < NN) ? deg[i] : 0;
    t[tid] = v;
    __syncthreads();
#pragma unroll
    for (int off = 1; off < 256; off <<= 1) {
        int u = (tid >= off) ? t[tid - off] : 0;
        __syncthreads();
        t[tid] += u;
        __syncthreads();
    }
    if (i < NN) rowptr[i] = t[tid] - v;
    if (tid == 255) bsums[blockIdx.x] = t[tid];
}
__global__ __launch_bounds__(256)
void k_scan2(int* __restrict__ bsums) {
    __shared__ int t[256];
    const int tid = threadIdx.x;
    int v = (tid < 196) ? bsums[tid] : 0;
    t[tid] = v;
    __syncthreads();
#pragma unroll
    for (int off = 1; off < 256; off <<= 1) {
        int u = (tid >= off) ? t[tid - off] : 0;
        __syncthreads();
        t[tid] += u;
        __syncthreads();
    }
    if (tid < 196) bsums[tid] = t[tid] - v;
}
__global__ __launch_bounds__(256)
void k_scan3(int* __restrict__ rowptr, const int* __restrict__ bsums, int* __restrict__ pos) {
    int i = blockIdx.x * 256 + threadIdx.x;
    if (i < NN) {
        int r = rowptr[i] + bsums[blockIdx.x];
        rowptr[i] = r;
        pos[i] = r;
    }
    if (i == 0) rowptr[NN] = EE;
}

// ---------------- bin-scatter: packed (src:16 | fp16(w):16) 4B into CSR order ----------------
__global__ void k_ssort(const int* __restrict__ ei, const float* __restrict__ ew,
                        int* __restrict__ pos, unsigned int* __restrict__ esw) {
    int e = blockIdx.x * blockDim.x + threadIdx.x;
    if (e < EE) {
        int d = ei[EE + e];
        int p = atomicAdd(&pos[d], 1);
        _Float16 hw = (_Float16)ew[e];
        unsigned short hwb = *(unsigned short*)&hw;
        esw[p] = (unsigned int)ei[e] | ((unsigned int)hwb << 16);
    }
}

// ---------------- gather-accumulate: one wave per node, unroll 8 ----------------
__global__ __launch_bounds__(256)
void k_gather(const int* __restrict__ rowptr, const unsigned int* __restrict__ esw,
              const _Float16* __restrict__ W16, const float* __restrict__ b_edge,
              _Float16* __restrict__ outHA) {
    const int wave = threadIdx.x >> 6;
    const int lane = threadIdx.x & 63;
    const int node = blockIdx.x * 4 + wave;
    if (node >= NN) return;
    int e = rowptr[node];
    const int end = rowptr[node + 1];
    const int c0 = lane * 4;
    f4 acc0 = {0.f, 0.f, 0.f, 0.f}, acc1 = {0.f, 0.f, 0.f, 0.f};
    for (; e + 7 < end; e += 8) {
        unsigned int v[8];
        h4 r[8];
#pragma unroll
        for (int j = 0; j < 8; ++j) v[j] = esw[e + j];
#pragma unroll
        for (int j = 0; j < 8; ++j)
            r[j] = *(const h4*)(W16 + (size_t)(v[j] & 0xFFFF) * HH + c0);
#pragma unroll
        for (int j = 0; j < 8; j += 2) {
            unsigned short b0 = (unsigned short)(v[j] >> 16);
            unsigned short b1 = (unsigned short)(v[j + 1] >> 16);
            float w0 = (float)*(_Float16*)&b0;
            float w1 = (float)*(_Float16*)&b1;
            f4 f0 = {(float)r[j][0], (float)r[j][1], (float)r[j][2], (float)r[j][3]};
            f4 f1 = {(float)r[j + 1][0], (float)r[j + 1][1], (float)r[j + 1][2], (float)r[j + 1][3]};
            acc0 += w0 * f0;
            acc1 += w1 * f1;
        }
    }
    for (; e < end; ++e) {
        unsigned int v = esw[e];
        unsigned short bb = (unsigned short)(v >> 16);
        h4 rr = *(const h4*)(W16 + (size_t)(v & 0xFFFF) * HH + c0);
        f4 ff = {(float)rr[0], (float)rr[1], (float)rr[2], (float)rr[3]};
        acc0 += (float)*(_Float16*)&bb * ff;
    }
    f4 b = *(const f4*)(b_edge + c0);
    f4 acc = acc0 + acc1 + b;
    h4 hv;
    hv[0] = (_Float16)acc[0]; hv[1] = (_Float16)acc[1];
    hv[2] = (_Float16)acc[2]; hv[3] = (_Float16)acc[3];
    *(h4*)(outHA + (size_t)node * HH + c0) = hv;
}

// ---------------- fused B+C: h = relu( relu(h_a@(I+Wc1) + x@Wcomb + bB) @ W_f1 + b_f1 ) + BN stats ----------------
// 512 thr (8 waves). Wave w owns output cols [w*32, w*32+32) of both stages.
// LDS: sX [32][256B] @0 ; sA1 [32][512B] @8192 ; sOutB [32][512B] @24576. Total 40KB.
__global__ __launch_bounds__(512)
void k_gemmBC(const float* __restrict__ x, const _Float16* __restrict__ A1,
              const _Float16* __restrict__ pW, const float* __restrict__ bB,
              const float* __restrict__ b_f1, _Float16* __restrict__ H,
              float* __restrict__ stats) {
    __shared__ __align__(16) char sm[40960];
    const int tid = threadIdx.x;
    const int w = tid >> 6, l = tid & 63;
    const int lm = l & 15, lg = l >> 4;
    const int rx = tid >> 4, sx = tid & 15;

    h8 w1[8][2], wc[4][2], wf[8][2];
#pragma unroll
    for (int kb = 0; kb < 8; ++kb)
#pragma unroll
        for (int n = 0; n < 2; ++n) {
            w1[kb][n] = *(const h8*)(pW + OFF_C1 + (size_t)(kb * 16 + w * 2 + n) * 512 + l * 8);
            wf[kb][n] = *(const h8*)(pW + OFF_F1 + (size_t)(kb * 16 + w * 2 + n) * 512 + l * 8);
        }
#pragma unroll
    for (int kb = 0; kb < 4; ++kb)
#pragma unroll
        for (int n = 0; n < 2; ++n)
            wc[kb][n] = *(const h8*)(pW + OFF_NODE + (size_t)(kb * 16 + w * 2 + n) * 512 + l * 8);

    float bBreg[2], bFreg[2];
#pragma unroll
    for (int n = 0; n < 2; ++n) {
        bBreg[n] = bB[w * 32 + n * 16 + lm];
        bFreg[n] = b_f1[w * 32 + n * 16 + lm];
    }
    float sS[2] = {0.f, 0.f}, sQ[2] = {0.f, 0.f};

    const int NT = (NN + 31) / 32;
    f4 pXa, pXb;
    int4 p1[2];
    int t = blockIdx.x;
    {
        int grow = t * 32 + rx;
        const f4 zf = {0.f, 0.f, 0.f, 0.f};
        pXa = (grow < NN) ? *(const f4*)(x + (size_t)grow * FF + sx * 8) : zf;
        pXb = (grow < NN) ? *(const f4*)(x + (size_t)grow * FF + sx * 8 + 4) : zf;
#pragma unroll
        for (int j = 0; j < 2; ++j) {
            int unit = tid * 2 + j;
            int r = unit >> 5, s = unit & 31;
            int g2 = t * 32 + r;
            int4 z = {0, 0, 0, 0};
            p1[j] = (g2 < NN) ? *(const int4*)(A1 + (size_t)g2 * HH + s * 8) : z;
        }
    }

    for (; t < NT; t += gridDim.x) {
        __syncthreads();  // b0: all waves done with previous tile's LDS (incl. sOutB reads)
        {
            h8 hx;
            hx[0] = (_Float16)pXa[0]; hx[1] = (_Float16)pXa[1];
            hx[2] = (_Float16)pXa[2]; hx[3] = (_Float16)pXa[3];
            hx[4] = (_Float16)pXb[0]; hx[5] = (_Float16)pXb[1];
            hx[6] = (_Float16)pXb[2]; hx[7] = (_Float16)pXb[3];
            *(int4*)(sm + rx * 256 + SWZ(rx, sx * 16)) = *(int4*)&hx;
        }
#pragma unroll
        for (int j = 0; j < 2; ++j) {
            int unit = tid * 2 + j;
            int r = unit >> 5, s = unit & 31;
            *(int4*)(sm + 8192 + r * 512 + SWZ(r, s * 16)) = p1[j];
        }
        int tn = t + gridDim.x;
        if (tn < NT) {
            int grow = tn * 32 + rx;
            const f4 zf = {0.f, 0.f, 0.f, 0.f};
            pXa = (grow < NN) ? *(const f4*)(x + (size_t)grow * FF + sx * 8) : zf;
            pXb = (grow < NN) ? *(const f4*)(x + (size_t)grow * FF + sx * 8 + 4) : zf;
#pragma unroll
            for (int j = 0; j < 2; ++j) {
                int unit = tid * 2 + j;
                int r = unit >> 5, s = unit & 31;
                int g2 = tn * 32 + r;
                int4 z = {0, 0, 0, 0};
                p1[j] = (g2 < NN) ? *(const int4*)(A1 + (size_t)g2 * HH + s * 8) : z;
            }
        }
        __syncthreads();  // b1: sX, sA1 ready

        // ---- stage B: outB = relu(h_a@(I+Wc1) + x@Wcomb + bB)
        f4 acc[2][2];
        const f4 z4 = {0.f, 0.f, 0.f, 0.f};
#pragma unroll
        for (int rf = 0; rf < 2; ++rf)
#pragma unroll
            for (int n = 0; n < 2; ++n) acc[rf][n] = z4;

#pragma unroll
        for (int kb = 0; kb < 8; ++kb) {
            h8 a0 = *(const h8*)(sm + 8192 + lm * 512 + SWZ(lm, kb * 64 + lg * 16));
            h8 a1 = *(const h8*)(sm + 8192 + (16 + lm) * 512 + SWZ(16 + lm, kb * 64 + lg * 16));
#pragma unroll
            for (int n = 0; n < 2; ++n) {
                acc[0][n] = __builtin_amdgcn_mfma_f32_16x16x32_f16(a0, w1[kb][n], acc[0][n], 0, 0, 0);
                acc[1][n] = __builtin_amdgcn_mfma_f32_16x16x32_f16(a1, w1[kb][n], acc[1][n], 0, 0, 0);
            }
        }
#pragma unroll
        for (int kb = 0; kb < 4; ++kb) {
            h8 a0 = *(const h8*)(sm + lm * 256 + SWZ(lm, kb * 64 + lg * 16));
            h8 a1 = *(const h8*)(sm + (16 + lm) * 256 + SWZ(16 + lm, kb * 64 + lg * 16));
#pragma unroll
            for (int n = 0; n < 2; ++n) {
                acc[0][n] = __builtin_amdgcn_mfma_f32_16x16x32_f16(a0, wc[kb][n], acc[0][n], 0, 0, 0);
                acc[1][n] = __builtin_amdgcn_mfma_f32_16x16x32_f16(a1, wc[kb][n], acc[1][n], 0, 0, 0);
            }
        }
        // epilogue B -> sOutB (fp16), wave's 32-col stripe
#pragma unroll
        for (int rf = 0; rf < 2; ++rf)
#pragma unroll
            for (int n = 0; n < 2; ++n) {
                int c2 = (w * 32 + n * 16 + lm) * 2;
#pragma unroll
                for (int q = 0; q < 4; ++q) {
                    int r = rf * 16 + lg * 4 + q;
                    float v = fmaxf(acc[rf][n][q] + bBreg[n], 0.f);
                    *(_Float16*)(sm + 24576 + r * 512 + SWZ(r, c2)) = (_Float16)v;
                }
            }
        __syncthreads();  // b2: sOutB ready

        // ---- stage C: h = relu(outB @ W_f1 + b_f1), BN stats
#pragma unroll
        for (int rf = 0; rf < 2; ++rf)
#pragma unroll
            for (int n = 0; n < 2; ++n) acc[rf][n] = z4;

#pragma unroll
        for (int kb = 0; kb < 8; ++kb) {
            h8 a0 = *(const h8*)(sm + 24576 + lm * 512 + SWZ(lm, kb * 64 + lg * 16));
            h8 a1 = *(const h8*)(sm + 24576 + (16 + lm) * 512 + SWZ(16 + lm, kb * 64 + lg * 16));
#pragma unroll
            for (int n = 0; n < 2; ++n) {
                acc[0][n] = __builtin_amdgcn_mfma_f32_16x16x32_f16(a0, wf[kb][n], acc[0][n], 0, 0, 0);
                acc[1][n] = __builtin_amdgcn_mfma_f32_16x16x32_f16(a1, wf[kb][n], acc[1][n], 0, 0, 0);
            }
        }

        const int row0 = t * 32;
#pragma unroll
        for (int rf = 0; rf < 2; ++rf)
#pragma unroll
            for (int n = 0; n < 2; ++n) {
                const int col = w * 32 + n * 16 + lm;
#pragma unroll
                for (int q = 0; q < 4; ++q) {
                    int grow = row0 + rf * 16 + lg * 4 + q;
                    if (grow < NN) {
                        float v = fmaxf(acc[rf][n][q] + bFreg[n], 0.f);
                        sS[n] += v;
                        sQ[n] += v * v;
                        H[(size_t)grow * HH + col] = (_Float16)v;
                    }
                }
            }
    }

#pragma unroll
    for (int n = 0; n < 2; ++n) {
        float s = sS[n];
        s += __shfl_xor(s, 16); s += __shfl_xor(s, 32);
        float q = sQ[n];
        q += __shfl_xor(q, 16); q += __shfl_xor(q, 32);
        if (lg == 0) {
            atomicAdd(&stats[w * 32 + n * 16 + lm], s);
            atomicAdd(&stats[HH + w * 32 + n * 16 + lm], q);
        }
    }
}

// ---------------- BN fold + pack final weights into MFMA-B fragments ----------------
__global__ __launch_bounds__(256)
void k_bnprep(const float* __restrict__ stats, const float* __restrict__ gamma,
              const float* __restrict__ beta, const float* __restrict__ W_f2,
              const float* __restrict__ b_f2, _Float16* __restrict__ pWf,
              float* __restrict__ bfold) {
    __shared__ float sh[HH];
    __shared__ float ssc[HH];
    const int tid = threadIdx.x;
    const float invN = 1.0f / (float)NN;
    {
        float mu = stats[tid] * invN;
        float var = stats[HH + tid] * invN - mu * mu;
        float scale = gamma[tid] * rsqrtf(var + BN_EPS);
        sh[tid] = beta[tid] - mu * scale;
        ssc[tid] = scale;
    }
    __syncthreads();
    if (tid < CC) {
        float b = b_f2[tid];
        for (int k = 0; k < HH; ++k) b += sh[k] * W_f2[k * CC + tid];
        bfold[tid] = b;
    }
    const int w = tid >> 6, l = tid & 63;
    const int lm = l & 15, lg = l >> 4;
#pragma unroll
    for (int i = 0; i < 6; ++i) {
        int u = w + i * 4;  // 0..23
        int kb = u / 3, nb = u % 3;
        h8 hv;
#pragma unroll
        for (int j = 0; j < 8; ++j) {
            int k = kb * 32 + lg * 8 + j;
            int c = nb * 16 + lm;
            float v = (c < CC) ? ssc[k] * W_f2[k * CC + c] : 0.f;
            hv[j] = (_Float16)v;
        }
        *(h8*)(pWf + (size_t)u * 512 + l * 8) = hv;
    }
}

// ---------------- final via MFMA: out = h @ (scale*W_f2) + bfold ----------------
__global__ __launch_bounds__(256)
void k_finalM(const _Float16* __restrict__ h, const _Float16* __restrict__ pWf,
              const float* __restrict__ bfold, float* __restrict__ out) {
    __shared__ __align__(16) char sA[64 * 512];
    const int tid = threadIdx.x;
    const int w = tid >> 6, l = tid & 63;
    const int lm = l & 15, lg = l >> 4;

    h8 wreg[8][3];
#pragma unroll
    for (int kb = 0; kb < 8; ++kb)
#pragma unroll
        for (int nb = 0; nb < 3; ++nb)
            wreg[kb][nb] = *(const h8*)(pWf + (size_t)(kb * 3 + nb) * 512 + l * 8);

    const int row0 = blockIdx.x * 64;
#pragma unroll
    for (int j = 0; j < 8; ++j) {
        int unit = tid * 8 + j;
        int r = unit >> 5, s = unit & 31;
        int grow = row0 + r;
        int4 z = {0, 0, 0, 0};
        int4 v = (grow < NN) ? *(const int4*)(h + (size_t)grow * HH + s * 8) : z;
        *(int4*)(sA + r * 512 + SWZ(r, s * 16)) = v;
    }
    __syncthreads();

    f4 acc[3];
    const f4 z4 = {0.f, 0.f, 0.f, 0.f};
#pragma unroll
    for (int nb = 0; nb < 3; ++nb) acc[nb] = z4;

    const int ar = w * 16 + lm;
#pragma unroll
    for (int kb = 0; kb < 8; ++kb) {
        h8 a = *(const h8*)(sA + ar * 512 + SWZ(ar, kb * 64 + lg * 16));
#pragma unroll
        for (int nb = 0; nb < 3; ++nb)
            acc[nb] = __builtin_amdgcn_mfma_f32_16x16x32_f16(a, wreg[kb][nb], acc[nb], 0, 0, 0);
    }

#pragma unroll
    for (int nb = 0; nb < 3; ++nb) {
        int col = nb * 16 + lm;
        if (col < CC) {
            float bb = bfold[col];
#pragma unroll
            for (int q = 0; q < 4; ++q) {
                int grow = row0 + w * 16 + lg * 4 + q;
                if (grow < NN) out[(size_t)grow * CC + col] = acc[nb][q] + bb;
            }
        }
    }
}

extern "C" void kernel_launch(void* const* d_in, const int* in_sizes, int n_in,
                              void* d_out, int out_size, void* d_ws, size_t ws_size,
                              hipStream_t stream) {
    const float* x      = (const float*)d_in[0];
    const int*   ei     = (const int*)d_in[1];
    const float* ew     = (const float*)d_in[2];
    const float* W_edge = (const float*)d_in[3];
    const float* b_edge = (const float*)d_in[4];
    const float* W_node = (const float*)d_in[5];
    const float* b_node = (const float*)d_in[6];
    const float* W_c1   = (const float*)d_in[7];
    const float* b_c1   = (const float*)d_in[8];
    const float* W_c2   = (const float*)d_in[9];
    const float* b_c2   = (const float*)d_in[10];
    const float* W_f1   = (const float*)d_in[11];
    const float* b_f1   = (const float*)d_in[12];
    const float* gamma  = (const float*)d_in[13];
    const float* beta   = (const float*)d_in[14];
    const float* W_f2   = (const float*)d_in[15];
    const float* b_f2   = (const float*)d_in[16];
    float* out = (float*)d_out;

    const size_t NNH = (size_t)NN * HH;
    _Float16* bufA = (_Float16*)d_ws;            // h_a
    _Float16* bufH = bufA + NNH;                 // h
    _Float16* W16  = bufH + NNH;                 // fp16 W_edge
    unsigned int* esw = (unsigned int*)(W16 + NNH);  // E packed
    float* stats   = (float*)(esw + EE);         // 512
    float* bB      = stats + 2 * HH;             // 256
    float* bfold   = bB + HH;                    // 64
    _Float16* pWf  = (_Float16*)(bfold + 64);    // 24*512
    _Float16* pW   = pWf + 24 * 512;             // PW_HALVES
    int* deg       = (int*)(pW + PW_HALVES);     // N
    int* rowptr    = deg + NN;                   // N+1
    int* pos       = rowptr + NN + 1;            // N
    int* bsums     = pos + NN;                   // 256

    hipMemsetAsync(stats, 0, 2 * HH * sizeof(float), stream);
    hipMemsetAsync(deg, 0, NN * sizeof(int), stream);

    k_prep2<<<2161, 256, 0, stream>>>(W_edge, W16, ei, deg, W_node, W_c1, W_c2, W_f1,
                                      b_node, b_c1, b_c2, pW, bB);
    k_scan1<<<196, 256, 0, stream>>>(deg, rowptr, bsums);
    k_scan2<<<1, 256, 0, stream>>>(bsums);
    k_scan3<<<196, 256, 0, stream>>>(rowptr, bsums, pos);
    k_ssort<<<(EE + 255) / 256, 256, 0, stream>>>(ei, ew, pos, esw);
    k_gather<<<12500, 256, 0, stream>>>(rowptr, esw, W16, b_edge, bufA);

    // fused B+C: h = relu( relu(h_a@(I+Wc1) + x@Wcomb + bB) @ W_f1 + b_f1 ) + stats
    k_gemmBC<<<256, 512, 0, stream>>>(x, bufA, pW, bB, b_f1, bufH, stats);

    k_bnprep<<<1, 256, 0, stream>>>(stats, gamma, beta, W_f2, b_f2, pWf, bfold);
    k_finalM<<<(NN + 63) / 64, 256, 0, stream>>>(bufH, pWf, bfold, out);
}

// Round 12
// 268.382 us; speedup vs baseline: 1.0425x; 1.0425x over previous
//
#include <hip/hip_runtime.h>

#define NN 50000
#define EE 800000
#define FF 128
#define HH 256
#define CC 40
#define BN_EPS 1e-5f

typedef float f4 __attribute__((ext_vector_type(4)));
typedef _Float16 h8 __attribute__((ext_vector_type(8)));
typedef _Float16 h4 __attribute__((ext_vector_type(4)));

// packed units (512 halves each): [0,64) Wcomb (K=128), [64,192) I+Wc1 (K=256), [192,320) W_f1 (K=256)
#define OFF_NODE 0
#define OFF_C1   32768
#define OFF_F1   98304
#define PW_HALVES 163840

#define SWZ(row, c2) ((c2) ^ (((row) & 7) << 4))

// ---------------- Wcomb = Wn + Wn@Wc2  (fp32, coalesced) ----------------
__global__ __launch_bounds__(256)
void k_wcomb(const float* __restrict__ Wn, const float* __restrict__ Wc2,
             float* __restrict__ Wcomb) {
    __shared__ float WnL[16][256];
    const int c = threadIdx.x;
    const int r0 = blockIdx.x * 16;
    for (int i = threadIdx.x; i < 16 * 256; i += 256)
        WnL[i >> 8][i & 255] = Wn[(r0 + (i >> 8)) * HH + (i & 255)];
    __syncthreads();
    float acc[16];
#pragma unroll
    for (int r = 0; r < 16; ++r) acc[r] = WnL[r][c];
    for (int k = 0; k < 256; ++k) {
        float wv = Wc2[k * HH + c];
#pragma unroll
        for (int r = 0; r < 16; ++r) acc[r] += WnL[r][k] * wv;
    }
#pragma unroll
    for (int r = 0; r < 16; ++r) Wcomb[(r0 + r) * HH + c] = acc[r];
}

// ---------------- prep: W_edge -> fp16  +  histogram of dst ----------------
__global__ __launch_bounds__(256)
void k_prep(const float* __restrict__ W, _Float16* __restrict__ W16,
            const int* __restrict__ ei, int* __restrict__ deg) {
    const int gsz = gridDim.x * blockDim.x;
    const int i0 = blockIdx.x * blockDim.x + threadIdx.x;
    for (int j = i0; j < NN * HH / 8; j += gsz) {
        f4 v0 = ((const f4*)W)[j * 2];
        f4 v1 = ((const f4*)W)[j * 2 + 1];
        h8 h;
        h[0] = (_Float16)v0[0]; h[1] = (_Float16)v0[1];
        h[2] = (_Float16)v0[2]; h[3] = (_Float16)v0[3];
        h[4] = (_Float16)v1[0]; h[5] = (_Float16)v1[1];
        h[6] = (_Float16)v1[2]; h[7] = (_Float16)v1[3];
        ((h8*)W16)[j] = h;
    }
    for (int e = i0; e < EE; e += gsz) atomicAdd(&deg[ei[EE + e]], 1);
}

// ---------------- pack weights into MFMA-B fragment layout (fp16) ----------------
// 81 blocks: 80 fragment blocks (320 units) + bias block (blockIdx 80)
__global__ __launch_bounds__(256)
void k_pack(const float* __restrict__ Wcomb, const float* __restrict__ W_c1,
            const float* __restrict__ W_c2, const float* __restrict__ W_f1,
            const float* __restrict__ b_node, const float* __restrict__ b_c1,
            const float* __restrict__ b_c2, _Float16* __restrict__ pW,
            float* __restrict__ bB) {
    const int tid = threadIdx.x;
    if (blockIdx.x == 80) {  // combined phase-B bias: b_c1+b_c2+b_node@(I+W_c2)
        int c = tid;
        if (c < HH) {
            float a = 0.f;
            for (int k = 0; k < HH; ++k) a += b_node[k] * W_c2[k * HH + c];
            bB[c] = a + b_node[c] + b_c1[c] + b_c2[c];
        }
        return;
    }
    const int unit = blockIdx.x * 4 + (tid >> 6);
    const int lane = tid & 63, lm = lane & 15, lg = lane >> 4;
    const float* Ws;
    bool addI;
    int u = unit;
    if (u < 64)       { Ws = Wcomb; addI = false; }
    else if (u < 192) { Ws = W_c1;  addI = true;  u -= 64; }
    else              { Ws = W_f1;  addI = false; u -= 192; }
    const int kb = u >> 4, nb = u & 15;
    h8 hv;
#pragma unroll
    for (int j = 0; j < 8; ++j) {
        int kr = kb * 32 + lg * 8 + j;
        int col = nb * 16 + lm;
        float v = Ws[kr * HH + col];
        if (addI && kr == col) v += 1.f;
        hv[j] = (_Float16)v;
    }
    *(h8*)(pW + (size_t)unit * 512 + lane * 8) = hv;
}

// ---------------- two-level scan ----------------
__global__ __launch_bounds__(256)
void k_scan1(const int* __restrict__ deg, int* __restrict__ rowptr, int* __restrict__ bsums) {
    __shared__ int t[256];
    const int tid = threadIdx.x;
    int i = blockIdx.x * 256 + tid;
    int v = (i < NN) ? deg[i] : 0;
    t[tid] = v;
    __syncthreads();
#pragma unroll
    for (int off = 1; off < 256; off <<= 1) {
        int u = (tid >= off) ? t[tid - off] : 0;
        __syncthreads();
        t[tid] += u;
        __syncthreads();
    }
    if (i < NN) rowptr[i] = t[tid] - v;
    if (tid == 255) bsums[blockIdx.x] = t[tid];
}
__global__ __launch_bounds__(256)
void k_scan2(int* __restrict__ bsums) {
    __shared__ int t[256];
    const int tid = threadIdx.x;
    int v = (tid < 196) ? bsums[tid] : 0;
    t[tid] = v;
    __syncthreads();
#pragma unroll
    for (int off = 1; off < 256; off <<= 1) {
        int u = (tid >= off) ? t[tid - off] : 0;
        __syncthreads();
        t[tid] += u;
        __syncthreads();
    }
    if (tid < 196) bsums[tid] = t[tid] - v;
}
__global__ __launch_bounds__(256)
void k_scan3(int* __restrict__ rowptr, const int* __restrict__ bsums, int* __restrict__ pos) {
    int i = blockIdx.x * 256 + threadIdx.x;
    if (i < NN) {
        int r = rowptr[i] + bsums[blockIdx.x];
        rowptr[i] = r;
        pos[i] = r;
    }
    if (i == 0) rowptr[NN] = EE;
}

// ---------------- bin-scatter: packed (src:16 | fp16(w):16) 4B into CSR order ----------------
__global__ void k_ssort(const int* __restrict__ ei, const float* __restrict__ ew,
                        int* __restrict__ pos, unsigned int* __restrict__ esw) {
    int e = blockIdx.x * blockDim.x + threadIdx.x;
    if (e < EE) {
        int d = ei[EE + e];
        int p = atomicAdd(&pos[d], 1);
        _Float16 hw = (_Float16)ew[e];
        unsigned short hwb = *(unsigned short*)&hw;
        esw[p] = (unsigned int)ei[e] | ((unsigned int)hwb << 16);
    }
}

// ---------------- gather-accumulate: one wave per node, unroll 8 ----------------
__global__ __launch_bounds__(256)
void k_gather(const int* __restrict__ rowptr, const unsigned int* __restrict__ esw,
              const _Float16* __restrict__ W16, const float* __restrict__ b_edge,
              _Float16* __restrict__ outHA) {
    const int wave = threadIdx.x >> 6;
    const int lane = threadIdx.x & 63;
    const int node = blockIdx.x * 4 + wave;
    if (node >= NN) return;
    int e = rowptr[node];
    const int end = rowptr[node + 1];
    const int c0 = lane * 4;
    f4 acc0 = {0.f, 0.f, 0.f, 0.f}, acc1 = {0.f, 0.f, 0.f, 0.f};
    for (; e + 7 < end; e += 8) {
        unsigned int v[8];
        h4 r[8];
#pragma unroll
        for (int j = 0; j < 8; ++j) v[j] = esw[e + j];
#pragma unroll
        for (int j = 0; j < 8; ++j)
            r[j] = *(const h4*)(W16 + (size_t)(v[j] & 0xFFFF) * HH + c0);
#pragma unroll
        for (int j = 0; j < 8; j += 2) {
            unsigned short b0 = (unsigned short)(v[j] >> 16);
            unsigned short b1 = (unsigned short)(v[j + 1] >> 16);
            float w0 = (float)*(_Float16*)&b0;
            float w1 = (float)*(_Float16*)&b1;
            f4 f0 = {(float)r[j][0], (float)r[j][1], (float)r[j][2], (float)r[j][3]};
            f4 f1 = {(float)r[j + 1][0], (float)r[j + 1][1], (float)r[j + 1][2], (float)r[j + 1][3]};
            acc0 += w0 * f0;
            acc1 += w1 * f1;
        }
    }
    for (; e < end; ++e) {
        unsigned int v = esw[e];
        unsigned short bb = (unsigned short)(v >> 16);
        h4 rr = *(const h4*)(W16 + (size_t)(v & 0xFFFF) * HH + c0);
        f4 ff = {(float)rr[0], (float)rr[1], (float)rr[2], (float)rr[3]};
        acc0 += (float)*(_Float16*)&bb * ff;
    }
    f4 b = *(const f4*)(b_edge + c0);
    f4 acc = acc0 + acc1 + b;
    h4 hv;
    hv[0] = (_Float16)acc[0]; hv[1] = (_Float16)acc[1];
    hv[2] = (_Float16)acc[2]; hv[3] = (_Float16)acc[3];
    *(h4*)(outHA + (size_t)node * HH + c0) = hv;
}

// ---------------- fused B+C: h = relu( relu(h_a@(I+Wc1) + x@Wcomb + bB) @ W_f1 + b_f1 ) + BN stats ----------------
// 512 thr (8 waves). Wave w owns output cols [w*32, w*32+32) of both stages.
// LDS: sX [32][256B] @0 ; sA1 [32][512B] @8192 ; sOutB [32][512B] @24576. Total 40KB.
__global__ __launch_bounds__(512)
void k_gemmBC(const float* __restrict__ x, const _Float16* __restrict__ A1,
              const _Float16* __restrict__ pW, const float* __restrict__ bB,
              const float* __restrict__ b_f1, _Float16* __restrict__ H,
              float* __restrict__ stats) {
    __shared__ __align__(16) char sm[40960];
    const int tid = threadIdx.x;
    const int w = tid >> 6, l = tid & 63;
    const int lm = l & 15, lg = l >> 4;
    const int rx = tid >> 4, sx = tid & 15;

    h8 w1[8][2], wc[4][2], wf[8][2];
#pragma unroll
    for (int kb = 0; kb < 8; ++kb)
#pragma unroll
        for (int n = 0; n < 2; ++n) {
            w1[kb][n] = *(const h8*)(pW + OFF_C1 + (size_t)(kb * 16 + w * 2 + n) * 512 + l * 8);
            wf[kb][n] = *(const h8*)(pW + OFF_F1 + (size_t)(kb * 16 + w * 2 + n) * 512 + l * 8);
        }
#pragma unroll
    for (int kb = 0; kb < 4; ++kb)
#pragma unroll
        for (int n = 0; n < 2; ++n)
            wc[kb][n] = *(const h8*)(pW + OFF_NODE + (size_t)(kb * 16 + w * 2 + n) * 512 + l * 8);

    float bBreg[2], bFreg[2];
#pragma unroll
    for (int n = 0; n < 2; ++n) {
        bBreg[n] = bB[w * 32 + n * 16 + lm];
        bFreg[n] = b_f1[w * 32 + n * 16 + lm];
    }
    float sS[2] = {0.f, 0.f}, sQ[2] = {0.f, 0.f};

    const int NT = (NN + 31) / 32;
    f4 pXa, pXb;
    int4 p1[2];
    int t = blockIdx.x;
    {
        int grow = t * 32 + rx;
        const f4 zf = {0.f, 0.f, 0.f, 0.f};
        pXa = (grow < NN) ? *(const f4*)(x + (size_t)grow * FF + sx * 8) : zf;
        pXb = (grow < NN) ? *(const f4*)(x + (size_t)grow * FF + sx * 8 + 4) : zf;
#pragma unroll
        for (int j = 0; j < 2; ++j) {
            int unit = tid * 2 + j;
            int r = unit >> 5, s = unit & 31;
            int g2 = t * 32 + r;
            int4 z = {0, 0, 0, 0};
            p1[j] = (g2 < NN) ? *(const int4*)(A1 + (size_t)g2 * HH + s * 8) : z;
        }
    }

    for (; t < NT; t += gridDim.x) {
        __syncthreads();  // b0: all waves done with previous tile's LDS
        {
            h8 hx;
            hx[0] = (_Float16)pXa[0]; hx[1] = (_Float16)pXa[1];
            hx[2] = (_Float16)pXa[2]; hx[3] = (_Float16)pXa[3];
            hx[4] = (_Float16)pXb[0]; hx[5] = (_Float16)pXb[1];
            hx[6] = (_Float16)pXb[2]; hx[7] = (_Float16)pXb[3];
            *(int4*)(sm + rx * 256 + SWZ(rx, sx * 16)) = *(int4*)&hx;
        }
#pragma unroll
        for (int j = 0; j < 2; ++j) {
            int unit = tid * 2 + j;
            int r = unit >> 5, s = unit & 31;
            *(int4*)(sm + 8192 + r * 512 + SWZ(r, s * 16)) = p1[j];
        }
        int tn = t + gridDim.x;
        if (tn < NT) {
            int grow = tn * 32 + rx;
            const f4 zf = {0.f, 0.f, 0.f, 0.f};
            pXa = (grow < NN) ? *(const f4*)(x + (size_t)grow * FF + sx * 8) : zf;
            pXb = (grow < NN) ? *(const f4*)(x + (size_t)grow * FF + sx * 8 + 4) : zf;
#pragma unroll
            for (int j = 0; j < 2; ++j) {
                int unit = tid * 2 + j;
                int r = unit >> 5, s = unit & 31;
                int g2 = tn * 32 + r;
                int4 z = {0, 0, 0, 0};
                p1[j] = (g2 < NN) ? *(const int4*)(A1 + (size_t)g2 * HH + s * 8) : z;
            }
        }
        __syncthreads();  // b1: sX, sA1 ready

        // ---- stage B: outB = relu(h_a@(I+Wc1) + x@Wcomb + bB)
        f4 acc[2][2];
        const f4 z4 = {0.f, 0.f, 0.f, 0.f};
#pragma unroll
        for (int rf = 0; rf < 2; ++rf)
#pragma unroll
            for (int n = 0; n < 2; ++n) acc[rf][n] = z4;

#pragma unroll
        for (int kb = 0; kb < 8; ++kb) {
            h8 a0 = *(const h8*)(sm + 8192 + lm * 512 + SWZ(lm, kb * 64 + lg * 16));
            h8 a1 = *(const h8*)(sm + 8192 + (16 + lm) * 512 + SWZ(16 + lm, kb * 64 + lg * 16));
#pragma unroll
            for (int n = 0; n < 2; ++n) {
                acc[0][n] = __builtin_amdgcn_mfma_f32_16x16x32_f16(a0, w1[kb][n], acc[0][n], 0, 0, 0);
                acc[1][n] = __builtin_amdgcn_mfma_f32_16x16x32_f16(a1, w1[kb][n], acc[1][n], 0, 0, 0);
            }
        }
#pragma unroll
        for (int kb = 0; kb < 4; ++kb) {
            h8 a0 = *(const h8*)(sm + lm * 256 + SWZ(lm, kb * 64 + lg * 16));
            h8 a1 = *(const h8*)(sm + (16 + lm) * 256 + SWZ(16 + lm, kb * 64 + lg * 16));
#pragma unroll
            for (int n = 0; n < 2; ++n) {
                acc[0][n] = __builtin_amdgcn_mfma_f32_16x16x32_f16(a0, wc[kb][n], acc[0][n], 0, 0, 0);
                acc[1][n] = __builtin_amdgcn_mfma_f32_16x16x32_f16(a1, wc[kb][n], acc[1][n], 0, 0, 0);
            }
        }
        // epilogue B -> sOutB (fp16), wave's 32-col stripe
#pragma unroll
        for (int rf = 0; rf < 2; ++rf)
#pragma unroll
            for (int n = 0; n < 2; ++n) {
                int c2 = (w * 32 + n * 16 + lm) * 2;
#pragma unroll
                for (int q = 0; q < 4; ++q) {
                    int r = rf * 16 + lg * 4 + q;
                    float v = fmaxf(acc[rf][n][q] + bBreg[n], 0.f);
                    *(_Float16*)(sm + 24576 + r * 512 + SWZ(r, c2)) = (_Float16)v;
                }
            }
        __syncthreads();  // b2: sOutB ready

        // ---- stage C: h = relu(outB @ W_f1 + b_f1), BN stats
#pragma unroll
        for (int rf = 0; rf < 2; ++rf)
#pragma unroll
            for (int n = 0; n < 2; ++n) acc[rf][n] = z4;

#pragma unroll
        for (int kb = 0; kb < 8; ++kb) {
            h8 a0 = *(const h8*)(sm + 24576 + lm * 512 + SWZ(lm, kb * 64 + lg * 16));
            h8 a1 = *(const h8*)(sm + 24576 + (16 + lm) * 512 + SWZ(16 + lm, kb * 64 + lg * 16));
#pragma unroll
            for (int n = 0; n < 2; ++n) {
                acc[0][n] = __builtin_amdgcn_mfma_f32_16x16x32_f16(a0, wf[kb][n], acc[0][n], 0, 0, 0);
                acc[1][n] = __builtin_amdgcn_mfma_f32_16x16x32_f16(a1, wf[kb][n], acc[1][n], 0, 0, 0);
            }
        }

        const int row0 = t * 32;
#pragma unroll
        for (int rf = 0; rf < 2; ++rf)
#pragma unroll
            for (int n = 0; n < 2; ++n) {
                const int col = w * 32 + n * 16 + lm;
#pragma unroll
                for (int q = 0; q < 4; ++q) {
                    int grow = row0 + rf * 16 + lg * 4 + q;
                    if (grow < NN) {
                        float v = fmaxf(acc[rf][n][q] + bFreg[n], 0.f);
                        sS[n] += v;
                        sQ[n] += v * v;
                        H[(size_t)grow * HH + col] = (_Float16)v;
                    }
                }
            }
    }

#pragma unroll
    for (int n = 0; n < 2; ++n) {
        float s = sS[n];
        s += __shfl_xor(s, 16); s += __shfl_xor(s, 32);
        float q = sQ[n];
        q += __shfl_xor(q, 16); q += __shfl_xor(q, 32);
        if (lg == 0) {
            atomicAdd(&stats[w * 32 + n * 16 + lm], s);
            atomicAdd(&stats[HH + w * 32 + n * 16 + lm], q);
        }
    }
}

// ---------------- BN fold + pack final weights into MFMA-B fragments ----------------
__global__ __launch_bounds__(256)
void k_bnprep(const float* __restrict__ stats, const float* __restrict__ gamma,
              const float* __restrict__ beta, const float* __restrict__ W_f2,
              const float* __restrict__ b_f2, _Float16* __restrict__ pWf,
              float* __restrict__ bfold) {
    __shared__ float sh[HH];
    __shared__ float ssc[HH];
    const int tid = threadIdx.x;
    const float invN = 1.0f / (float)NN;
    {
        float mu = stats[tid] * invN;
        float var = stats[HH + tid] * invN - mu * mu;
        float scale = gamma[tid] * rsqrtf(var + BN_EPS);
        sh[tid] = beta[tid] - mu * scale;
        ssc[tid] = scale;
    }
    __syncthreads();
    if (tid < CC) {
        float b = b_f2[tid];
        for (int k = 0; k < HH; ++k) b += sh[k] * W_f2[k * CC + tid];
        bfold[tid] = b;
    }
    const int w = tid >> 6, l = tid & 63;
    const int lm = l & 15, lg = l >> 4;
#pragma unroll
    for (int i = 0; i < 6; ++i) {
        int u = w + i * 4;  // 0..23
        int kb = u / 3, nb = u % 3;
        h8 hv;
#pragma unroll
        for (int j = 0; j < 8; ++j) {
            int k = kb * 32 + lg * 8 + j;
            int c = nb * 16 + lm;
            float v = (c < CC) ? ssc[k] * W_f2[k * CC + c] : 0.f;
            hv[j] = (_Float16)v;
        }
        *(h8*)(pWf + (size_t)u * 512 + l * 8) = hv;
    }
}

// ---------------- final via MFMA: out = h @ (scale*W_f2) + bfold ----------------
__global__ __launch_bounds__(256)
void k_finalM(const _Float16* __restrict__ h, const _Float16* __restrict__ pWf,
              const float* __restrict__ bfold, float* __restrict__ out) {
    __shared__ __align__(16) char sA[64 * 512];
    const int tid = threadIdx.x;
    const int w = tid >> 6, l = tid & 63;
    const int lm = l & 15, lg = l >> 4;

    h8 wreg[8][3];
#pragma unroll
    for (int kb = 0; kb < 8; ++kb)
#pragma unroll
        for (int nb = 0; nb < 3; ++nb)
            wreg[kb][nb] = *(const h8*)(pWf + (size_t)(kb * 3 + nb) * 512 + l * 8);

    const int row0 = blockIdx.x * 64;
#pragma unroll
    for (int j = 0; j < 8; ++j) {
        int unit = tid * 8 + j;
        int r = unit >> 5, s = unit & 31;
        int grow = row0 + r;
        int4 z = {0, 0, 0, 0};
        int4 v = (grow < NN) ? *(const int4*)(h + (size_t)grow * HH + s * 8) : z;
        *(int4*)(sA + r * 512 + SWZ(r, s * 16)) = v;
    }
    __syncthreads();

    f4 acc[3];
    const f4 z4 = {0.f, 0.f, 0.f, 0.f};
#pragma unroll
    for (int nb = 0; nb < 3; ++nb) acc[nb] = z4;

    const int ar = w * 16 + lm;
#pragma unroll
    for (int kb = 0; kb < 8; ++kb) {
        h8 a = *(const h8*)(sA + ar * 512 + SWZ(ar, kb * 64 + lg * 16));
#pragma unroll
        for (int nb = 0; nb < 3; ++nb)
            acc[nb] = __builtin_amdgcn_mfma_f32_16x16x32_f16(a, wreg[kb][nb], acc[nb], 0, 0, 0);
    }

#pragma unroll
    for (int nb = 0; nb < 3; ++nb) {
        int col = nb * 16 + lm;
        if (col < CC) {
            float bb = bfold[col];
#pragma unroll
            for (int q = 0; q < 4; ++q) {
                int grow = row0 + w * 16 + lg * 4 + q;
                if (grow < NN) out[(size_t)grow * CC + col] = acc[nb][q] + bb;
            }
        }
    }
}

extern "C" void kernel_launch(void* const* d_in, const int* in_sizes, int n_in,
                              void* d_out, int out_size, void* d_ws, size_t ws_size,
                              hipStream_t stream) {
    const float* x      = (const float*)d_in[0];
    const int*   ei     = (const int*)d_in[1];
    const float* ew     = (const float*)d_in[2];
    const float* W_edge = (const float*)d_in[3];
    const float* b_edge = (const float*)d_in[4];
    const float* W_node = (const float*)d_in[5];
    const float* b_node = (const float*)d_in[6];
    const float* W_c1   = (const float*)d_in[7];
    const float* b_c1   = (const float*)d_in[8];
    const float* W_c2   = (const float*)d_in[9];
    const float* b_c2   = (const float*)d_in[10];
    const float* W_f1   = (const float*)d_in[11];
    const float* b_f1   = (const float*)d_in[12];
    const float* gamma  = (const float*)d_in[13];
    const float* beta   = (const float*)d_in[14];
    const float* W_f2   = (const float*)d_in[15];
    const float* b_f2   = (const float*)d_in[16];
    float* out = (float*)d_out;

    const size_t NNH = (size_t)NN * HH;
    _Float16* bufA = (_Float16*)d_ws;            // h_a
    _Float16* bufH = bufA + NNH;                 // h
    _Float16* W16  = bufH + NNH;                 // fp16 W_edge
    unsigned int* esw = (unsigned int*)(W16 + NNH);  // E packed
    float* stats   = (float*)(esw + EE);         // 512
    float* bB      = stats + 2 * HH;             // 256
    float* bfold   = bB + HH;                    // 64
    _Float16* pWf  = (_Float16*)(bfold + 64);    // 24*512
    _Float16* pW   = pWf + 24 * 512;             // PW_HALVES
    float* Wcomb   = (float*)(pW + PW_HALVES);   // 128*256 fp32
    int* deg       = (int*)(Wcomb + FF * HH);    // N
    int* rowptr    = deg + NN;                   // N+1
    int* pos       = rowptr + NN + 1;            // N
    int* bsums     = pos + NN;                   // 256

    hipMemsetAsync(stats, 0, 2 * HH * sizeof(float), stream);
    hipMemsetAsync(deg, 0, NN * sizeof(int), stream);

    k_wcomb<<<8, 256, 0, stream>>>(W_node, W_c2, Wcomb);
    k_prep<<<2048, 256, 0, stream>>>(W_edge, W16, ei, deg);
    k_pack<<<81, 256, 0, stream>>>(Wcomb, W_c1, W_c2, W_f1, b_node, b_c1, b_c2, pW, bB);
    k_scan1<<<196, 256, 0, stream>>>(deg, rowptr, bsums);
    k_scan2<<<1, 256, 0, stream>>>(bsums);
    k_scan3<<<196, 256, 0, stream>>>(rowptr, bsums, pos);
    k_ssort<<<(EE + 255) / 256, 256, 0, stream>>>(ei, ew, pos, esw);
    k_gather<<<12500, 256, 0, stream>>>(rowptr, esw, W16, b_edge, bufA);

    // fused B+C: h = relu( relu(h_a@(I+Wc1) + x@Wcomb + bB) @ W_f1 + b_f1 ) + stats
    k_gemmBC<<<256, 512, 0, stream>>>(x, bufA, pW, bB, b_f1, bufH, stats);

    k_bnprep<<<1, 256, 0, stream>>>(stats, gamma, beta, W_f2, b_f2, pWf, bfold);
    k_finalM<<<(NN + 63) / 64, 256, 0, stream>>>(bufH, pWf, bfold, out);
}

// Round 13
// 242.238 us; speedup vs baseline: 1.1550x; 1.1079x over previous
//
#include <hip/hip_runtime.h>

#define NN 50000
#define EE 800000
#define FF 128
#define HH 256
#define CC 40
#define BN_EPS 1e-5f
#define NBUCK 196
#define CHK 3200
#define BCAP 6144

typedef float f4 __attribute__((ext_vector_type(4)));
typedef _Float16 h8 __attribute__((ext_vector_type(8)));
typedef _Float16 h4 __attribute__((ext_vector_type(4)));

// packed units (512 halves each): [0,64) Wcomb (K=128), [64,192) I+Wc1 (K=256), [192,320) W_f1 (K=256)
#define OFF_NODE 0
#define OFF_C1   32768
#define OFF_F1   98304
#define PW_HALVES 163840

#define SWZ(row, c2) ((c2) ^ (((row) & 7) << 4))

// ---------------- Wcomb = Wn + Wn@Wc2  (fp32, coalesced) ----------------
__global__ __launch_bounds__(256)
void k_wcomb(const float* __restrict__ Wn, const float* __restrict__ Wc2,
             float* __restrict__ Wcomb) {
    __shared__ float WnL[16][256];
    const int c = threadIdx.x;
    const int r0 = blockIdx.x * 16;
    for (int i = threadIdx.x; i < 16 * 256; i += 256)
        WnL[i >> 8][i & 255] = Wn[(r0 + (i >> 8)) * HH + (i & 255)];
    __syncthreads();
    float acc[16];
#pragma unroll
    for (int r = 0; r < 16; ++r) acc[r] = WnL[r][c];
    for (int k = 0; k < 256; ++k) {
        float wv = Wc2[k * HH + c];
#pragma unroll
        for (int r = 0; r < 16; ++r) acc[r] += WnL[r][k] * wv;
    }
#pragma unroll
    for (int r = 0; r < 16; ++r) Wcomb[(r0 + r) * HH + c] = acc[r];
}

// ---------------- prep: W_edge -> fp16  +  histogram of dst ----------------
__global__ __launch_bounds__(256)
void k_prep(const float* __restrict__ W, _Float16* __restrict__ W16,
            const int* __restrict__ ei, int* __restrict__ deg) {
    const int gsz = gridDim.x * blockDim.x;
    const int i0 = blockIdx.x * blockDim.x + threadIdx.x;
    for (int j = i0; j < NN * HH / 8; j += gsz) {
        f4 v0 = ((const f4*)W)[j * 2];
        f4 v1 = ((const f4*)W)[j * 2 + 1];
        h8 h;
        h[0] = (_Float16)v0[0]; h[1] = (_Float16)v0[1];
        h[2] = (_Float16)v0[2]; h[3] = (_Float16)v0[3];
        h[4] = (_Float16)v1[0]; h[5] = (_Float16)v1[1];
        h[6] = (_Float16)v1[2]; h[7] = (_Float16)v1[3];
        ((h8*)W16)[j] = h;
    }
    for (int e = i0; e < EE; e += gsz) atomicAdd(&deg[ei[EE + e]], 1);
}

// ---------------- pack weights into MFMA-B fragment layout (fp16) ----------------
__global__ __launch_bounds__(256)
void k_pack(const float* __restrict__ Wcomb, const float* __restrict__ W_c1,
            const float* __restrict__ W_c2, const float* __restrict__ W_f1,
            const float* __restrict__ b_node, const float* __restrict__ b_c1,
            const float* __restrict__ b_c2, _Float16* __restrict__ pW,
            float* __restrict__ bB) {
    const int tid = threadIdx.x;
    if (blockIdx.x == 80) {  // combined phase-B bias: b_c1+b_c2+b_node@(I+W_c2)
        int c = tid;
        if (c < HH) {
            float a = 0.f;
            for (int k = 0; k < HH; ++k) a += b_node[k] * W_c2[k * HH + c];
            bB[c] = a + b_node[c] + b_c1[c] + b_c2[c];
        }
        return;
    }
    const int unit = blockIdx.x * 4 + (tid >> 6);
    const int lane = tid & 63, lm = lane & 15, lg = lane >> 4;
    const float* Ws;
    bool addI;
    int u = unit;
    if (u < 64)       { Ws = Wcomb; addI = false; }
    else if (u < 192) { Ws = W_c1;  addI = true;  u -= 64; }
    else              { Ws = W_f1;  addI = false; u -= 192; }
    const int kb = u >> 4, nb = u & 15;
    h8 hv;
#pragma unroll
    for (int j = 0; j < 8; ++j) {
        int kr = kb * 32 + lg * 8 + j;
        int col = nb * 16 + lm;
        float v = Ws[kr * HH + col];
        if (addI && kr == col) v += 1.f;
        hv[j] = (_Float16)v;
    }
    *(h8*)(pW + (size_t)unit * 512 + lane * 8) = hv;
}

// ---------------- two-level scan (btail init folded into scan3) ----------------
__global__ __launch_bounds__(256)
void k_scan1(const int* __restrict__ deg, int* __restrict__ rowptr, int* __restrict__ bsums) {
    __shared__ int t[256];
    const int tid = threadIdx.x;
    int i = blockIdx.x * 256 + tid;
    int v = (i < NN) ? deg[i] : 0;
    t[tid] = v;
    __syncthreads();
#pragma unroll
    for (int off = 1; off < 256; off <<= 1) {
        int u = (tid >= off) ? t[tid - off] : 0;
        __syncthreads();
        t[tid] += u;
        __syncthreads();
    }
    if (i < NN) rowptr[i] = t[tid] - v;
    if (tid == 255) bsums[blockIdx.x] = t[tid];
}
__global__ __launch_bounds__(256)
void k_scan2(int* __restrict__ bsums) {
    __shared__ int t[256];
    const int tid = threadIdx.x;
    int v = (tid < NBUCK) ? bsums[tid] : 0;
    t[tid] = v;
    __syncthreads();
#pragma unroll
    for (int off = 1; off < 256; off <<= 1) {
        int u = (tid >= off) ? t[tid - off] : 0;
        __syncthreads();
        t[tid] += u;
        __syncthreads();
    }
    if (tid < NBUCK) bsums[tid] = t[tid] - v;
}
__global__ __launch_bounds__(256)
void k_scan3(int* __restrict__ rowptr, const int* __restrict__ bsums, int* __restrict__ btail) {
    int i = blockIdx.x * 256 + threadIdx.x;
    if (i < NN) {
        int r = rowptr[i] + bsums[blockIdx.x];
        rowptr[i] = r;
        if ((i & 255) == 0) btail[i >> 8] = r;  // bucket write cursor = bucket base
    }
    if (i == 0) rowptr[NN] = EE;
}

// ---------------- phase A: LDS-staged coarse binning into tmp (uint2 {src|w, dst}) ----------------
__global__ __launch_bounds__(256)
void k_binA(const int* __restrict__ ei, const float* __restrict__ ew,
            int* __restrict__ btail, uint2* __restrict__ tmp) {
    __shared__ int lcnt[NBUCK], lpre[NBUCK], lbase[NBUCK], lcnt2[NBUCK];
    __shared__ int t[256];
    __shared__ uint2 staged[CHK];
    __shared__ unsigned char bslot[CHK];
    const int tid = threadIdx.x;
    const int e0 = blockIdx.x * CHK;
    const int n = min(CHK, EE - e0);
    for (int i = tid; i < NBUCK; i += 256) { lcnt[i] = 0; lcnt2[i] = 0; }
    __syncthreads();
    for (int i = tid; i < n; i += 256) {
        int d = ei[EE + e0 + i];
        atomicAdd(&lcnt[d >> 8], 1);
    }
    __syncthreads();
    {
        int v = (tid < NBUCK) ? lcnt[tid] : 0;
        t[tid] = v;
        __syncthreads();
#pragma unroll
        for (int off = 1; off < 256; off <<= 1) {
            int u = (tid >= off) ? t[tid - off] : 0;
            __syncthreads();
            t[tid] += u;
            __syncthreads();
        }
        if (tid < NBUCK) lpre[tid] = t[tid] - v;
    }
    __syncthreads();
    if (tid < NBUCK && lcnt[tid] > 0)
        lbase[tid] = atomicAdd(&btail[tid], lcnt[tid]);
    __syncthreads();
    for (int i = tid; i < n; i += 256) {
        int e = e0 + i;
        int d = ei[EE + e];
        int b = d >> 8;
        _Float16 hw = (_Float16)ew[e];
        unsigned short hwb = *(unsigned short*)&hw;
        unsigned int lo = (unsigned int)ei[e] | ((unsigned int)hwb << 16);
        int slot = lpre[b] + atomicAdd(&lcnt2[b], 1);
        uint2 v;
        v.x = lo;
        v.y = (unsigned int)d;
        staged[slot] = v;
        bslot[slot] = (unsigned char)b;
    }
    __syncthreads();
    for (int s = tid; s < n; s += 256) {
        int b = bslot[s];
        tmp[lbase[b] + (s - lpre[b])] = staged[s];  // coalesced runs per bucket
    }
}

// ---------------- phase B: exact per-node CSR sort within each bucket -> esw ----------------
__global__ __launch_bounds__(256)
void k_binB(const int* __restrict__ rowptr, const uint2* __restrict__ tmp,
            unsigned int* __restrict__ esw) {
    __shared__ int lpos[256];
    __shared__ unsigned int sout[BCAP];
    const int tid = threadIdx.x;
    const int b = blockIdx.x;
    const int nb0 = b * 256;
    const int nEnd = min(nb0 + 256, NN);
    const int base = rowptr[nb0];
    const int cnt = rowptr[nEnd] - base;
    lpos[tid] = (nb0 + tid < nEnd) ? rowptr[nb0 + tid] - base : 0;
    __syncthreads();
    if (cnt <= BCAP) {
        for (int i = tid; i < cnt; i += 256) {
            uint2 v = tmp[base + i];
            int dr = (int)v.y - nb0;
            int p = atomicAdd(&lpos[dr], 1);
            sout[p] = v.x;
        }
        __syncthreads();
        for (int s = tid; s < cnt; s += 256) esw[base + s] = sout[s];  // coalesced, single XCD
    } else {
        for (int i = tid; i < cnt; i += 256) {
            uint2 v = tmp[base + i];
            int dr = (int)v.y - nb0;
            int p = atomicAdd(&lpos[dr], 1);
            esw[base + p] = v.x;
        }
    }
}

// ---------------- gather-accumulate: one wave per node, unroll 8 (proven) ----------------
__global__ __launch_bounds__(256)
void k_gather(const int* __restrict__ rowptr, const unsigned int* __restrict__ esw,
              const _Float16* __restrict__ W16, const float* __restrict__ b_edge,
              _Float16* __restrict__ outHA) {
    const int wave = threadIdx.x >> 6;
    const int lane = threadIdx.x & 63;
    const int node = blockIdx.x * 4 + wave;
    if (node >= NN) return;
    int e = rowptr[node];
    const int end = rowptr[node + 1];
    const int c0 = lane * 4;
    f4 acc0 = {0.f, 0.f, 0.f, 0.f}, acc1 = {0.f, 0.f, 0.f, 0.f};
    for (; e + 7 < end; e += 8) {
        unsigned int v[8];
        h4 r[8];
#pragma unroll
        for (int j = 0; j < 8; ++j) v[j] = esw[e + j];
#pragma unroll
        for (int j = 0; j < 8; ++j)
            r[j] = *(const h4*)(W16 + (size_t)(v[j] & 0xFFFF) * HH + c0);
#pragma unroll
        for (int j = 0; j < 8; j += 2) {
            unsigned short b0 = (unsigned short)(v[j] >> 16);
            unsigned short b1 = (unsigned short)(v[j + 1] >> 16);
            float w0 = (float)*(_Float16*)&b0;
            float w1 = (float)*(_Float16*)&b1;
            f4 f0 = {(float)r[j][0], (float)r[j][1], (float)r[j][2], (float)r[j][3]};
            f4 f1 = {(float)r[j + 1][0], (float)r[j + 1][1], (float)r[j + 1][2], (float)r[j + 1][3]};
            acc0 += w0 * f0;
            acc1 += w1 * f1;
        }
    }
    for (; e < end; ++e) {
        unsigned int v = esw[e];
        unsigned short bb = (unsigned short)(v >> 16);
        h4 rr = *(const h4*)(W16 + (size_t)(v & 0xFFFF) * HH + c0);
        f4 ff = {(float)rr[0], (float)rr[1], (float)rr[2], (float)rr[3]};
        acc0 += (float)*(_Float16*)&bb * ff;
    }
    f4 b = *(const f4*)(b_edge + c0);
    f4 acc = acc0 + acc1 + b;
    h4 hv;
    hv[0] = (_Float16)acc[0]; hv[1] = (_Float16)acc[1];
    hv[2] = (_Float16)acc[2]; hv[3] = (_Float16)acc[3];
    *(h4*)(outHA + (size_t)node * HH + c0) = hv;
}

// ---------------- fused B+C: h = relu( relu(h_a@(I+Wc1) + x@Wcomb + bB) @ W_f1 + b_f1 ) + BN stats ----------------
__global__ __launch_bounds__(512)
void k_gemmBC(const float* __restrict__ x, const _Float16* __restrict__ A1,
              const _Float16* __restrict__ pW, const float* __restrict__ bB,
              const float* __restrict__ b_f1, _Float16* __restrict__ H,
              float* __restrict__ stats) {
    __shared__ __align__(16) char sm[40960];
    const int tid = threadIdx.x;
    const int w = tid >> 6, l = tid & 63;
    const int lm = l & 15, lg = l >> 4;
    const int rx = tid >> 4, sx = tid & 15;

    h8 w1[8][2], wc[4][2], wf[8][2];
#pragma unroll
    for (int kb = 0; kb < 8; ++kb)
#pragma unroll
        for (int n = 0; n < 2; ++n) {
            w1[kb][n] = *(const h8*)(pW + OFF_C1 + (size_t)(kb * 16 + w * 2 + n) * 512 + l * 8);
            wf[kb][n] = *(const h8*)(pW + OFF_F1 + (size_t)(kb * 16 + w * 2 + n) * 512 + l * 8);
        }
#pragma unroll
    for (int kb = 0; kb < 4; ++kb)
#pragma unroll
        for (int n = 0; n < 2; ++n)
            wc[kb][n] = *(const h8*)(pW + OFF_NODE + (size_t)(kb * 16 + w * 2 + n) * 512 + l * 8);

    float bBreg[2], bFreg[2];
#pragma unroll
    for (int n = 0; n < 2; ++n) {
        bBreg[n] = bB[w * 32 + n * 16 + lm];
        bFreg[n] = b_f1[w * 32 + n * 16 + lm];
    }
    float sS[2] = {0.f, 0.f}, sQ[2] = {0.f, 0.f};

    const int NT = (NN + 31) / 32;
    f4 pXa, pXb;
    int4 p1[2];
    int t = blockIdx.x;
    {
        int grow = t * 32 + rx;
        const f4 zf = {0.f, 0.f, 0.f, 0.f};
        pXa = (grow < NN) ? *(const f4*)(x + (size_t)grow * FF + sx * 8) : zf;
        pXb = (grow < NN) ? *(const f4*)(x + (size_t)grow * FF + sx * 8 + 4) : zf;
#pragma unroll
        for (int j = 0; j < 2; ++j) {
            int unit = tid * 2 + j;
            int r = unit >> 5, s = unit & 31;
            int g2 = t * 32 + r;
            int4 z = {0, 0, 0, 0};
            p1[j] = (g2 < NN) ? *(const int4*)(A1 + (size_t)g2 * HH + s * 8) : z;
        }
    }

    for (; t < NT; t += gridDim.x) {
        __syncthreads();  // b0
        {
            h8 hx;
            hx[0] = (_Float16)pXa[0]; hx[1] = (_Float16)pXa[1];
            hx[2] = (_Float16)pXa[2]; hx[3] = (_Float16)pXa[3];
            hx[4] = (_Float16)pXb[0]; hx[5] = (_Float16)pXb[1];
            hx[6] = (_Float16)pXb[2]; hx[7] = (_Float16)pXb[3];
            *(int4*)(sm + rx * 256 + SWZ(rx, sx * 16)) = *(int4*)&hx;
        }
#pragma unroll
        for (int j = 0; j < 2; ++j) {
            int unit = tid * 2 + j;
            int r = unit >> 5, s = unit & 31;
            *(int4*)(sm + 8192 + r * 512 + SWZ(r, s * 16)) = p1[j];
        }
        int tn = t + gridDim.x;
        if (tn < NT) {
            int grow = tn * 32 + rx;
            const f4 zf = {0.f, 0.f, 0.f, 0.f};
            pXa = (grow < NN) ? *(const f4*)(x + (size_t)grow * FF + sx * 8) : zf;
            pXb = (grow < NN) ? *(const f4*)(x + (size_t)grow * FF + sx * 8 + 4) : zf;
#pragma unroll
            for (int j = 0; j < 2; ++j) {
                int unit = tid * 2 + j;
                int r = unit >> 5, s = unit & 31;
                int g2 = tn * 32 + r;
                int4 z = {0, 0, 0, 0};
                p1[j] = (g2 < NN) ? *(const int4*)(A1 + (size_t)g2 * HH + s * 8) : z;
            }
        }
        __syncthreads();  // b1

        // ---- stage B
        f4 acc[2][2];
        const f4 z4 = {0.f, 0.f, 0.f, 0.f};
#pragma unroll
        for (int rf = 0; rf < 2; ++rf)
#pragma unroll
            for (int n = 0; n < 2; ++n) acc[rf][n] = z4;

#pragma unroll
        for (int kb = 0; kb < 8; ++kb) {
            h8 a0 = *(const h8*)(sm + 8192 + lm * 512 + SWZ(lm, kb * 64 + lg * 16));
            h8 a1 = *(const h8*)(sm + 8192 + (16 + lm) * 512 + SWZ(16 + lm, kb * 64 + lg * 16));
#pragma unroll
            for (int n = 0; n < 2; ++n) {
                acc[0][n] = __builtin_amdgcn_mfma_f32_16x16x32_f16(a0, w1[kb][n], acc[0][n], 0, 0, 0);
                acc[1][n] = __builtin_amdgcn_mfma_f32_16x16x32_f16(a1, w1[kb][n], acc[1][n], 0, 0, 0);
            }
        }
#pragma unroll
        for (int kb = 0; kb < 4; ++kb) {
            h8 a0 = *(const h8*)(sm + lm * 256 + SWZ(lm, kb * 64 + lg * 16));
            h8 a1 = *(const h8*)(sm + (16 + lm) * 256 + SWZ(16 + lm, kb * 64 + lg * 16));
#pragma unroll
            for (int n = 0; n < 2; ++n) {
                acc[0][n] = __builtin_amdgcn_mfma_f32_16x16x32_f16(a0, wc[kb][n], acc[0][n], 0, 0, 0);
                acc[1][n] = __builtin_amdgcn_mfma_f32_16x16x32_f16(a1, wc[kb][n], acc[1][n], 0, 0, 0);
            }
        }
#pragma unroll
        for (int rf = 0; rf < 2; ++rf)
#pragma unroll
            for (int n = 0; n < 2; ++n) {
                int c2 = (w * 32 + n * 16 + lm) * 2;
#pragma unroll
                for (int q = 0; q < 4; ++q) {
                    int r = rf * 16 + lg * 4 + q;
                    float v = fmaxf(acc[rf][n][q] + bBreg[n], 0.f);
                    *(_Float16*)(sm + 24576 + r * 512 + SWZ(r, c2)) = (_Float16)v;
                }
            }
        __syncthreads();  // b2

        // ---- stage C
#pragma unroll
        for (int rf = 0; rf < 2; ++rf)
#pragma unroll
            for (int n = 0; n < 2; ++n) acc[rf][n] = z4;

#pragma unroll
        for (int kb = 0; kb < 8; ++kb) {
            h8 a0 = *(const h8*)(sm + 24576 + lm * 512 + SWZ(lm, kb * 64 + lg * 16));
            h8 a1 = *(const h8*)(sm + 24576 + (16 + lm) * 512 + SWZ(16 + lm, kb * 64 + lg * 16));
#pragma unroll
            for (int n = 0; n < 2; ++n) {
                acc[0][n] = __builtin_amdgcn_mfma_f32_16x16x32_f16(a0, wf[kb][n], acc[0][n], 0, 0, 0);
                acc[1][n] = __builtin_amdgcn_mfma_f32_16x16x32_f16(a1, wf[kb][n], acc[1][n], 0, 0, 0);
            }
        }

        const int row0 = t * 32;
#pragma unroll
        for (int rf = 0; rf < 2; ++rf)
#pragma unroll
            for (int n = 0; n < 2; ++n) {
                const int col = w * 32 + n * 16 + lm;
#pragma unroll
                for (int q = 0; q < 4; ++q) {
                    int grow = row0 + rf * 16 + lg * 4 + q;
                    if (grow < NN) {
                        float v = fmaxf(acc[rf][n][q] + bFreg[n], 0.f);
                        sS[n] += v;
                        sQ[n] += v * v;
                        H[(size_t)grow * HH + col] = (_Float16)v;
                    }
                }
            }
    }

#pragma unroll
    for (int n = 0; n < 2; ++n) {
        float s = sS[n];
        s += __shfl_xor(s, 16); s += __shfl_xor(s, 32);
        float q = sQ[n];
        q += __shfl_xor(q, 16); q += __shfl_xor(q, 32);
        if (lg == 0) {
            atomicAdd(&stats[w * 32 + n * 16 + lm], s);
            atomicAdd(&stats[HH + w * 32 + n * 16 + lm], q);
        }
    }
}

// ---------------- BN fold + pack final weights into MFMA-B fragments ----------------
__global__ __launch_bounds__(256)
void k_bnprep(const float* __restrict__ stats, const float* __restrict__ gamma,
              const float* __restrict__ beta, const float* __restrict__ W_f2,
              const float* __restrict__ b_f2, _Float16* __restrict__ pWf,
              float* __restrict__ bfold) {
    __shared__ float sh[HH];
    __shared__ float ssc[HH];
    const int tid = threadIdx.x;
    const float invN = 1.0f / (float)NN;
    {
        float mu = stats[tid] * invN;
        float var = stats[HH + tid] * invN - mu * mu;
        float scale = gamma[tid] * rsqrtf(var + BN_EPS);
        sh[tid] = beta[tid] - mu * scale;
        ssc[tid] = scale;
    }
    __syncthreads();
    if (tid < CC) {
        float b = b_f2[tid];
        for (int k = 0; k < HH; ++k) b += sh[k] * W_f2[k * CC + tid];
        bfold[tid] = b;
    }
    const int w = tid >> 6, l = tid & 63;
    const int lm = l & 15, lg = l >> 4;
#pragma unroll
    for (int i = 0; i < 6; ++i) {
        int u = w + i * 4;  // 0..23
        int kb = u / 3, nb = u % 3;
        h8 hv;
#pragma unroll
        for (int j = 0; j < 8; ++j) {
            int k = kb * 32 + lg * 8 + j;
            int c = nb * 16 + lm;
            float v = (c < CC) ? ssc[k] * W_f2[k * CC + c] : 0.f;
            hv[j] = (_Float16)v;
        }
        *(h8*)(pWf + (size_t)u * 512 + l * 8) = hv;
    }
}

// ---------------- final via MFMA: out = h @ (scale*W_f2) + bfold ----------------
__global__ __launch_bounds__(256)
void k_finalM(const _Float16* __restrict__ h, const _Float16* __restrict__ pWf,
              const float* __restrict__ bfold, float* __restrict__ out) {
    __shared__ __align__(16) char sA[64 * 512];
    const int tid = threadIdx.x;
    const int w = tid >> 6, l = tid & 63;
    const int lm = l & 15, lg = l >> 4;

    h8 wreg[8][3];
#pragma unroll
    for (int kb = 0; kb < 8; ++kb)
#pragma unroll
        for (int nb = 0; nb < 3; ++nb)
            wreg[kb][nb] = *(const h8*)(pWf + (size_t)(kb * 3 + nb) * 512 + l * 8);

    const int row0 = blockIdx.x * 64;
#pragma unroll
    for (int j = 0; j < 8; ++j) {
        int unit = tid * 8 + j;
        int r = unit >> 5, s = unit & 31;
        int grow = row0 + r;
        int4 z = {0, 0, 0, 0};
        int4 v = (grow < NN) ? *(const int4*)(h + (size_t)grow * HH + s * 8) : z;
        *(int4*)(sA + r * 512 + SWZ(r, s * 16)) = v;
    }
    __syncthreads();

    f4 acc[3];
    const f4 z4 = {0.f, 0.f, 0.f, 0.f};
#pragma unroll
    for (int nb = 0; nb < 3; ++nb) acc[nb] = z4;

    const int ar = w * 16 + lm;
#pragma unroll
    for (int kb = 0; kb < 8; ++kb) {
        h8 a = *(const h8*)(sA + ar * 512 + SWZ(ar, kb * 64 + lg * 16));
#pragma unroll
        for (int nb = 0; nb < 3; ++nb)
            acc[nb] = __builtin_amdgcn_mfma_f32_16x16x32_f16(a, wreg[kb][nb], acc[nb], 0, 0, 0);
    }

#pragma unroll
    for (int nb = 0; nb < 3; ++nb) {
        int col = nb * 16 + lm;
        if (col < CC) {
            float bb = bfold[col];
#pragma unroll
            for (int q = 0; q < 4; ++q) {
                int grow = row0 + w * 16 + lg * 4 + q;
                if (grow < NN) out[(size_t)grow * CC + col] = acc[nb][q] + bb;
            }
        }
    }
}

extern "C" void kernel_launch(void* const* d_in, const int* in_sizes, int n_in,
                              void* d_out, int out_size, void* d_ws, size_t ws_size,
                              hipStream_t stream) {
    const float* x      = (const float*)d_in[0];
    const int*   ei     = (const int*)d_in[1];
    const float* ew     = (const float*)d_in[2];
    const float* W_edge = (const float*)d_in[3];
    const float* b_edge = (const float*)d_in[4];
    const float* W_node = (const float*)d_in[5];
    const float* b_node = (const float*)d_in[6];
    const float* W_c1   = (const float*)d_in[7];
    const float* b_c1   = (const float*)d_in[8];
    const float* W_c2   = (const float*)d_in[9];
    const float* b_c2   = (const float*)d_in[10];
    const float* W_f1   = (const float*)d_in[11];
    const float* b_f1   = (const float*)d_in[12];
    const float* gamma  = (const float*)d_in[13];
    const float* beta   = (const float*)d_in[14];
    const float* W_f2   = (const float*)d_in[15];
    const float* b_f2   = (const float*)d_in[16];
    float* out = (float*)d_out;

    const size_t NNH = (size_t)NN * HH;
    _Float16* bufA = (_Float16*)d_ws;            // h_a
    _Float16* bufH = bufA + NNH;                 // h
    _Float16* W16  = bufH + NNH;                 // fp16 W_edge
    unsigned int* esw = (unsigned int*)(W16 + NNH);  // E packed 4B
    float* stats   = (float*)(esw + EE);         // 512
    float* bB      = stats + 2 * HH;             // 256
    float* bfold   = bB + HH;                    // 64
    _Float16* pWf  = (_Float16*)(bfold + 64);    // 24*512
    _Float16* pW   = pWf + 24 * 512;             // PW_HALVES
    float* Wcomb   = (float*)(pW + PW_HALVES);   // 128*256 fp32
    uint2* tmp     = (uint2*)(Wcomb + FF * HH);  // E uint2 (8B-aligned)
    int* deg       = (int*)(tmp + EE);           // N
    int* rowptr    = deg + NN;                   // N+1
    int* btail     = rowptr + NN + 1;            // NBUCK
    int* bsums     = btail + NBUCK;              // 256

    hipMemsetAsync(stats, 0, 2 * HH * sizeof(float), stream);
    hipMemsetAsync(deg, 0, NN * sizeof(int), stream);

    k_wcomb<<<8, 256, 0, stream>>>(W_node, W_c2, Wcomb);
    k_prep<<<2048, 256, 0, stream>>>(W_edge, W16, ei, deg);
    k_pack<<<81, 256, 0, stream>>>(Wcomb, W_c1, W_c2, W_f1, b_node, b_c1, b_c2, pW, bB);
    k_scan1<<<196, 256, 0, stream>>>(deg, rowptr, bsums);
    k_scan2<<<1, 256, 0, stream>>>(bsums);
    k_scan3<<<196, 256, 0, stream>>>(rowptr, bsums, btail);
    k_binA<<<(EE + CHK - 1) / CHK, 256, 0, stream>>>(ei, ew, btail, tmp);
    k_binB<<<NBUCK, 256, 0, stream>>>(rowptr, tmp, esw);
    k_gather<<<12500, 256, 0, stream>>>(rowptr, esw, W16, b_edge, bufA);

    // fused B+C: h = relu( relu(h_a@(I+Wc1) + x@Wcomb + bB) @ W_f1 + b_f1 ) + stats
    k_gemmBC<<<256, 512, 0, stream>>>(x, bufA, pW, bB, b_f1, bufH, stats);

    k_bnprep<<<1, 256, 0, stream>>>(stats, gamma, beta, W_f2, b_f2, pWf, bfold);
    k_finalM<<<(NN + 63) / 64, 256, 0, stream>>>(bufH, pWf, bfold, out);
}

// Round 14
// 237.782 us; speedup vs baseline: 1.1767x; 1.0187x over previous
//
#include <hip/hip_runtime.h>

#define NN 50000
#define EE 800000
#define FF 128
#define HH 256
#define CC 40
#define BN_EPS 1e-5f
#define NBUCK 196
#define CHK 3200
#define BCAP 6144

typedef float f4 __attribute__((ext_vector_type(4)));
typedef _Float16 h8 __attribute__((ext_vector_type(8)));
typedef _Float16 h4 __attribute__((ext_vector_type(4)));

// packed units (512 halves each): [0,64) Wcomb (K=128), [64,192) I+Wc1 (K=256), [192,320) W_f1 (K=256)
#define OFF_NODE 0
#define OFF_C1   32768
#define OFF_F1   98304
#define PW_HALVES 163840

#define SWZ(row, c2) ((c2) ^ (((row) & 7) << 4))

// ---------------- Wcomb = Wn + Wn@Wc2  (fp32, coalesced) ----------------
__global__ __launch_bounds__(256)
void k_wcomb(const float* __restrict__ Wn, const float* __restrict__ Wc2,
             float* __restrict__ Wcomb) {
    __shared__ float WnL[16][256];
    const int c = threadIdx.x;
    const int r0 = blockIdx.x * 16;
    for (int i = threadIdx.x; i < 16 * 256; i += 256)
        WnL[i >> 8][i & 255] = Wn[(r0 + (i >> 8)) * HH + (i & 255)];
    __syncthreads();
    float acc[16];
#pragma unroll
    for (int r = 0; r < 16; ++r) acc[r] = WnL[r][c];
    for (int k = 0; k < 256; ++k) {
        float wv = Wc2[k * HH + c];
#pragma unroll
        for (int r = 0; r < 16; ++r) acc[r] += WnL[r][k] * wv;
    }
#pragma unroll
    for (int r = 0; r < 16; ++r) Wcomb[(r0 + r) * HH + c] = acc[r];
}

// ---------------- prep: W_edge -> fp16  +  histogram of dst ----------------
__global__ __launch_bounds__(256)
void k_prep(const float* __restrict__ W, _Float16* __restrict__ W16,
            const int* __restrict__ ei, int* __restrict__ deg) {
    const int gsz = gridDim.x * blockDim.x;
    const int i0 = blockIdx.x * blockDim.x + threadIdx.x;
    for (int j = i0; j < NN * HH / 8; j += gsz) {
        f4 v0 = ((const f4*)W)[j * 2];
        f4 v1 = ((const f4*)W)[j * 2 + 1];
        h8 h;
        h[0] = (_Float16)v0[0]; h[1] = (_Float16)v0[1];
        h[2] = (_Float16)v0[2]; h[3] = (_Float16)v0[3];
        h[4] = (_Float16)v1[0]; h[5] = (_Float16)v1[1];
        h[6] = (_Float16)v1[2]; h[7] = (_Float16)v1[3];
        ((h8*)W16)[j] = h;
    }
    for (int e = i0; e < EE; e += gsz) atomicAdd(&deg[ei[EE + e]], 1);
}

// ---------------- pack weights into MFMA-B fragment layout (fp16) ----------------
__global__ __launch_bounds__(256)
void k_pack(const float* __restrict__ Wcomb, const float* __restrict__ W_c1,
            const float* __restrict__ W_c2, const float* __restrict__ W_f1,
            const float* __restrict__ b_node, const float* __restrict__ b_c1,
            const float* __restrict__ b_c2, _Float16* __restrict__ pW,
            float* __restrict__ bB) {
    const int tid = threadIdx.x;
    if (blockIdx.x == 80) {  // combined phase-B bias: b_c1+b_c2+b_node@(I+W_c2)
        int c = tid;
        if (c < HH) {
            float a = 0.f;
            for (int k = 0; k < HH; ++k) a += b_node[k] * W_c2[k * HH + c];
            bB[c] = a + b_node[c] + b_c1[c] + b_c2[c];
        }
        return;
    }
    const int unit = blockIdx.x * 4 + (tid >> 6);
    const int lane = tid & 63, lm = lane & 15, lg = lane >> 4;
    const float* Ws;
    bool addI;
    int u = unit;
    if (u < 64)       { Ws = Wcomb; addI = false; }
    else if (u < 192) { Ws = W_c1;  addI = true;  u -= 64; }
    else              { Ws = W_f1;  addI = false; u -= 192; }
    const int kb = u >> 4, nb = u & 15;
    h8 hv;
#pragma unroll
    for (int j = 0; j < 8; ++j) {
        int kr = kb * 32 + lg * 8 + j;
        int col = nb * 16 + lm;
        float v = Ws[kr * HH + col];
        if (addI && kr == col) v += 1.f;
        hv[j] = (_Float16)v;
    }
    *(h8*)(pW + (size_t)unit * 512 + lane * 8) = hv;
}

// ---------------- scan (2 kernels: per-block scan; fixup+btail with inline bucket prefix) ----------------
__global__ __launch_bounds__(256)
void k_scan1(const int* __restrict__ deg, int* __restrict__ rowptr, int* __restrict__ bsums) {
    __shared__ int t[256];
    const int tid = threadIdx.x;
    int i = blockIdx.x * 256 + tid;
    int v = (i < NN) ? deg[i] : 0;
    t[tid] = v;
    __syncthreads();
#pragma unroll
    for (int off = 1; off < 256; off <<= 1) {
        int u = (tid >= off) ? t[tid - off] : 0;
        __syncthreads();
        t[tid] += u;
        __syncthreads();
    }
    if (i < NN) rowptr[i] = t[tid] - v;
    if (tid == 255) bsums[blockIdx.x] = t[tid];
}
__global__ __launch_bounds__(256)
void k_scan3(int* __restrict__ rowptr, const int* __restrict__ bsums, int* __restrict__ btail) {
    __shared__ int t[256];
    const int tid = threadIdx.x;
    const int b = blockIdx.x;
    // exclusive prefix of bsums up to b, via tree reduce
    t[tid] = (tid < b) ? bsums[tid] : 0;
    __syncthreads();
#pragma unroll
    for (int off = 128; off > 0; off >>= 1) {
        if (tid < off) t[tid] += t[tid + off];
        __syncthreads();
    }
    const int pref = t[0];
    __syncthreads();
    int i = b * 256 + tid;
    if (i < NN) {
        int r = rowptr[i] + pref;
        rowptr[i] = r;
        if ((i & 255) == 0) btail[i >> 8] = r;  // bucket write cursor = bucket base
    }
    if (i == 0) rowptr[NN] = EE;
}

// ---------------- phase A: LDS-staged coarse binning into tmp (uint2 {src|w, dst}) ----------------
__global__ __launch_bounds__(256)
void k_binA(const int* __restrict__ ei, const float* __restrict__ ew,
            int* __restrict__ btail, uint2* __restrict__ tmp) {
    __shared__ int lcnt[NBUCK], lpre[NBUCK], lbase[NBUCK], lcnt2[NBUCK];
    __shared__ int t[256];
    __shared__ uint2 staged[CHK];
    __shared__ unsigned char bslot[CHK];
    const int tid = threadIdx.x;
    const int e0 = blockIdx.x * CHK;
    const int n = min(CHK, EE - e0);
    for (int i = tid; i < NBUCK; i += 256) { lcnt[i] = 0; lcnt2[i] = 0; }
    __syncthreads();
    for (int i = tid; i < n; i += 256) {
        int d = ei[EE + e0 + i];
        atomicAdd(&lcnt[d >> 8], 1);
    }
    __syncthreads();
    {
        int v = (tid < NBUCK) ? lcnt[tid] : 0;
        t[tid] = v;
        __syncthreads();
#pragma unroll
        for (int off = 1; off < 256; off <<= 1) {
            int u = (tid >= off) ? t[tid - off] : 0;
            __syncthreads();
            t[tid] += u;
            __syncthreads();
        }
        if (tid < NBUCK) lpre[tid] = t[tid] - v;
    }
    __syncthreads();
    if (tid < NBUCK && lcnt[tid] > 0)
        lbase[tid] = atomicAdd(&btail[tid], lcnt[tid]);
    __syncthreads();
    for (int i = tid; i < n; i += 256) {
        int e = e0 + i;
        int d = ei[EE + e];
        int b = d >> 8;
        _Float16 hw = (_Float16)ew[e];
        unsigned short hwb = *(unsigned short*)&hw;
        unsigned int lo = (unsigned int)ei[e] | ((unsigned int)hwb << 16);
        int slot = lpre[b] + atomicAdd(&lcnt2[b], 1);
        uint2 v;
        v.x = lo;
        v.y = (unsigned int)d;
        staged[slot] = v;
        bslot[slot] = (unsigned char)b;
    }
    __syncthreads();
    for (int s = tid; s < n; s += 256) {
        int b = bslot[s];
        tmp[lbase[b] + (s - lpre[b])] = staged[s];  // coalesced runs per bucket
    }
}

// ---------------- phase B: exact per-node CSR sort within each bucket -> esw ----------------
__global__ __launch_bounds__(256)
void k_binB(const int* __restrict__ rowptr, const uint2* __restrict__ tmp,
            unsigned int* __restrict__ esw) {
    __shared__ int lpos[256];
    __shared__ unsigned int sout[BCAP];
    const int tid = threadIdx.x;
    const int b = blockIdx.x;
    const int nb0 = b * 256;
    const int nEnd = min(nb0 + 256, NN);
    const int base = rowptr[nb0];
    const int cnt = rowptr[nEnd] - base;
    lpos[tid] = (nb0 + tid < nEnd) ? rowptr[nb0 + tid] - base : 0;
    __syncthreads();
    if (cnt <= BCAP) {
        for (int i = tid; i < cnt; i += 256) {
            uint2 v = tmp[base + i];
            int dr = (int)v.y - nb0;
            int p = atomicAdd(&lpos[dr], 1);
            sout[p] = v.x;
        }
        __syncthreads();
        for (int s = tid; s < cnt; s += 256) esw[base + s] = sout[s];  // coalesced, single XCD
    } else {
        for (int i = tid; i < cnt; i += 256) {
            uint2 v = tmp[base + i];
            int dr = (int)v.y - nb0;
            int p = atomicAdd(&lpos[dr], 1);
            esw[base + p] = v.x;
        }
    }
}

// ---------------- gather-accumulate: one wave per node, unroll 8 + masked tail ----------------
__global__ __launch_bounds__(256)
void k_gather(const int* __restrict__ rowptr, const unsigned int* __restrict__ esw,
              const _Float16* __restrict__ W16, const float* __restrict__ b_edge,
              _Float16* __restrict__ outHA) {
    const int wave = threadIdx.x >> 6;
    const int lane = threadIdx.x & 63;
    const int node = blockIdx.x * 4 + wave;
    if (node >= NN) return;
    int e = rowptr[node];
    const int end = rowptr[node + 1];
    const int c0 = lane * 4;
    f4 acc0 = {0.f, 0.f, 0.f, 0.f}, acc1 = {0.f, 0.f, 0.f, 0.f};
    for (; e + 7 < end; e += 8) {
        unsigned int v[8];
        h4 r[8];
#pragma unroll
        for (int j = 0; j < 8; ++j) v[j] = esw[e + j];
#pragma unroll
        for (int j = 0; j < 8; ++j)
            r[j] = *(const h4*)(W16 + (size_t)(v[j] & 0xFFFF) * HH + c0);
#pragma unroll
        for (int j = 0; j < 8; j += 2) {
            unsigned short b0 = (unsigned short)(v[j] >> 16);
            unsigned short b1 = (unsigned short)(v[j + 1] >> 16);
            float w0 = (float)*(_Float16*)&b0;
            float w1 = (float)*(_Float16*)&b1;
            f4 f0 = {(float)r[j][0], (float)r[j][1], (float)r[j][2], (float)r[j][3]};
            f4 f1 = {(float)r[j + 1][0], (float)r[j + 1][1], (float)r[j + 1][2], (float)r[j + 1][3]};
            acc0 += w0 * f0;
            acc1 += w1 * f1;
        }
    }
    if (e < end) {
        const int rem = end - e;
        unsigned int v[8];
        h4 r[8];
#pragma unroll
        for (int j = 0; j < 8; ++j) v[j] = esw[(j < rem) ? (e + j) : e];
#pragma unroll
        for (int j = 0; j < 8; ++j)
            r[j] = *(const h4*)(W16 + (size_t)(v[j] & 0xFFFF) * HH + c0);
#pragma unroll
        for (int j = 0; j < 8; j += 2) {
            unsigned short b0 = (unsigned short)(v[j] >> 16);
            unsigned short b1 = (unsigned short)(v[j + 1] >> 16);
            float w0 = (j < rem) ? (float)*(_Float16*)&b0 : 0.f;
            float w1 = (j + 1 < rem) ? (float)*(_Float16*)&b1 : 0.f;
            f4 f0 = {(float)r[j][0], (float)r[j][1], (float)r[j][2], (float)r[j][3]};
            f4 f1 = {(float)r[j + 1][0], (float)r[j + 1][1], (float)r[j + 1][2], (float)r[j + 1][3]};
            acc0 += w0 * f0;
            acc1 += w1 * f1;
        }
    }
    f4 b = *(const f4*)(b_edge + c0);
    f4 acc = acc0 + acc1 + b;
    h4 hv;
    hv[0] = (_Float16)acc[0]; hv[1] = (_Float16)acc[1];
    hv[2] = (_Float16)acc[2]; hv[3] = (_Float16)acc[3];
    *(h4*)(outHA + (size_t)node * HH + c0) = hv;
}

// ---------------- fused B+C: h = relu( relu(h_a@(I+Wc1) + x@Wcomb + bB) @ W_f1 + b_f1 ) + BN stats ----------------
__global__ __launch_bounds__(512)
void k_gemmBC(const float* __restrict__ x, const _Float16* __restrict__ A1,
              const _Float16* __restrict__ pW, const float* __restrict__ bB,
              const float* __restrict__ b_f1, _Float16* __restrict__ H,
              float* __restrict__ stats) {
    __shared__ __align__(16) char sm[40960];
    const int tid = threadIdx.x;
    const int w = tid >> 6, l = tid & 63;
    const int lm = l & 15, lg = l >> 4;
    const int rx = tid >> 4, sx = tid & 15;

    h8 w1[8][2], wc[4][2], wf[8][2];
#pragma unroll
    for (int kb = 0; kb < 8; ++kb)
#pragma unroll
        for (int n = 0; n < 2; ++n) {
            w1[kb][n] = *(const h8*)(pW + OFF_C1 + (size_t)(kb * 16 + w * 2 + n) * 512 + l * 8);
            wf[kb][n] = *(const h8*)(pW + OFF_F1 + (size_t)(kb * 16 + w * 2 + n) * 512 + l * 8);
        }
#pragma unroll
    for (int kb = 0; kb < 4; ++kb)
#pragma unroll
        for (int n = 0; n < 2; ++n)
            wc[kb][n] = *(const h8*)(pW + OFF_NODE + (size_t)(kb * 16 + w * 2 + n) * 512 + l * 8);

    float bBreg[2], bFreg[2];
#pragma unroll
    for (int n = 0; n < 2; ++n) {
        bBreg[n] = bB[w * 32 + n * 16 + lm];
        bFreg[n] = b_f1[w * 32 + n * 16 + lm];
    }
    float sS[2] = {0.f, 0.f}, sQ[2] = {0.f, 0.f};

    const int NT = (NN + 31) / 32;
    f4 pXa, pXb;
    int4 p1[2];
    int t = blockIdx.x;
    {
        int grow = t * 32 + rx;
        const f4 zf = {0.f, 0.f, 0.f, 0.f};
        pXa = (grow < NN) ? *(const f4*)(x + (size_t)grow * FF + sx * 8) : zf;
        pXb = (grow < NN) ? *(const f4*)(x + (size_t)grow * FF + sx * 8 + 4) : zf;
#pragma unroll
        for (int j = 0; j < 2; ++j) {
            int unit = tid * 2 + j;
            int r = unit >> 5, s = unit & 31;
            int g2 = t * 32 + r;
            int4 z = {0, 0, 0, 0};
            p1[j] = (g2 < NN) ? *(const int4*)(A1 + (size_t)g2 * HH + s * 8) : z;
        }
    }

    for (; t < NT; t += gridDim.x) {
        __syncthreads();  // b0
        {
            h8 hx;
            hx[0] = (_Float16)pXa[0]; hx[1] = (_Float16)pXa[1];
            hx[2] = (_Float16)pXa[2]; hx[3] = (_Float16)pXa[3];
            hx[4] = (_Float16)pXb[0]; hx[5] = (_Float16)pXb[1];
            hx[6] = (_Float16)pXb[2]; hx[7] = (_Float16)pXb[3];
            *(int4*)(sm + rx * 256 + SWZ(rx, sx * 16)) = *(int4*)&hx;
        }
#pragma unroll
        for (int j = 0; j < 2; ++j) {
            int unit = tid * 2 + j;
            int r = unit >> 5, s = unit & 31;
            *(int4*)(sm + 8192 + r * 512 + SWZ(r, s * 16)) = p1[j];
        }
        int tn = t + gridDim.x;
        if (tn < NT) {
            int grow = tn * 32 + rx;
            const f4 zf = {0.f, 0.f, 0.f, 0.f};
            pXa = (grow < NN) ? *(const f4*)(x + (size_t)grow * FF + sx * 8) : zf;
            pXb = (grow < NN) ? *(const f4*)(x + (size_t)grow * FF + sx * 8 + 4) : zf;
#pragma unroll
            for (int j = 0; j < 2; ++j) {
                int unit = tid * 2 + j;
                int r = unit >> 5, s = unit & 31;
                int g2 = tn * 32 + r;
                int4 z = {0, 0, 0, 0};
                p1[j] = (g2 < NN) ? *(const int4*)(A1 + (size_t)g2 * HH + s * 8) : z;
            }
        }
        __syncthreads();  // b1

        // ---- stage B
        f4 acc[2][2];
        const f4 z4 = {0.f, 0.f, 0.f, 0.f};
#pragma unroll
        for (int rf = 0; rf < 2; ++rf)
#pragma unroll
            for (int n = 0; n < 2; ++n) acc[rf][n] = z4;

#pragma unroll
        for (int kb = 0; kb < 8; ++kb) {
            h8 a0 = *(const h8*)(sm + 8192 + lm * 512 + SWZ(lm, kb * 64 + lg * 16));
            h8 a1 = *(const h8*)(sm + 8192 + (16 + lm) * 512 + SWZ(16 + lm, kb * 64 + lg * 16));
#pragma unroll
            for (int n = 0; n < 2; ++n) {
                acc[0][n] = __builtin_amdgcn_mfma_f32_16x16x32_f16(a0, w1[kb][n], acc[0][n], 0, 0, 0);
                acc[1][n] = __builtin_amdgcn_mfma_f32_16x16x32_f16(a1, w1[kb][n], acc[1][n], 0, 0, 0);
            }
        }
#pragma unroll
        for (int kb = 0; kb < 4; ++kb) {
            h8 a0 = *(const h8*)(sm + lm * 256 + SWZ(lm, kb * 64 + lg * 16));
            h8 a1 = *(const h8*)(sm + (16 + lm) * 256 + SWZ(16 + lm, kb * 64 + lg * 16));
#pragma unroll
            for (int n = 0; n < 2; ++n) {
                acc[0][n] = __builtin_amdgcn_mfma_f32_16x16x32_f16(a0, wc[kb][n], acc[0][n], 0, 0, 0);
                acc[1][n] = __builtin_amdgcn_mfma_f32_16x16x32_f16(a1, wc[kb][n], acc[1][n], 0, 0, 0);
            }
        }
#pragma unroll
        for (int rf = 0; rf < 2; ++rf)
#pragma unroll
            for (int n = 0; n < 2; ++n) {
                int c2 = (w * 32 + n * 16 + lm) * 2;
#pragma unroll
                for (int q = 0; q < 4; ++q) {
                    int r = rf * 16 + lg * 4 + q;
                    float v = fmaxf(acc[rf][n][q] + bBreg[n], 0.f);
                    *(_Float16*)(sm + 24576 + r * 512 + SWZ(r, c2)) = (_Float16)v;
                }
            }
        __syncthreads();  // b2

        // ---- stage C
#pragma unroll
        for (int rf = 0; rf < 2; ++rf)
#pragma unroll
            for (int n = 0; n < 2; ++n) acc[rf][n] = z4;

#pragma unroll
        for (int kb = 0; kb < 8; ++kb) {
            h8 a0 = *(const h8*)(sm + 24576 + lm * 512 + SWZ(lm, kb * 64 + lg * 16));
            h8 a1 = *(const h8*)(sm + 24576 + (16 + lm) * 512 + SWZ(16 + lm, kb * 64 + lg * 16));
#pragma unroll
            for (int n = 0; n < 2; ++n) {
                acc[0][n] = __builtin_amdgcn_mfma_f32_16x16x32_f16(a0, wf[kb][n], acc[0][n], 0, 0, 0);
                acc[1][n] = __builtin_amdgcn_mfma_f32_16x16x32_f16(a1, wf[kb][n], acc[1][n], 0, 0, 0);
            }
        }

        const int row0 = t * 32;
#pragma unroll
        for (int rf = 0; rf < 2; ++rf)
#pragma unroll
            for (int n = 0; n < 2; ++n) {
                const int col = w * 32 + n * 16 + lm;
#pragma unroll
                for (int q = 0; q < 4; ++q) {
                    int grow = row0 + rf * 16 + lg * 4 + q;
                    if (grow < NN) {
                        float v = fmaxf(acc[rf][n][q] + bFreg[n], 0.f);
                        sS[n] += v;
                        sQ[n] += v * v;
                        H[(size_t)grow * HH + col] = (_Float16)v;
                    }
                }
            }
    }

#pragma unroll
    for (int n = 0; n < 2; ++n) {
        float s = sS[n];
        s += __shfl_xor(s, 16); s += __shfl_xor(s, 32);
        float q = sQ[n];
        q += __shfl_xor(q, 16); q += __shfl_xor(q, 32);
        if (lg == 0) {
            atomicAdd(&stats[w * 32 + n * 16 + lm], s);
            atomicAdd(&stats[HH + w * 32 + n * 16 + lm], q);
        }
    }
}

// ---------------- BN fold + pack final weights into MFMA-B fragments ----------------
__global__ __launch_bounds__(256)
void k_bnprep(const float* __restrict__ stats, const float* __restrict__ gamma,
              const float* __restrict__ beta, const float* __restrict__ W_f2,
              const float* __restrict__ b_f2, _Float16* __restrict__ pWf,
              float* __restrict__ bfold) {
    __shared__ float sh[HH];
    __shared__ float ssc[HH];
    const int tid = threadIdx.x;
    const float invN = 1.0f / (float)NN;
    {
        float mu = stats[tid] * invN;
        float var = stats[HH + tid] * invN - mu * mu;
        float scale = gamma[tid] * rsqrtf(var + BN_EPS);
        sh[tid] = beta[tid] - mu * scale;
        ssc[tid] = scale;
    }
    __syncthreads();
    if (tid < CC) {
        float b = b_f2[tid];
        for (int k = 0; k < HH; ++k) b += sh[k] * W_f2[k * CC + tid];
        bfold[tid] = b;
    }
    const int w = tid >> 6, l = tid & 63;
    const int lm = l & 15, lg = l >> 4;
#pragma unroll
    for (int i = 0; i < 6; ++i) {
        int u = w + i * 4;  // 0..23
        int kb = u / 3, nb = u % 3;
        h8 hv;
#pragma unroll
        for (int j = 0; j < 8; ++j) {
            int k = kb * 32 + lg * 8 + j;
            int c = nb * 16 + lm;
            float v = (c < CC) ? ssc[k] * W_f2[k * CC + c] : 0.f;
            hv[j] = (_Float16)v;
        }
        *(h8*)(pWf + (size_t)u * 512 + l * 8) = hv;
    }
}

// ---------------- final via MFMA: out = h @ (scale*W_f2) + bfold ----------------
__global__ __launch_bounds__(256)
void k_finalM(const _Float16* __restrict__ h, const _Float16* __restrict__ pWf,
              const float* __restrict__ bfold, float* __restrict__ out) {
    __shared__ __align__(16) char sA[64 * 512];
    const int tid = threadIdx.x;
    const int w = tid >> 6, l = tid & 63;
    const int lm = l & 15, lg = l >> 4;

    h8 wreg[8][3];
#pragma unroll
    for (int kb = 0; kb < 8; ++kb)
#pragma unroll
        for (int nb = 0; nb < 3; ++nb)
            wreg[kb][nb] = *(const h8*)(pWf + (size_t)(kb * 3 + nb) * 512 + l * 8);

    const int row0 = blockIdx.x * 64;
#pragma unroll
    for (int j = 0; j < 8; ++j) {
        int unit = tid * 8 + j;
        int r = unit >> 5, s = unit & 31;
        int grow = row0 + r;
        int4 z = {0, 0, 0, 0};
        int4 v = (grow < NN) ? *(const int4*)(h + (size_t)grow * HH + s * 8) : z;
        *(int4*)(sA + r * 512 + SWZ(r, s * 16)) = v;
    }
    __syncthreads();

    f4 acc[3];
    const f4 z4 = {0.f, 0.f, 0.f, 0.f};
#pragma unroll
    for (int nb = 0; nb < 3; ++nb) acc[nb] = z4;

    const int ar = w * 16 + lm;
#pragma unroll
    for (int kb = 0; kb < 8; ++kb) {
        h8 a = *(const h8*)(sA + ar * 512 + SWZ(ar, kb * 64 + lg * 16));
#pragma unroll
        for (int nb = 0; nb < 3; ++nb)
            acc[nb] = __builtin_amdgcn_mfma_f32_16x16x32_f16(a, wreg[kb][nb], acc[nb], 0, 0, 0);
    }

#pragma unroll
    for (int nb = 0; nb < 3; ++nb) {
        int col = nb * 16 + lm;
        if (col < CC) {
            float bb = bfold[col];
#pragma unroll
            for (int q = 0; q < 4; ++q) {
                int grow = row0 + w * 16 + lg * 4 + q;
                if (grow < NN) out[(size_t)grow * CC + col] = acc[nb][q] + bb;
            }
        }
    }
}

extern "C" void kernel_launch(void* const* d_in, const int* in_sizes, int n_in,
                              void* d_out, int out_size, void* d_ws, size_t ws_size,
                              hipStream_t stream) {
    const float* x      = (const float*)d_in[0];
    const int*   ei     = (const int*)d_in[1];
    const float* ew     = (const float*)d_in[2];
    const float* W_edge = (const float*)d_in[3];
    const float* b_edge = (const float*)d_in[4];
    const float* W_node = (const float*)d_in[5];
    const float* b_node = (const float*)d_in[6];
    const float* W_c1   = (const float*)d_in[7];
    const float* b_c1   = (const float*)d_in[8];
    const float* W_c2   = (const float*)d_in[9];
    const float* b_c2   = (const float*)d_in[10];
    const float* W_f1   = (const float*)d_in[11];
    const float* b_f1   = (const float*)d_in[12];
    const float* gamma  = (const float*)d_in[13];
    const float* beta   = (const float*)d_in[14];
    const float* W_f2   = (const float*)d_in[15];
    const float* b_f2   = (const float*)d_in[16];
    float* out = (float*)d_out;

    const size_t NNH = (size_t)NN * HH;
    _Float16* bufA = (_Float16*)d_ws;            // h_a
    _Float16* bufH = bufA + NNH;                 // h
    _Float16* W16  = bufH + NNH;                 // fp16 W_edge
    unsigned int* esw = (unsigned int*)(W16 + NNH);  // E packed 4B
    float* stats   = (float*)(esw + EE);         // 512
    float* bB      = stats + 2 * HH;             // 256
    float* bfold   = bB + HH;                    // 64
    _Float16* pWf  = (_Float16*)(bfold + 64);    // 24*512
    _Float16* pW   = pWf + 24 * 512;             // PW_HALVES
    float* Wcomb   = (float*)(pW + PW_HALVES);   // 128*256 fp32
    uint2* tmp     = (uint2*)(Wcomb + FF * HH);  // E uint2 (8B-aligned)
    int* deg       = (int*)(tmp + EE);           // N
    int* rowptr    = deg + NN;                   // N+1
    int* btail     = rowptr + NN + 1;            // NBUCK
    int* bsums     = btail + NBUCK;              // 256

    hipMemsetAsync(stats, 0, 2 * HH * sizeof(float), stream);
    hipMemsetAsync(deg, 0, NN * sizeof(int), stream);

    k_wcomb<<<8, 256, 0, stream>>>(W_node, W_c2, Wcomb);
    k_prep<<<2048, 256, 0, stream>>>(W_edge, W16, ei, deg);
    k_pack<<<81, 256, 0, stream>>>(Wcomb, W_c1, W_c2, W_f1, b_node, b_c1, b_c2, pW, bB);
    k_scan1<<<196, 256, 0, stream>>>(deg, rowptr, bsums);
    k_scan3<<<196, 256, 0, stream>>>(rowptr, bsums, btail);
    k_binA<<<(EE + CHK - 1) / CHK, 256, 0, stream>>>(ei, ew, btail, tmp);
    k_binB<<<NBUCK, 256, 0, stream>>>(rowptr, tmp, esw);
    k_gather<<<12500, 256, 0, stream>>>(rowptr, esw, W16, b_edge, bufA);

    // fused B+C: h = relu( relu(h_a@(I+Wc1) + x@Wcomb + bB) @ W_f1 + b_f1 ) + stats
    k_gemmBC<<<256, 512, 0, stream>>>(x, bufA, pW, bB, b_f1, bufH, stats);

    k_bnprep<<<1, 256, 0, stream>>>(stats, gamma, beta, W_f2, b_f2, pWf, bfold);
    k_finalM<<<(NN + 63) / 64, 256, 0, stream>>>(bufH, pWf, bfold, out);
}

// Round 15
// 214.741 us; speedup vs baseline: 1.3029x; 1.1073x over previous
//
#include <hip/hip_runtime.h>

#define NN 50000
#define EE 800000
#define FF 128
#define HH 256
#define CC 40
#define BN_EPS 1e-5f
#define NBUCK 196
#define CHK 3200
#define BCAP 6144

typedef float f4 __attribute__((ext_vector_type(4)));
typedef float f2 __attribute__((ext_vector_type(2)));
typedef _Float16 h8 __attribute__((ext_vector_type(8)));
typedef _Float16 h4 __attribute__((ext_vector_type(4)));

// packed units (512 halves each): [0,64) Wcomb (K=128), [64,192) I+Wc1 (K=256), [192,320) W_f1 (K=256)
#define OFF_NODE 0
#define OFF_C1   32768
#define OFF_F1   98304
#define PW_HALVES 163840

#define SWZ(row, c2) ((c2) ^ (((row) & 7) << 4))

// ---------------- Wcomb = Wn + Wn@Wc2  (fp32, coalesced) ----------------
__global__ __launch_bounds__(256)
void k_wcomb(const float* __restrict__ Wn, const float* __restrict__ Wc2,
             float* __restrict__ Wcomb) {
    __shared__ float WnL[16][256];
    const int c = threadIdx.x;
    const int r0 = blockIdx.x * 16;
    for (int i = threadIdx.x; i < 16 * 256; i += 256)
        WnL[i >> 8][i & 255] = Wn[(r0 + (i >> 8)) * HH + (i & 255)];
    __syncthreads();
    float acc[16];
#pragma unroll
    for (int r = 0; r < 16; ++r) acc[r] = WnL[r][c];
    for (int k = 0; k < 256; ++k) {
        float wv = Wc2[k * HH + c];
#pragma unroll
        for (int r = 0; r < 16; ++r) acc[r] += WnL[r][k] * wv;
    }
#pragma unroll
    for (int r = 0; r < 16; ++r) Wcomb[(r0 + r) * HH + c] = acc[r];
}

// ---------------- prep: W_edge -> fp8 e4m3 (x256 scale)  +  histogram of dst ----------------
__global__ __launch_bounds__(256)
void k_prep(const float* __restrict__ W, unsigned char* __restrict__ W8,
            const int* __restrict__ ei, int* __restrict__ deg) {
    const int gsz = gridDim.x * blockDim.x;
    const int i0 = blockIdx.x * blockDim.x + threadIdx.x;
    for (int j = i0; j < NN * HH / 8; j += gsz) {
        f4 v0 = ((const f4*)W)[j * 2];
        f4 v1 = ((const f4*)W)[j * 2 + 1];
        int p0 = 0, p1 = 0;
        p0 = __builtin_amdgcn_cvt_pk_fp8_f32(v0[0] * 256.f, v0[1] * 256.f, p0, false);
        p0 = __builtin_amdgcn_cvt_pk_fp8_f32(v0[2] * 256.f, v0[3] * 256.f, p0, true);
        p1 = __builtin_amdgcn_cvt_pk_fp8_f32(v1[0] * 256.f, v1[1] * 256.f, p1, false);
        p1 = __builtin_amdgcn_cvt_pk_fp8_f32(v1[2] * 256.f, v1[3] * 256.f, p1, true);
        uint2 u;
        u.x = (unsigned int)p0;
        u.y = (unsigned int)p1;
        ((uint2*)W8)[j] = u;
    }
    for (int e = i0; e < EE; e += gsz) atomicAdd(&deg[ei[EE + e]], 1);
}

// ---------------- pack weights into MFMA-B fragment layout (fp16) ----------------
__global__ __launch_bounds__(256)
void k_pack(const float* __restrict__ Wcomb, const float* __restrict__ W_c1,
            const float* __restrict__ W_c2, const float* __restrict__ W_f1,
            const float* __restrict__ b_node, const float* __restrict__ b_c1,
            const float* __restrict__ b_c2, _Float16* __restrict__ pW,
            float* __restrict__ bB) {
    const int tid = threadIdx.x;
    if (blockIdx.x == 80) {  // combined phase-B bias: b_c1+b_c2+b_node@(I+W_c2)
        int c = tid;
        if (c < HH) {
            float a = 0.f;
            for (int k = 0; k < HH; ++k) a += b_node[k] * W_c2[k * HH + c];
            bB[c] = a + b_node[c] + b_c1[c] + b_c2[c];
        }
        return;
    }
    const int unit = blockIdx.x * 4 + (tid >> 6);
    const int lane = tid & 63, lm = lane & 15, lg = lane >> 4;
    const float* Ws;
    bool addI;
    int u = unit;
    if (u < 64)       { Ws = Wcomb; addI = false; }
    else if (u < 192) { Ws = W_c1;  addI = true;  u -= 64; }
    else              { Ws = W_f1;  addI = false; u -= 192; }
    const int kb = u >> 4, nb = u & 15;
    h8 hv;
#pragma unroll
    for (int j = 0; j < 8; ++j) {
        int kr = kb * 32 + lg * 8 + j;
        int col = nb * 16 + lm;
        float v = Ws[kr * HH + col];
        if (addI && kr == col) v += 1.f;
        hv[j] = (_Float16)v;
    }
    *(h8*)(pW + (size_t)unit * 512 + lane * 8) = hv;
}

// ---------------- scan ----------------
__global__ __launch_bounds__(256)
void k_scan1(const int* __restrict__ deg, int* __restrict__ rowptr, int* __restrict__ bsums) {
    __shared__ int t[256];
    const int tid = threadIdx.x;
    int i = blockIdx.x * 256 + tid;
    int v = (i < NN) ? deg[i] : 0;
    t[tid] = v;
    __syncthreads();
#pragma unroll
    for (int off = 1; off < 256; off <<= 1) {
        int u = (tid >= off) ? t[tid - off] : 0;
        __syncthreads();
        t[tid] += u;
        __syncthreads();
    }
    if (i < NN) rowptr[i] = t[tid] - v;
    if (tid == 255) bsums[blockIdx.x] = t[tid];
}
__global__ __launch_bounds__(256)
void k_scan3(int* __restrict__ rowptr, const int* __restrict__ bsums, int* __restrict__ btail) {
    __shared__ int t[256];
    const int tid = threadIdx.x;
    const int b = blockIdx.x;
    t[tid] = (tid < b) ? bsums[tid] : 0;
    __syncthreads();
#pragma unroll
    for (int off = 128; off > 0; off >>= 1) {
        if (tid < off) t[tid] += t[tid + off];
        __syncthreads();
    }
    const int pref = t[0];
    __syncthreads();
    int i = b * 256 + tid;
    if (i < NN) {
        int r = rowptr[i] + pref;
        rowptr[i] = r;
        if ((i & 255) == 0) btail[i >> 8] = r;
    }
    if (i == 0) rowptr[NN] = EE;
}

// ---------------- phase A: LDS-staged coarse binning into tmp (uint2 {src|w, dst}) ----------------
__global__ __launch_bounds__(256)
void k_binA(const int* __restrict__ ei, const float* __restrict__ ew,
            int* __restrict__ btail, uint2* __restrict__ tmp) {
    __shared__ int lcnt[NBUCK], lpre[NBUCK], lbase[NBUCK], lcnt2[NBUCK];
    __shared__ int t[256];
    __shared__ uint2 staged[CHK];
    __shared__ unsigned char bslot[CHK];
    const int tid = threadIdx.x;
    const int e0 = blockIdx.x * CHK;
    const int n = min(CHK, EE - e0);
    for (int i = tid; i < NBUCK; i += 256) { lcnt[i] = 0; lcnt2[i] = 0; }
    __syncthreads();
    for (int i = tid; i < n; i += 256) {
        int d = ei[EE + e0 + i];
        atomicAdd(&lcnt[d >> 8], 1);
    }
    __syncthreads();
    {
        int v = (tid < NBUCK) ? lcnt[tid] : 0;
        t[tid] = v;
        __syncthreads();
#pragma unroll
        for (int off = 1; off < 256; off <<= 1) {
            int u = (tid >= off) ? t[tid - off] : 0;
            __syncthreads();
            t[tid] += u;
            __syncthreads();
        }
        if (tid < NBUCK) lpre[tid] = t[tid] - v;
    }
    __syncthreads();
    if (tid < NBUCK && lcnt[tid] > 0)
        lbase[tid] = atomicAdd(&btail[tid], lcnt[tid]);
    __syncthreads();
    for (int i = tid; i < n; i += 256) {
        int e = e0 + i;
        int d = ei[EE + e];
        int b = d >> 8;
        _Float16 hw = (_Float16)ew[e];
        unsigned short hwb = *(unsigned short*)&hw;
        unsigned int lo = (unsigned int)ei[e] | ((unsigned int)hwb << 16);
        int slot = lpre[b] + atomicAdd(&lcnt2[b], 1);
        uint2 v;
        v.x = lo;
        v.y = (unsigned int)d;
        staged[slot] = v;
        bslot[slot] = (unsigned char)b;
    }
    __syncthreads();
    for (int s = tid; s < n; s += 256) {
        int b = bslot[s];
        tmp[lbase[b] + (s - lpre[b])] = staged[s];
    }
}

// ---------------- phase B: exact per-node CSR sort within each bucket -> esw ----------------
__global__ __launch_bounds__(256)
void k_binB(const int* __restrict__ rowptr, const uint2* __restrict__ tmp,
            unsigned int* __restrict__ esw) {
    __shared__ int lpos[256];
    __shared__ unsigned int sout[BCAP];
    const int tid = threadIdx.x;
    const int b = blockIdx.x;
    const int nb0 = b * 256;
    const int nEnd = min(nb0 + 256, NN);
    const int base = rowptr[nb0];
    const int cnt = rowptr[nEnd] - base;
    lpos[tid] = (nb0 + tid < nEnd) ? rowptr[nb0 + tid] - base : 0;
    __syncthreads();
    if (cnt <= BCAP) {
        for (int i = tid; i < cnt; i += 256) {
            uint2 v = tmp[base + i];
            int dr = (int)v.y - nb0;
            int p = atomicAdd(&lpos[dr], 1);
            sout[p] = v.x;
        }
        __syncthreads();
        for (int s = tid; s < cnt; s += 256) esw[base + s] = sout[s];
    } else {
        for (int i = tid; i < cnt; i += 256) {
            uint2 v = tmp[base + i];
            int dr = (int)v.y - nb0;
            int p = atomicAdd(&lpos[dr], 1);
            esw[base + p] = v.x;
        }
    }
}

// ---------------- gather-accumulate: fp8 table, one wave per node, unroll 8 + masked tail ----------------
__global__ __launch_bounds__(256)
void k_gather(const int* __restrict__ rowptr, const unsigned int* __restrict__ esw,
              const unsigned char* __restrict__ W8, const float* __restrict__ b_edge,
              _Float16* __restrict__ outHA) {
    const int wave = threadIdx.x >> 6;
    const int lane = threadIdx.x & 63;
    const int node = blockIdx.x * 4 + wave;
    if (node >= NN) return;
    int e = rowptr[node];
    const int end = rowptr[node + 1];
    const int c0 = lane * 4;  // fp8 element (=byte) offset
    f4 acc0 = {0.f, 0.f, 0.f, 0.f}, acc1 = {0.f, 0.f, 0.f, 0.f};
    for (; e + 7 < end; e += 8) {
        unsigned int v[8];
        unsigned int rw[8];
#pragma unroll
        for (int j = 0; j < 8; ++j) v[j] = esw[e + j];
#pragma unroll
        for (int j = 0; j < 8; ++j)
            rw[j] = *(const unsigned int*)(W8 + (size_t)(v[j] & 0xFFFF) * HH + c0);
#pragma unroll
        for (int j = 0; j < 8; j += 2) {
            unsigned short b0 = (unsigned short)(v[j] >> 16);
            unsigned short b1 = (unsigned short)(v[j + 1] >> 16);
            float w0 = (float)*(_Float16*)&b0;
            float w1 = (float)*(_Float16*)&b1;
            f2 l0 = __builtin_amdgcn_cvt_pk_f32_fp8((int)rw[j], false);
            f2 h0 = __builtin_amdgcn_cvt_pk_f32_fp8((int)rw[j], true);
            f2 l1 = __builtin_amdgcn_cvt_pk_f32_fp8((int)rw[j + 1], false);
            f2 h1 = __builtin_amdgcn_cvt_pk_f32_fp8((int)rw[j + 1], true);
            f4 f0 = {l0[0], l0[1], h0[0], h0[1]};
            f4 f1 = {l1[0], l1[1], h1[0], h1[1]};
            acc0 += w0 * f0;
            acc1 += w1 * f1;
        }
    }
    if (e < end) {
        const int rem = end - e;
        unsigned int v[8];
        unsigned int rw[8];
#pragma unroll
        for (int j = 0; j < 8; ++j) v[j] = esw[(j < rem) ? (e + j) : e];
#pragma unroll
        for (int j = 0; j < 8; ++j)
            rw[j] = *(const unsigned int*)(W8 + (size_t)(v[j] & 0xFFFF) * HH + c0);
#pragma unroll
        for (int j = 0; j < 8; j += 2) {
            unsigned short b0 = (unsigned short)(v[j] >> 16);
            unsigned short b1 = (unsigned short)(v[j + 1] >> 16);
            float w0 = (j < rem) ? (float)*(_Float16*)&b0 : 0.f;
            float w1 = (j + 1 < rem) ? (float)*(_Float16*)&b1 : 0.f;
            f2 l0 = __builtin_amdgcn_cvt_pk_f32_fp8((int)rw[j], false);
            f2 h0 = __builtin_amdgcn_cvt_pk_f32_fp8((int)rw[j], true);
            f2 l1 = __builtin_amdgcn_cvt_pk_f32_fp8((int)rw[j + 1], false);
            f2 h1 = __builtin_amdgcn_cvt_pk_f32_fp8((int)rw[j + 1], true);
            f4 f0 = {l0[0], l0[1], h0[0], h0[1]};
            f4 f1 = {l1[0], l1[1], h1[0], h1[1]};
            acc0 += w0 * f0;
            acc1 += w1 * f1;
        }
    }
    f4 b = *(const f4*)(b_edge + c0);
    f4 acc = (acc0 + acc1) * (1.f / 256.f) + b;
    h4 hv;
    hv[0] = (_Float16)acc[0]; hv[1] = (_Float16)acc[1];
    hv[2] = (_Float16)acc[2]; hv[3] = (_Float16)acc[3];
    *(h4*)(outHA + (size_t)node * HH + c0) = hv;
}

// ---------------- fused B+C: h = relu( relu(h_a@(I+Wc1) + x@Wcomb + bB) @ W_f1 + b_f1 ) + BN stats ----------------
__global__ __launch_bounds__(512)
void k_gemmBC(const float* __restrict__ x, const _Float16* __restrict__ A1,
              const _Float16* __restrict__ pW, const float* __restrict__ bB,
              const float* __restrict__ b_f1, _Float16* __restrict__ H,
              float* __restrict__ stats) {
    __shared__ __align__(16) char sm[40960];
    const int tid = threadIdx.x;
    const int w = tid >> 6, l = tid & 63;
    const int lm = l & 15, lg = l >> 4;
    const int rx = tid >> 4, sx = tid & 15;

    h8 w1[8][2], wc[4][2], wf[8][2];
#pragma unroll
    for (int kb = 0; kb < 8; ++kb)
#pragma unroll
        for (int n = 0; n < 2; ++n) {
            w1[kb][n] = *(const h8*)(pW + OFF_C1 + (size_t)(kb * 16 + w * 2 + n) * 512 + l * 8);
            wf[kb][n] = *(const h8*)(pW + OFF_F1 + (size_t)(kb * 16 + w * 2 + n) * 512 + l * 8);
        }
#pragma unroll
    for (int kb = 0; kb < 4; ++kb)
#pragma unroll
        for (int n = 0; n < 2; ++n)
            wc[kb][n] = *(const h8*)(pW + OFF_NODE + (size_t)(kb * 16 + w * 2 + n) * 512 + l * 8);

    float bBreg[2], bFreg[2];
#pragma unroll
    for (int n = 0; n < 2; ++n) {
        bBreg[n] = bB[w * 32 + n * 16 + lm];
        bFreg[n] = b_f1[w * 32 + n * 16 + lm];
    }
    float sS[2] = {0.f, 0.f}, sQ[2] = {0.f, 0.f};

    const int NT = (NN + 31) / 32;
    f4 pXa, pXb;
    int4 p1[2];
    int t = blockIdx.x;
    {
        int grow = t * 32 + rx;
        const f4 zf = {0.f, 0.f, 0.f, 0.f};
        pXa = (grow < NN) ? *(const f4*)(x + (size_t)grow * FF + sx * 8) : zf;
        pXb = (grow < NN) ? *(const f4*)(x + (size_t)grow * FF + sx * 8 + 4) : zf;
#pragma unroll
        for (int j = 0; j < 2; ++j) {
            int unit = tid * 2 + j;
            int r = unit >> 5, s = unit & 31;
            int g2 = t * 32 + r;
            int4 z = {0, 0, 0, 0};
            p1[j] = (g2 < NN) ? *(const int4*)(A1 + (size_t)g2 * HH + s * 8) : z;
        }
    }

    for (; t < NT; t += gridDim.x) {
        __syncthreads();  // b0
        {
            h8 hx;
            hx[0] = (_Float16)pXa[0]; hx[1] = (_Float16)pXa[1];
            hx[2] = (_Float16)pXa[2]; hx[3] = (_Float16)pXa[3];
            hx[4] = (_Float16)pXb[0]; hx[5] = (_Float16)pXb[1];
            hx[6] = (_Float16)pXb[2]; hx[7] = (_Float16)pXb[3];
            *(int4*)(sm + rx * 256 + SWZ(rx, sx * 16)) = *(int4*)&hx;
        }
#pragma unroll
        for (int j = 0; j < 2; ++j) {
            int unit = tid * 2 + j;
            int r = unit >> 5, s = unit & 31;
            *(int4*)(sm + 8192 + r * 512 + SWZ(r, s * 16)) = p1[j];
        }
        int tn = t + gridDim.x;
        if (tn < NT) {
            int grow = tn * 32 + rx;
            const f4 zf = {0.f, 0.f, 0.f, 0.f};
            pXa = (grow < NN) ? *(const f4*)(x + (size_t)grow * FF + sx * 8) : zf;
            pXb = (grow < NN) ? *(const f4*)(x + (size_t)grow * FF + sx * 8 + 4) : zf;
#pragma unroll
            for (int j = 0; j < 2; ++j) {
                int unit = tid * 2 + j;
                int r = unit >> 5, s = unit & 31;
                int g2 = tn * 32 + r;
                int4 z = {0, 0, 0, 0};
                p1[j] = (g2 < NN) ? *(const int4*)(A1 + (size_t)g2 * HH + s * 8) : z;
            }
        }
        __syncthreads();  // b1

        // ---- stage B
        f4 acc[2][2];
        const f4 z4 = {0.f, 0.f, 0.f, 0.f};
#pragma unroll
        for (int rf = 0; rf < 2; ++rf)
#pragma unroll
            for (int n = 0; n < 2; ++n) acc[rf][n] = z4;

#pragma unroll
        for (int kb = 0; kb < 8; ++kb) {
            h8 a0 = *(const h8*)(sm + 8192 + lm * 512 + SWZ(lm, kb * 64 + lg * 16));
            h8 a1 = *(const h8*)(sm + 8192 + (16 + lm) * 512 + SWZ(16 + lm, kb * 64 + lg * 16));
#pragma unroll
            for (int n = 0; n < 2; ++n) {
                acc[0][n] = __builtin_amdgcn_mfma_f32_16x16x32_f16(a0, w1[kb][n], acc[0][n], 0, 0, 0);
                acc[1][n] = __builtin_amdgcn_mfma_f32_16x16x32_f16(a1, w1[kb][n], acc[1][n], 0, 0, 0);
            }
        }
#pragma unroll
        for (int kb = 0; kb < 4; ++kb) {
            h8 a0 = *(const h8*)(sm + lm * 256 + SWZ(lm, kb * 64 + lg * 16));
            h8 a1 = *(const h8*)(sm + (16 + lm) * 256 + SWZ(16 + lm, kb * 64 + lg * 16));
#pragma unroll
            for (int n = 0; n < 2; ++n) {
                acc[0][n] = __builtin_amdgcn_mfma_f32_16x16x32_f16(a0, wc[kb][n], acc[0][n], 0, 0, 0);
                acc[1][n] = __builtin_amdgcn_mfma_f32_16x16x32_f16(a1, wc[kb][n], acc[1][n], 0, 0, 0);
            }
        }
#pragma unroll
        for (int rf = 0; rf < 2; ++rf)
#pragma unroll
            for (int n = 0; n < 2; ++n) {
                int c2 = (w * 32 + n * 16 + lm) * 2;
#pragma unroll
                for (int q = 0; q < 4; ++q) {
                    int r = rf * 16 + lg * 4 + q;
                    float v = fmaxf(acc[rf][n][q] + bBreg[n], 0.f);
                    *(_Float16*)(sm + 24576 + r * 512 + SWZ(r, c2)) = (_Float16)v;
                }
            }
        __syncthreads();  // b2

        // ---- stage C
#pragma unroll
        for (int rf = 0; rf < 2; ++rf)
#pragma unroll
            for (int n = 0; n < 2; ++n) acc[rf][n] = z4;

#pragma unroll
        for (int kb = 0; kb < 8; ++kb) {
            h8 a0 = *(const h8*)(sm + 24576 + lm * 512 + SWZ(lm, kb * 64 + lg * 16));
            h8 a1 = *(const h8*)(sm + 24576 + (16 + lm) * 512 + SWZ(16 + lm, kb * 64 + lg * 16));
#pragma unroll
            for (int n = 0; n < 2; ++n) {
                acc[0][n] = __builtin_amdgcn_mfma_f32_16x16x32_f16(a0, wf[kb][n], acc[0][n], 0, 0, 0);
                acc[1][n] = __builtin_amdgcn_mfma_f32_16x16x32_f16(a1, wf[kb][n], acc[1][n], 0, 0, 0);
            }
        }

        const int row0 = t * 32;
#pragma unroll
        for (int rf = 0; rf < 2; ++rf)
#pragma unroll
            for (int n = 0; n < 2; ++n) {
                const int col = w * 32 + n * 16 + lm;
#pragma unroll
                for (int q = 0; q < 4; ++q) {
                    int grow = row0 + rf * 16 + lg * 4 + q;
                    if (grow < NN) {
                        float v = fmaxf(acc[rf][n][q] + bFreg[n], 0.f);
                        sS[n] += v;
                        sQ[n] += v * v;
                        H[(size_t)grow * HH + col] = (_Float16)v;
                    }
                }
            }
    }

#pragma unroll
    for (int n = 0; n < 2; ++n) {
        float s = sS[n];
        s += __shfl_xor(s, 16); s += __shfl_xor(s, 32);
        float q = sQ[n];
        q += __shfl_xor(q, 16); q += __shfl_xor(q, 32);
        if (lg == 0) {
            atomicAdd(&stats[w * 32 + n * 16 + lm], s);
            atomicAdd(&stats[HH + w * 32 + n * 16 + lm], q);
        }
    }
}

// ---------------- BN fold + pack final weights into MFMA-B fragments ----------------
__global__ __launch_bounds__(256)
void k_bnprep(const float* __restrict__ stats, const float* __restrict__ gamma,
              const float* __restrict__ beta, const float* __restrict__ W_f2,
              const float* __restrict__ b_f2, _Float16* __restrict__ pWf,
              float* __restrict__ bfold) {
    __shared__ float sh[HH];
    __shared__ float ssc[HH];
    const int tid = threadIdx.x;
    const float invN = 1.0f / (float)NN;
    {
        float mu = stats[tid] * invN;
        float var = stats[HH + tid] * invN - mu * mu;
        float scale = gamma[tid] * rsqrtf(var + BN_EPS);
        sh[tid] = beta[tid] - mu * scale;
        ssc[tid] = scale;
    }
    __syncthreads();
    if (tid < CC) {
        float b = b_f2[tid];
        for (int k = 0; k < HH; ++k) b += sh[k] * W_f2[k * CC + tid];
        bfold[tid] = b;
    }
    const int w = tid >> 6, l = tid & 63;
    const int lm = l & 15, lg = l >> 4;
#pragma unroll
    for (int i = 0; i < 6; ++i) {
        int u = w + i * 4;  // 0..23
        int kb = u / 3, nb = u % 3;
        h8 hv;
#pragma unroll
        for (int j = 0; j < 8; ++j) {
            int k = kb * 32 + lg * 8 + j;
            int c = nb * 16 + lm;
            float v = (c < CC) ? ssc[k] * W_f2[k * CC + c] : 0.f;
            hv[j] = (_Float16)v;
        }
        *(h8*)(pWf + (size_t)u * 512 + l * 8) = hv;
    }
}

// ---------------- final via MFMA: out = h @ (scale*W_f2) + bfold ----------------
__global__ __launch_bounds__(256)
void k_finalM(const _Float16* __restrict__ h, const _Float16* __restrict__ pWf,
              const float* __restrict__ bfold, float* __restrict__ out) {
    __shared__ __align__(16) char sA[64 * 512];
    const int tid = threadIdx.x;
    const int w = tid >> 6, l = tid & 63;
    const int lm = l & 15, lg = l >> 4;

    h8 wreg[8][3];
#pragma unroll
    for (int kb = 0; kb < 8; ++kb)
#pragma unroll
        for (int nb = 0; nb < 3; ++nb)
            wreg[kb][nb] = *(const h8*)(pWf + (size_t)(kb * 3 + nb) * 512 + l * 8);

    const int row0 = blockIdx.x * 64;
#pragma unroll
    for (int j = 0; j < 8; ++j) {
        int unit = tid * 8 + j;
        int r = unit >> 5, s = unit & 31;
        int grow = row0 + r;
        int4 z = {0, 0, 0, 0};
        int4 v = (grow < NN) ? *(const int4*)(h + (size_t)grow * HH + s * 8) : z;
        *(int4*)(sA + r * 512 + SWZ(r, s * 16)) = v;
    }
    __syncthreads();

    f4 acc[3];
    const f4 z4 = {0.f, 0.f, 0.f, 0.f};
#pragma unroll
    for (int nb = 0; nb < 3; ++nb) acc[nb] = z4;

    const int ar = w * 16 + lm;
#pragma unroll
    for (int kb = 0; kb < 8; ++kb) {
        h8 a = *(const h8*)(sA + ar * 512 + SWZ(ar, kb * 64 + lg * 16));
#pragma unroll
        for (int nb = 0; nb < 3; ++nb)
            acc[nb] = __builtin_amdgcn_mfma_f32_16x16x32_f16(a, wreg[kb][nb], acc[nb], 0, 0, 0);
    }

#pragma unroll
    for (int nb = 0; nb < 3; ++nb) {
        int col = nb * 16 + lm;
        if (col < CC) {
            float bb = bfold[col];
#pragma unroll
            for (int q = 0; q < 4; ++q) {
                int grow = row0 + w * 16 + lg * 4 + q;
                if (grow < NN) out[(size_t)grow * CC + col] = acc[nb][q] + bb;
            }
        }
    }
}

extern "C" void kernel_launch(void* const* d_in, const int* in_sizes, int n_in,
                              void* d_out, int out_size, void* d_ws, size_t ws_size,
                              hipStream_t stream) {
    const float* x      = (const float*)d_in[0];
    const int*   ei     = (const int*)d_in[1];
    const float* ew     = (const float*)d_in[2];
    const float* W_edge = (const float*)d_in[3];
    const float* b_edge = (const float*)d_in[4];
    const float* W_node = (const float*)d_in[5];
    const float* b_node = (const float*)d_in[6];
    const float* W_c1   = (const float*)d_in[7];
    const float* b_c1   = (const float*)d_in[8];
    const float* W_c2   = (const float*)d_in[9];
    const float* b_c2   = (const float*)d_in[10];
    const float* W_f1   = (const float*)d_in[11];
    const float* b_f1   = (const float*)d_in[12];
    const float* gamma  = (const float*)d_in[13];
    const float* beta   = (const float*)d_in[14];
    const float* W_f2   = (const float*)d_in[15];
    const float* b_f2   = (const float*)d_in[16];
    float* out = (float*)d_out;

    const size_t NNH = (size_t)NN * HH;
    _Float16* bufA = (_Float16*)d_ws;            // h_a
    _Float16* bufH = bufA + NNH;                 // h
    unsigned char* W8 = (unsigned char*)(bufH + NNH);  // fp8 W_edge (x256), NNH bytes
    unsigned int* esw = (unsigned int*)(W8 + NNH);     // E packed 4B
    float* stats   = (float*)(esw + EE);         // 512
    float* bB      = stats + 2 * HH;             // 256
    float* bfold   = bB + HH;                    // 64
    _Float16* pWf  = (_Float16*)(bfold + 64);    // 24*512
    _Float16* pW   = pWf + 24 * 512;             // PW_HALVES
    float* Wcomb   = (float*)(pW + PW_HALVES);   // 128*256 fp32
    uint2* tmp     = (uint2*)(Wcomb + FF * HH);  // E uint2
    int* deg       = (int*)(tmp + EE);           // N
    int* rowptr    = deg + NN;                   // N+1
    int* btail     = rowptr + NN + 1;            // NBUCK
    int* bsums     = btail + NBUCK;              // 256

    hipMemsetAsync(stats, 0, 2 * HH * sizeof(float), stream);
    hipMemsetAsync(deg, 0, NN * sizeof(int), stream);

    k_wcomb<<<8, 256, 0, stream>>>(W_node, W_c2, Wcomb);
    k_prep<<<2048, 256, 0, stream>>>(W_edge, W8, ei, deg);
    k_pack<<<81, 256, 0, stream>>>(Wcomb, W_c1, W_c2, W_f1, b_node, b_c1, b_c2, pW, bB);
    k_scan1<<<196, 256, 0, stream>>>(deg, rowptr, bsums);
    k_scan3<<<196, 256, 0, stream>>>(rowptr, bsums, btail);
    k_binA<<<(EE + CHK - 1) / CHK, 256, 0, stream>>>(ei, ew, btail, tmp);
    k_binB<<<NBUCK, 256, 0, stream>>>(rowptr, tmp, esw);
    k_gather<<<12500, 256, 0, stream>>>(rowptr, esw, W8, b_edge, bufA);

    // fused B+C: h = relu( relu(h_a@(I+Wc1) + x@Wcomb + bB) @ W_f1 + b_f1 ) + stats
    k_gemmBC<<<256, 512, 0, stream>>>(x, bufA, pW, bB, b_f1, bufH, stats);

    k_bnprep<<<1, 256, 0, stream>>>(stats, gamma, beta, W_f2, b_f2, pWf, bfold);
    k_finalM<<<(NN + 63) / 64, 256, 0, stream>>>(bufH, pWf, bfold, out);
}

// Round 16
// 186.754 us; speedup vs baseline: 1.4982x; 1.1499x over previous
//
#include <hip/hip_runtime.h>

#define NN 50000
#define EE 800000
#define FF 128
#define HH 256
#define CC 40
#define BN_EPS 1e-5f
#define NBUCK 196
#define CHK 3200
#define BCAP 6144

typedef float f4 __attribute__((ext_vector_type(4)));
typedef float f2 __attribute__((ext_vector_type(2)));
typedef _Float16 h8 __attribute__((ext_vector_type(8)));
typedef _Float16 h4 __attribute__((ext_vector_type(4)));

// packed units (512 halves each): [0,64) Wcomb (K=128), [64,192) I+Wc1 (K=256), [192,320) W_f1 (K=256)
#define OFF_NODE 0
#define OFF_C1   32768
#define OFF_F1   98304
#define PW_HALVES 163840

#define SWZ(row, c2) ((c2) ^ (((row) & 7) << 4))

// ---------------- Wcomb = Wn + Wn@Wc2 (fp32)  +  btail init ----------------
__global__ __launch_bounds__(256)
void k_wcomb(const float* __restrict__ Wn, const float* __restrict__ Wc2,
             float* __restrict__ Wcomb, int* __restrict__ btail) {
    if (blockIdx.x == 8) {
        if (threadIdx.x < NBUCK) btail[threadIdx.x] = threadIdx.x * BCAP;
        return;
    }
    __shared__ float WnL[16][256];
    const int c = threadIdx.x;
    const int r0 = blockIdx.x * 16;
    for (int i = threadIdx.x; i < 16 * 256; i += 256)
        WnL[i >> 8][i & 255] = Wn[(r0 + (i >> 8)) * HH + (i & 255)];
    __syncthreads();
    float acc[16];
#pragma unroll
    for (int r = 0; r < 16; ++r) acc[r] = WnL[r][c];
    for (int k = 0; k < 256; ++k) {
        float wv = Wc2[k * HH + c];
#pragma unroll
        for (int r = 0; r < 16; ++r) acc[r] += WnL[r][k] * wv;
    }
#pragma unroll
    for (int r = 0; r < 16; ++r) Wcomb[(r0 + r) * HH + c] = acc[r];
}

// ---------------- prep: W_edge -> fp8 e4m3 (x256 scale), conversion only ----------------
__global__ __launch_bounds__(256)
void k_prep(const float* __restrict__ W, unsigned char* __restrict__ W8) {
    const int gsz = gridDim.x * blockDim.x;
    const int i0 = blockIdx.x * blockDim.x + threadIdx.x;
    for (int j = i0; j < NN * HH / 8; j += gsz) {
        f4 v0 = ((const f4*)W)[j * 2];
        f4 v1 = ((const f4*)W)[j * 2 + 1];
        int p0 = 0, p1 = 0;
        p0 = __builtin_amdgcn_cvt_pk_fp8_f32(v0[0] * 256.f, v0[1] * 256.f, p0, false);
        p0 = __builtin_amdgcn_cvt_pk_fp8_f32(v0[2] * 256.f, v0[3] * 256.f, p0, true);
        p1 = __builtin_amdgcn_cvt_pk_fp8_f32(v1[0] * 256.f, v1[1] * 256.f, p1, false);
        p1 = __builtin_amdgcn_cvt_pk_fp8_f32(v1[2] * 256.f, v1[3] * 256.f, p1, true);
        uint2 u;
        u.x = (unsigned int)p0;
        u.y = (unsigned int)p1;
        ((uint2*)W8)[j] = u;
    }
}

// ---------------- pack weights into MFMA-B fragment layout (fp16) ----------------
__global__ __launch_bounds__(256)
void k_pack(const float* __restrict__ Wcomb, const float* __restrict__ W_c1,
            const float* __restrict__ W_c2, const float* __restrict__ W_f1,
            const float* __restrict__ b_node, const float* __restrict__ b_c1,
            const float* __restrict__ b_c2, _Float16* __restrict__ pW,
            float* __restrict__ bB) {
    const int tid = threadIdx.x;
    if (blockIdx.x == 80) {  // combined phase-B bias: b_c1+b_c2+b_node@(I+W_c2)
        int c = tid;
        if (c < HH) {
            float a = 0.f;
            for (int k = 0; k < HH; ++k) a += b_node[k] * W_c2[k * HH + c];
            bB[c] = a + b_node[c] + b_c1[c] + b_c2[c];
        }
        return;
    }
    const int unit = blockIdx.x * 4 + (tid >> 6);
    const int lane = tid & 63, lm = lane & 15, lg = lane >> 4;
    const float* Ws;
    bool addI;
    int u = unit;
    if (u < 64)       { Ws = Wcomb; addI = false; }
    else if (u < 192) { Ws = W_c1;  addI = true;  u -= 64; }
    else              { Ws = W_f1;  addI = false; u -= 192; }
    const int kb = u >> 4, nb = u & 15;
    h8 hv;
#pragma unroll
    for (int j = 0; j < 8; ++j) {
        int kr = kb * 32 + lg * 8 + j;
        int col = nb * 16 + lm;
        float v = Ws[kr * HH + col];
        if (addI && kr == col) v += 1.f;
        hv[j] = (_Float16)v;
    }
    *(h8*)(pW + (size_t)unit * 512 + lane * 8) = hv;
}

// ---------------- phase A: LDS-staged coarse binning into padded tmp ----------------
__global__ __launch_bounds__(256)
void k_binA(const int* __restrict__ ei, const float* __restrict__ ew,
            int* __restrict__ btail, uint2* __restrict__ tmp) {
    __shared__ int lcnt[NBUCK], lpre[NBUCK], lbase[NBUCK], lcnt2[NBUCK];
    __shared__ int t[256];
    __shared__ uint2 staged[CHK];
    __shared__ unsigned char bslot[CHK];
    const int tid = threadIdx.x;
    const int e0 = blockIdx.x * CHK;
    const int n = min(CHK, EE - e0);
    for (int i = tid; i < NBUCK; i += 256) { lcnt[i] = 0; lcnt2[i] = 0; }
    __syncthreads();
    for (int i = tid; i < n; i += 256) {
        int d = ei[EE + e0 + i];
        atomicAdd(&lcnt[d >> 8], 1);
    }
    __syncthreads();
    {
        int v = (tid < NBUCK) ? lcnt[tid] : 0;
        t[tid] = v;
        __syncthreads();
#pragma unroll
        for (int off = 1; off < 256; off <<= 1) {
            int u = (tid >= off) ? t[tid - off] : 0;
            __syncthreads();
            t[tid] += u;
            __syncthreads();
        }
        if (tid < NBUCK) lpre[tid] = t[tid] - v;
    }
    __syncthreads();
    if (tid < NBUCK && lcnt[tid] > 0)
        lbase[tid] = atomicAdd(&btail[tid], lcnt[tid]);
    __syncthreads();
    for (int i = tid; i < n; i += 256) {
        int e = e0 + i;
        int d = ei[EE + e];
        int b = d >> 8;
        _Float16 hw = (_Float16)ew[e];
        unsigned short hwb = *(unsigned short*)&hw;
        unsigned int lo = (unsigned int)ei[e] | ((unsigned int)hwb << 16);
        int slot = lpre[b] + atomicAdd(&lcnt2[b], 1);
        uint2 v;
        v.x = lo;
        v.y = (unsigned int)d;
        staged[slot] = v;
        bslot[slot] = (unsigned char)b;
    }
    __syncthreads();
    for (int s = tid; s < n; s += 256) {
        int b = bslot[s];
        int idx = lbase[b] + (s - lpre[b]);
        if (idx < (b + 1) * BCAP) tmp[idx] = staged[s];  // overflow guard (unreachable)
    }
}

// ---------------- phase B: derive rowptr + CSR-sorted esw per bucket ----------------
__global__ __launch_bounds__(256)
void k_binB(const int* __restrict__ btail, const uint2* __restrict__ tmp,
            unsigned int* __restrict__ esw, int* __restrict__ rowptr) {
    __shared__ int lpos[256], lpre[256];
    __shared__ int t[256];
    __shared__ unsigned int sout[BCAP];
    const int tid = threadIdx.x;
    const int b = blockIdx.x;
    const int nb0 = b * 256;
    const int tb = b * BCAP;
    const int cnt = btail[b] - tb;
    // global base = sum of counts of buckets < b
    t[tid] = (tid < b) ? (btail[tid] - tid * BCAP) : 0;
    __syncthreads();
#pragma unroll
    for (int off = 128; off > 0; off >>= 1) {
        if (tid < off) t[tid] += t[tid + off];
        __syncthreads();
    }
    const int gbase = t[0];
    __syncthreads();
    // local per-node counts
    lpos[tid] = 0;
    __syncthreads();
    for (int i = tid; i < cnt; i += 256)
        atomicAdd(&lpos[(int)tmp[tb + i].y - nb0], 1);
    __syncthreads();
    // exclusive scan of counts
    {
        int v = lpos[tid];
        t[tid] = v;
        __syncthreads();
#pragma unroll
        for (int off = 1; off < 256; off <<= 1) {
            int u = (tid >= off) ? t[tid - off] : 0;
            __syncthreads();
            t[tid] += u;
            __syncthreads();
        }
        lpre[tid] = t[tid] - v;
    }
    __syncthreads();
    if (nb0 + tid < NN) rowptr[nb0 + tid] = gbase + lpre[tid];
    if (b == NBUCK - 1 && tid == 0) rowptr[NN] = EE;
    lpos[tid] = lpre[tid];  // cursors
    __syncthreads();
    for (int i = tid; i < cnt; i += 256) {
        uint2 v = tmp[tb + i];
        int dr = (int)v.y - nb0;
        int p = atomicAdd(&lpos[dr], 1);
        sout[p] = v.x;
    }
    __syncthreads();
    for (int s = tid; s < cnt; s += 256) esw[gbase + s] = sout[s];  // coalesced
}

// ---------------- gather-accumulate: fp8 table, one wave per node, unroll 8 + masked tail ----------------
__global__ __launch_bounds__(256)
void k_gather(const int* __restrict__ rowptr, const unsigned int* __restrict__ esw,
              const unsigned char* __restrict__ W8, const float* __restrict__ b_edge,
              _Float16* __restrict__ outHA) {
    const int wave = threadIdx.x >> 6;
    const int lane = threadIdx.x & 63;
    const int node = blockIdx.x * 4 + wave;
    if (node >= NN) return;
    int e = rowptr[node];
    const int end = rowptr[node + 1];
    const int c0 = lane * 4;
    f4 acc0 = {0.f, 0.f, 0.f, 0.f}, acc1 = {0.f, 0.f, 0.f, 0.f};
    for (; e + 7 < end; e += 8) {
        unsigned int v[8];
        unsigned int rw[8];
#pragma unroll
        for (int j = 0; j < 8; ++j) v[j] = esw[e + j];
#pragma unroll
        for (int j = 0; j < 8; ++j)
            rw[j] = *(const unsigned int*)(W8 + (size_t)(v[j] & 0xFFFF) * HH + c0);
#pragma unroll
        for (int j = 0; j < 8; j += 2) {
            unsigned short b0 = (unsigned short)(v[j] >> 16);
            unsigned short b1 = (unsigned short)(v[j + 1] >> 16);
            float w0 = (float)*(_Float16*)&b0;
            float w1 = (float)*(_Float16*)&b1;
            f2 l0 = __builtin_amdgcn_cvt_pk_f32_fp8((int)rw[j], false);
            f2 h0 = __builtin_amdgcn_cvt_pk_f32_fp8((int)rw[j], true);
            f2 l1 = __builtin_amdgcn_cvt_pk_f32_fp8((int)rw[j + 1], false);
            f2 h1 = __builtin_amdgcn_cvt_pk_f32_fp8((int)rw[j + 1], true);
            f4 f0 = {l0[0], l0[1], h0[0], h0[1]};
            f4 f1 = {l1[0], l1[1], h1[0], h1[1]};
            acc0 += w0 * f0;
            acc1 += w1 * f1;
        }
    }
    if (e < end) {
        const int rem = end - e;
        unsigned int v[8];
        unsigned int rw[8];
#pragma unroll
        for (int j = 0; j < 8; ++j) v[j] = esw[(j < rem) ? (e + j) : e];
#pragma unroll
        for (int j = 0; j < 8; ++j)
            rw[j] = *(const unsigned int*)(W8 + (size_t)(v[j] & 0xFFFF) * HH + c0);
#pragma unroll
        for (int j = 0; j < 8; j += 2) {
            unsigned short b0 = (unsigned short)(v[j] >> 16);
            unsigned short b1 = (unsigned short)(v[j + 1] >> 16);
            float w0 = (j < rem) ? (float)*(_Float16*)&b0 : 0.f;
            float w1 = (j + 1 < rem) ? (float)*(_Float16*)&b1 : 0.f;
            f2 l0 = __builtin_amdgcn_cvt_pk_f32_fp8((int)rw[j], false);
            f2 h0 = __builtin_amdgcn_cvt_pk_f32_fp8((int)rw[j], true);
            f2 l1 = __builtin_amdgcn_cvt_pk_f32_fp8((int)rw[j + 1], false);
            f2 h1 = __builtin_amdgcn_cvt_pk_f32_fp8((int)rw[j + 1], true);
            f4 f0 = {l0[0], l0[1], h0[0], h0[1]};
            f4 f1 = {l1[0], l1[1], h1[0], h1[1]};
            acc0 += w0 * f0;
            acc1 += w1 * f1;
        }
    }
    f4 b = *(const f4*)(b_edge + c0);
    f4 acc = (acc0 + acc1) * (1.f / 256.f) + b;
    h4 hv;
    hv[0] = (_Float16)acc[0]; hv[1] = (_Float16)acc[1];
    hv[2] = (_Float16)acc[2]; hv[3] = (_Float16)acc[3];
    *(h4*)(outHA + (size_t)node * HH + c0) = hv;
}

// ---------------- fused B+C: h = relu( relu(h_a@(I+Wc1) + x@Wcomb + bB) @ W_f1 + b_f1 ) + BN stats ----------------
__global__ __launch_bounds__(512)
void k_gemmBC(const float* __restrict__ x, const _Float16* __restrict__ A1,
              const _Float16* __restrict__ pW, const float* __restrict__ bB,
              const float* __restrict__ b_f1, _Float16* __restrict__ H,
              float* __restrict__ stats) {
    __shared__ __align__(16) char sm[40960];
    const int tid = threadIdx.x;
    const int w = tid >> 6, l = tid & 63;
    const int lm = l & 15, lg = l >> 4;
    const int rx = tid >> 4, sx = tid & 15;

    h8 w1[8][2], wc[4][2], wf[8][2];
#pragma unroll
    for (int kb = 0; kb < 8; ++kb)
#pragma unroll
        for (int n = 0; n < 2; ++n) {
            w1[kb][n] = *(const h8*)(pW + OFF_C1 + (size_t)(kb * 16 + w * 2 + n) * 512 + l * 8);
            wf[kb][n] = *(const h8*)(pW + OFF_F1 + (size_t)(kb * 16 + w * 2 + n) * 512 + l * 8);
        }
#pragma unroll
    for (int kb = 0; kb < 4; ++kb)
#pragma unroll
        for (int n = 0; n < 2; ++n)
            wc[kb][n] = *(const h8*)(pW + OFF_NODE + (size_t)(kb * 16 + w * 2 + n) * 512 + l * 8);

    float bBreg[2], bFreg[2];
#pragma unroll
    for (int n = 0; n < 2; ++n) {
        bBreg[n] = bB[w * 32 + n * 16 + lm];
        bFreg[n] = b_f1[w * 32 + n * 16 + lm];
    }
    float sS[2] = {0.f, 0.f}, sQ[2] = {0.f, 0.f};

    const int NT = (NN + 31) / 32;
    f4 pXa, pXb;
    int4 p1[2];
    int t = blockIdx.x;
    if (t < NT) {
        int grow = t * 32 + rx;
        const f4 zf = {0.f, 0.f, 0.f, 0.f};
        pXa = (grow < NN) ? *(const f4*)(x + (size_t)grow * FF + sx * 8) : zf;
        pXb = (grow < NN) ? *(const f4*)(x + (size_t)grow * FF + sx * 8 + 4) : zf;
#pragma unroll
        for (int j = 0; j < 2; ++j) {
            int unit = tid * 2 + j;
            int r = unit >> 5, s = unit & 31;
            int g2 = t * 32 + r;
            int4 z = {0, 0, 0, 0};
            p1[j] = (g2 < NN) ? *(const int4*)(A1 + (size_t)g2 * HH + s * 8) : z;
        }
    }

    for (; t < NT; t += gridDim.x) {
        __syncthreads();  // b0
        {
            h8 hx;
            hx[0] = (_Float16)pXa[0]; hx[1] = (_Float16)pXa[1];
            hx[2] = (_Float16)pXa[2]; hx[3] = (_Float16)pXa[3];
            hx[4] = (_Float16)pXb[0]; hx[5] = (_Float16)pXb[1];
            hx[6] = (_Float16)pXb[2]; hx[7] = (_Float16)pXb[3];
            *(int4*)(sm + rx * 256 + SWZ(rx, sx * 16)) = *(int4*)&hx;
        }
#pragma unroll
        for (int j = 0; j < 2; ++j) {
            int unit = tid * 2 + j;
            int r = unit >> 5, s = unit & 31;
            *(int4*)(sm + 8192 + r * 512 + SWZ(r, s * 16)) = p1[j];
        }
        int tn = t + gridDim.x;
        if (tn < NT) {
            int grow = tn * 32 + rx;
            const f4 zf = {0.f, 0.f, 0.f, 0.f};
            pXa = (grow < NN) ? *(const f4*)(x + (size_t)grow * FF + sx * 8) : zf;
            pXb = (grow < NN) ? *(const f4*)(x + (size_t)grow * FF + sx * 8 + 4) : zf;
#pragma unroll
            for (int j = 0; j < 2; ++j) {
                int unit = tid * 2 + j;
                int r = unit >> 5, s = unit & 31;
                int g2 = tn * 32 + r;
                int4 z = {0, 0, 0, 0};
                p1[j] = (g2 < NN) ? *(const int4*)(A1 + (size_t)g2 * HH + s * 8) : z;
            }
        }
        __syncthreads();  // b1

        // ---- stage B
        f4 acc[2][2];
        const f4 z4 = {0.f, 0.f, 0.f, 0.f};
#pragma unroll
        for (int rf = 0; rf < 2; ++rf)
#pragma unroll
            for (int n = 0; n < 2; ++n) acc[rf][n] = z4;

#pragma unroll
        for (int kb = 0; kb < 8; ++kb) {
            h8 a0 = *(const h8*)(sm + 8192 + lm * 512 + SWZ(lm, kb * 64 + lg * 16));
            h8 a1 = *(const h8*)(sm + 8192 + (16 + lm) * 512 + SWZ(16 + lm, kb * 64 + lg * 16));
#pragma unroll
            for (int n = 0; n < 2; ++n) {
                acc[0][n] = __builtin_amdgcn_mfma_f32_16x16x32_f16(a0, w1[kb][n], acc[0][n], 0, 0, 0);
                acc[1][n] = __builtin_amdgcn_mfma_f32_16x16x32_f16(a1, w1[kb][n], acc[1][n], 0, 0, 0);
            }
        }
#pragma unroll
        for (int kb = 0; kb < 4; ++kb) {
            h8 a0 = *(const h8*)(sm + lm * 256 + SWZ(lm, kb * 64 + lg * 16));
            h8 a1 = *(const h8*)(sm + (16 + lm) * 256 + SWZ(16 + lm, kb * 64 + lg * 16));
#pragma unroll
            for (int n = 0; n < 2; ++n) {
                acc[0][n] = __builtin_amdgcn_mfma_f32_16x16x32_f16(a0, wc[kb][n], acc[0][n], 0, 0, 0);
                acc[1][n] = __builtin_amdgcn_mfma_f32_16x16x32_f16(a1, wc[kb][n], acc[1][n], 0, 0, 0);
            }
        }
#pragma unroll
        for (int rf = 0; rf < 2; ++rf)
#pragma unroll
            for (int n = 0; n < 2; ++n) {
                int c2 = (w * 32 + n * 16 + lm) * 2;
#pragma unroll
                for (int q = 0; q < 4; ++q) {
                    int r = rf * 16 + lg * 4 + q;
                    float v = fmaxf(acc[rf][n][q] + bBreg[n], 0.f);
                    *(_Float16*)(sm + 24576 + r * 512 + SWZ(r, c2)) = (_Float16)v;
                }
            }
        __syncthreads();  // b2

        // ---- stage C
#pragma unroll
        for (int rf = 0; rf < 2; ++rf)
#pragma unroll
            for (int n = 0; n < 2; ++n) acc[rf][n] = z4;

#pragma unroll
        for (int kb = 0; kb < 8; ++kb) {
            h8 a0 = *(const h8*)(sm + 24576 + lm * 512 + SWZ(lm, kb * 64 + lg * 16));
            h8 a1 = *(const h8*)(sm + 24576 + (16 + lm) * 512 + SWZ(16 + lm, kb * 64 + lg * 16));
#pragma unroll
            for (int n = 0; n < 2; ++n) {
                acc[0][n] = __builtin_amdgcn_mfma_f32_16x16x32_f16(a0, wf[kb][n], acc[0][n], 0, 0, 0);
                acc[1][n] = __builtin_amdgcn_mfma_f32_16x16x32_f16(a1, wf[kb][n], acc[1][n], 0, 0, 0);
            }
        }

        const int row0 = t * 32;
#pragma unroll
        for (int rf = 0; rf < 2; ++rf)
#pragma unroll
            for (int n = 0; n < 2; ++n) {
                const int col = w * 32 + n * 16 + lm;
#pragma unroll
                for (int q = 0; q < 4; ++q) {
                    int grow = row0 + rf * 16 + lg * 4 + q;
                    if (grow < NN) {
                        float v = fmaxf(acc[rf][n][q] + bFreg[n], 0.f);
                        sS[n] += v;
                        sQ[n] += v * v;
                        H[(size_t)grow * HH + col] = (_Float16)v;
                    }
                }
            }
    }

#pragma unroll
    for (int n = 0; n < 2; ++n) {
        float s = sS[n];
        s += __shfl_xor(s, 16); s += __shfl_xor(s, 32);
        float q = sQ[n];
        q += __shfl_xor(q, 16); q += __shfl_xor(q, 32);
        if (lg == 0) {
            atomicAdd(&stats[w * 32 + n * 16 + lm], s);
            atomicAdd(&stats[HH + w * 32 + n * 16 + lm], q);
        }
    }
}

// ---------------- BN fold + pack final weights into MFMA-B fragments ----------------
__global__ __launch_bounds__(256)
void k_bnprep(const float* __restrict__ stats, const float* __restrict__ gamma,
              const float* __restrict__ beta, const float* __restrict__ W_f2,
              const float* __restrict__ b_f2, _Float16* __restrict__ pWf,
              float* __restrict__ bfold) {
    __shared__ float sh[HH];
    __shared__ float ssc[HH];
    const int tid = threadIdx.x;
    const float invN = 1.0f / (float)NN;
    {
        float mu = stats[tid] * invN;
        float var = stats[HH + tid] * invN - mu * mu;
        float scale = gamma[tid] * rsqrtf(var + BN_EPS);
        sh[tid] = beta[tid] - mu * scale;
        ssc[tid] = scale;
    }
    __syncthreads();
    if (tid < CC) {
        float b = b_f2[tid];
        for (int k = 0; k < HH; ++k) b += sh[k] * W_f2[k * CC + tid];
        bfold[tid] = b;
    }
    const int w = tid >> 6, l = tid & 63;
    const int lm = l & 15, lg = l >> 4;
#pragma unroll
    for (int i = 0; i < 6; ++i) {
        int u = w + i * 4;  // 0..23
        int kb = u / 3, nb = u % 3;
        h8 hv;
#pragma unroll
        for (int j = 0; j < 8; ++j) {
            int k = kb * 32 + lg * 8 + j;
            int c = nb * 16 + lm;
            float v = (c < CC) ? ssc[k] * W_f2[k * CC + c] : 0.f;
            hv[j] = (_Float16)v;
        }
        *(h8*)(pWf + (size_t)u * 512 + l * 8) = hv;
    }
}

// ---------------- final via MFMA: out = h @ (scale*W_f2) + bfold ----------------
__global__ __launch_bounds__(256)
void k_finalM(const _Float16* __restrict__ h, const _Float16* __restrict__ pWf,
              const float* __restrict__ bfold, float* __restrict__ out) {
    __shared__ __align__(16) char sA[64 * 512];
    const int tid = threadIdx.x;
    const int w = tid >> 6, l = tid & 63;
    const int lm = l & 15, lg = l >> 4;

    h8 wreg[8][3];
#pragma unroll
    for (int kb = 0; kb < 8; ++kb)
#pragma unroll
        for (int nb = 0; nb < 3; ++nb)
            wreg[kb][nb] = *(const h8*)(pWf + (size_t)(kb * 3 + nb) * 512 + l * 8);

    const int row0 = blockIdx.x * 64;
#pragma unroll
    for (int j = 0; j < 8; ++j) {
        int unit = tid * 8 + j;
        int r = unit >> 5, s = unit & 31;
        int grow = row0 + r;
        int4 z = {0, 0, 0, 0};
        int4 v = (grow < NN) ? *(const int4*)(h + (size_t)grow * HH + s * 8) : z;
        *(int4*)(sA + r * 512 + SWZ(r, s * 16)) = v;
    }
    __syncthreads();

    f4 acc[3];
    const f4 z4 = {0.f, 0.f, 0.f, 0.f};
#pragma unroll
    for (int nb = 0; nb < 3; ++nb) acc[nb] = z4;

    const int ar = w * 16 + lm;
#pragma unroll
    for (int kb = 0; kb < 8; ++kb) {
        h8 a = *(const h8*)(sA + ar * 512 + SWZ(ar, kb * 64 + lg * 16));
#pragma unroll
        for (int nb = 0; nb < 3; ++nb)
            acc[nb] = __builtin_amdgcn_mfma_f32_16x16x32_f16(a, wreg[kb][nb], acc[nb], 0, 0, 0);
    }

#pragma unroll
    for (int nb = 0; nb < 3; ++nb) {
        int col = nb * 16 + lm;
        if (col < CC) {
            float bb = bfold[col];
#pragma unroll
            for (int q = 0; q < 4; ++q) {
                int grow = row0 + w * 16 + lg * 4 + q;
                if (grow < NN) out[(size_t)grow * CC + col] = acc[nb][q] + bb;
            }
        }
    }
}

extern "C" void kernel_launch(void* const* d_in, const int* in_sizes, int n_in,
                              void* d_out, int out_size, void* d_ws, size_t ws_size,
                              hipStream_t stream) {
    const float* x      = (const float*)d_in[0];
    const int*   ei     = (const int*)d_in[1];
    const float* ew     = (const float*)d_in[2];
    const float* W_edge = (const float*)d_in[3];
    const float* b_edge = (const float*)d_in[4];
    const float* W_node = (const float*)d_in[5];
    const float* b_node = (const float*)d_in[6];
    const float* W_c1   = (const float*)d_in[7];
    const float* b_c1   = (const float*)d_in[8];
    const float* W_c2   = (const float*)d_in[9];
    const float* b_c2   = (const float*)d_in[10];
    const float* W_f1   = (const float*)d_in[11];
    const float* b_f1   = (const float*)d_in[12];
    const float* gamma  = (const float*)d_in[13];
    const float* beta   = (const float*)d_in[14];
    const float* W_f2   = (const float*)d_in[15];
    const float* b_f2   = (const float*)d_in[16];
    float* out = (float*)d_out;

    const size_t NNH = (size_t)NN * HH;
    _Float16* bufA = (_Float16*)d_ws;            // h_a
    _Float16* bufH = bufA + NNH;                 // h
    unsigned char* W8 = (unsigned char*)(bufH + NNH);  // fp8 W_edge (x256), NNH bytes
    unsigned int* esw = (unsigned int*)(W8 + NNH);     // E packed 4B
    float* stats   = (float*)(esw + EE);         // 512
    float* bB      = stats + 2 * HH;             // 256
    float* bfold   = bB + HH;                    // 64
    _Float16* pWf  = (_Float16*)(bfold + 64);    // 24*512
    _Float16* pW   = pWf + 24 * 512;             // PW_HALVES
    float* Wcomb   = (float*)(pW + PW_HALVES);   // 128*256 fp32
    uint2* tmp     = (uint2*)(Wcomb + FF * HH);  // NBUCK*BCAP uint2 (padded)
    int* rowptr    = (int*)(tmp + (size_t)NBUCK * BCAP);  // N+1
    int* btail     = rowptr + NN + 1;            // NBUCK

    hipMemsetAsync(stats, 0, 2 * HH * sizeof(float), stream);

    k_wcomb<<<9, 256, 0, stream>>>(W_node, W_c2, Wcomb, btail);
    k_prep<<<2048, 256, 0, stream>>>(W_edge, W8);
    k_pack<<<81, 256, 0, stream>>>(Wcomb, W_c1, W_c2, W_f1, b_node, b_c1, b_c2, pW, bB);
    k_binA<<<(EE + CHK - 1) / CHK, 256, 0, stream>>>(ei, ew, btail, tmp);
    k_binB<<<NBUCK, 256, 0, stream>>>(btail, tmp, esw, rowptr);
    k_gather<<<12500, 256, 0, stream>>>(rowptr, esw, W8, b_edge, bufA);

    // fused B+C: h = relu( relu(h_a@(I+Wc1) + x@Wcomb + bB) @ W_f1 + b_f1 ) + stats
    k_gemmBC<<<512, 512, 0, stream>>>(x, bufA, pW, bB, b_f1, bufH, stats);

    k_bnprep<<<1, 256, 0, stream>>>(stats, gamma, beta, W_f2, b_f2, pWf, bfold);
    k_finalM<<<(NN + 63) / 64, 256, 0, stream>>>(bufH, pWf, bfold, out);
}

// Round 17
// 183.597 us; speedup vs baseline: 1.5240x; 1.0172x over previous
//
#include <hip/hip_runtime.h>

#define NN 50000
#define EE 800000
#define FF 128
#define HH 256
#define CC 40
#define BN_EPS 1e-5f
#define NBUCK 196
#define CHK 3200
#define BCAP 6144

typedef float f4 __attribute__((ext_vector_type(4)));
typedef float f2 __attribute__((ext_vector_type(2)));
typedef _Float16 h8 __attribute__((ext_vector_type(8)));
typedef _Float16 h4 __attribute__((ext_vector_type(4)));

// packed units (512 halves each): [0,64) Wcomb (K=128), [64,192) I+Wc1 (K=256), [192,320) W_f1 (K=256)
#define OFF_NODE 0
#define OFF_C1   32768
#define OFF_F1   98304
#define PW_HALVES 163840

#define SWZ(row, c2) ((c2) ^ (((row) & 7) << 4))

// ---------------- Wcomb = Wn + Wn@Wc2 (fp32)  +  btail init ----------------
__global__ __launch_bounds__(256)
void k_wcomb(const float* __restrict__ Wn, const float* __restrict__ Wc2,
             float* __restrict__ Wcomb, int* __restrict__ btail) {
    if (blockIdx.x == 8) {
        if (threadIdx.x < NBUCK) btail[threadIdx.x] = threadIdx.x * BCAP;
        return;
    }
    __shared__ float WnL[16][256];
    const int c = threadIdx.x;
    const int r0 = blockIdx.x * 16;
    for (int i = threadIdx.x; i < 16 * 256; i += 256)
        WnL[i >> 8][i & 255] = Wn[(r0 + (i >> 8)) * HH + (i & 255)];
    __syncthreads();
    float acc[16];
#pragma unroll
    for (int r = 0; r < 16; ++r) acc[r] = WnL[r][c];
    for (int k = 0; k < 256; ++k) {
        float wv = Wc2[k * HH + c];
#pragma unroll
        for (int r = 0; r < 16; ++r) acc[r] += WnL[r][k] * wv;
    }
#pragma unroll
    for (int r = 0; r < 16; ++r) Wcomb[(r0 + r) * HH + c] = acc[r];
}

// ---------------- prep: W_edge -> fp8 e4m3 (x256)  +  x -> fp16 ----------------
__global__ __launch_bounds__(256)
void k_prep(const float* __restrict__ W, unsigned char* __restrict__ W8,
            const float* __restrict__ x, _Float16* __restrict__ x16) {
    const int gsz = gridDim.x * blockDim.x;
    const int i0 = blockIdx.x * blockDim.x + threadIdx.x;
    for (int j = i0; j < NN * HH / 8; j += gsz) {
        f4 v0 = ((const f4*)W)[j * 2];
        f4 v1 = ((const f4*)W)[j * 2 + 1];
        int p0 = 0, p1 = 0;
        p0 = __builtin_amdgcn_cvt_pk_fp8_f32(v0[0] * 256.f, v0[1] * 256.f, p0, false);
        p0 = __builtin_amdgcn_cvt_pk_fp8_f32(v0[2] * 256.f, v0[3] * 256.f, p0, true);
        p1 = __builtin_amdgcn_cvt_pk_fp8_f32(v1[0] * 256.f, v1[1] * 256.f, p1, false);
        p1 = __builtin_amdgcn_cvt_pk_fp8_f32(v1[2] * 256.f, v1[3] * 256.f, p1, true);
        uint2 u;
        u.x = (unsigned int)p0;
        u.y = (unsigned int)p1;
        ((uint2*)W8)[j] = u;
    }
    for (int j = i0; j < NN * FF / 8; j += gsz) {
        f4 v0 = ((const f4*)x)[j * 2];
        f4 v1 = ((const f4*)x)[j * 2 + 1];
        h8 h;
        h[0] = (_Float16)v0[0]; h[1] = (_Float16)v0[1];
        h[2] = (_Float16)v0[2]; h[3] = (_Float16)v0[3];
        h[4] = (_Float16)v1[0]; h[5] = (_Float16)v1[1];
        h[6] = (_Float16)v1[2]; h[7] = (_Float16)v1[3];
        ((h8*)x16)[j] = h;
    }
}

// ---------------- pack weights into MFMA-B fragment layout (fp16) ----------------
__global__ __launch_bounds__(256)
void k_pack(const float* __restrict__ Wcomb, const float* __restrict__ W_c1,
            const float* __restrict__ W_c2, const float* __restrict__ W_f1,
            const float* __restrict__ b_node, const float* __restrict__ b_c1,
            const float* __restrict__ b_c2, _Float16* __restrict__ pW,
            float* __restrict__ bB) {
    const int tid = threadIdx.x;
    if (blockIdx.x == 80) {  // combined phase-B bias: b_c1+b_c2+b_node@(I+W_c2)
        int c = tid;
        if (c < HH) {
            float a = 0.f;
            for (int k = 0; k < HH; ++k) a += b_node[k] * W_c2[k * HH + c];
            bB[c] = a + b_node[c] + b_c1[c] + b_c2[c];
        }
        return;
    }
    const int unit = blockIdx.x * 4 + (tid >> 6);
    const int lane = tid & 63, lm = lane & 15, lg = lane >> 4;
    const float* Ws;
    bool addI;
    int u = unit;
    if (u < 64)       { Ws = Wcomb; addI = false; }
    else if (u < 192) { Ws = W_c1;  addI = true;  u -= 64; }
    else              { Ws = W_f1;  addI = false; u -= 192; }
    const int kb = u >> 4, nb = u & 15;
    h8 hv;
#pragma unroll
    for (int j = 0; j < 8; ++j) {
        int kr = kb * 32 + lg * 8 + j;
        int col = nb * 16 + lm;
        float v = Ws[kr * HH + col];
        if (addI && kr == col) v += 1.f;
        hv[j] = (_Float16)v;
    }
    *(h8*)(pW + (size_t)unit * 512 + lane * 8) = hv;
}

// ---------------- phase A: LDS-staged coarse binning into padded tmp ----------------
__global__ __launch_bounds__(256)
void k_binA(const int* __restrict__ ei, const float* __restrict__ ew,
            int* __restrict__ btail, uint2* __restrict__ tmp) {
    __shared__ int lcnt[NBUCK], lpre[NBUCK], lbase[NBUCK], lcnt2[NBUCK];
    __shared__ int t[256];
    __shared__ uint2 staged[CHK];
    __shared__ unsigned char bslot[CHK];
    const int tid = threadIdx.x;
    const int e0 = blockIdx.x * CHK;
    const int n = min(CHK, EE - e0);
    for (int i = tid; i < NBUCK; i += 256) { lcnt[i] = 0; lcnt2[i] = 0; }
    __syncthreads();
    for (int i = tid; i < n; i += 256) {
        int d = ei[EE + e0 + i];
        atomicAdd(&lcnt[d >> 8], 1);
    }
    __syncthreads();
    {
        int v = (tid < NBUCK) ? lcnt[tid] : 0;
        t[tid] = v;
        __syncthreads();
#pragma unroll
        for (int off = 1; off < 256; off <<= 1) {
            int u = (tid >= off) ? t[tid - off] : 0;
            __syncthreads();
            t[tid] += u;
            __syncthreads();
        }
        if (tid < NBUCK) lpre[tid] = t[tid] - v;
    }
    __syncthreads();
    if (tid < NBUCK && lcnt[tid] > 0)
        lbase[tid] = atomicAdd(&btail[tid], lcnt[tid]);
    __syncthreads();
    for (int i = tid; i < n; i += 256) {
        int e = e0 + i;
        int d = ei[EE + e];
        int b = d >> 8;
        _Float16 hw = (_Float16)ew[e];
        unsigned short hwb = *(unsigned short*)&hw;
        unsigned int lo = (unsigned int)ei[e] | ((unsigned int)hwb << 16);
        int slot = lpre[b] + atomicAdd(&lcnt2[b], 1);
        uint2 v;
        v.x = lo;
        v.y = (unsigned int)d;
        staged[slot] = v;
        bslot[slot] = (unsigned char)b;
    }
    __syncthreads();
    for (int s = tid; s < n; s += 256) {
        int b = bslot[s];
        int idx = lbase[b] + (s - lpre[b]);
        if (idx < (b + 1) * BCAP) tmp[idx] = staged[s];
    }
}

// ---------------- phase B: derive rowptr + CSR-sorted esw per bucket ----------------
__global__ __launch_bounds__(256)
void k_binB(const int* __restrict__ btail, const uint2* __restrict__ tmp,
            unsigned int* __restrict__ esw, int* __restrict__ rowptr) {
    __shared__ int lpos[256], lpre[256];
    __shared__ int t[256];
    __shared__ unsigned int sout[BCAP];
    const int tid = threadIdx.x;
    const int b = blockIdx.x;
    const int nb0 = b * 256;
    const int tb = b * BCAP;
    const int cnt = btail[b] - tb;
    t[tid] = (tid < b) ? (btail[tid] - tid * BCAP) : 0;
    __syncthreads();
#pragma unroll
    for (int off = 128; off > 0; off >>= 1) {
        if (tid < off) t[tid] += t[tid + off];
        __syncthreads();
    }
    const int gbase = t[0];
    __syncthreads();
    lpos[tid] = 0;
    __syncthreads();
    for (int i = tid; i < cnt; i += 256)
        atomicAdd(&lpos[(int)tmp[tb + i].y - nb0], 1);
    __syncthreads();
    {
        int v = lpos[tid];
        t[tid] = v;
        __syncthreads();
#pragma unroll
        for (int off = 1; off < 256; off <<= 1) {
            int u = (tid >= off) ? t[tid - off] : 0;
            __syncthreads();
            t[tid] += u;
            __syncthreads();
        }
        lpre[tid] = t[tid] - v;
    }
    __syncthreads();
    if (nb0 + tid < NN) rowptr[nb0 + tid] = gbase + lpre[tid];
    if (b == NBUCK - 1 && tid == 0) rowptr[NN] = EE;
    lpos[tid] = lpre[tid];
    __syncthreads();
    for (int i = tid; i < cnt; i += 256) {
        uint2 v = tmp[tb + i];
        int dr = (int)v.y - nb0;
        int p = atomicAdd(&lpos[dr], 1);
        sout[p] = v.x;
    }
    __syncthreads();
    for (int s = tid; s < cnt; s += 256) esw[gbase + s] = sout[s];
}

// ---------------- gather-accumulate: fp8 table, one wave per node, unroll 8 + masked tail ----------------
__global__ __launch_bounds__(256)
void k_gather(const int* __restrict__ rowptr, const unsigned int* __restrict__ esw,
              const unsigned char* __restrict__ W8, const float* __restrict__ b_edge,
              _Float16* __restrict__ outHA) {
    const int wave = threadIdx.x >> 6;
    const int lane = threadIdx.x & 63;
    const int node = blockIdx.x * 4 + wave;
    if (node >= NN) return;
    int e = rowptr[node];
    const int end = rowptr[node + 1];
    const int c0 = lane * 4;
    f4 acc0 = {0.f, 0.f, 0.f, 0.f}, acc1 = {0.f, 0.f, 0.f, 0.f};
    for (; e + 7 < end; e += 8) {
        unsigned int v[8];
        unsigned int rw[8];
#pragma unroll
        for (int j = 0; j < 8; ++j) v[j] = esw[e + j];
#pragma unroll
        for (int j = 0; j < 8; ++j)
            rw[j] = *(const unsigned int*)(W8 + (size_t)(v[j] & 0xFFFF) * HH + c0);
#pragma unroll
        for (int j = 0; j < 8; j += 2) {
            unsigned short b0 = (unsigned short)(v[j] >> 16);
            unsigned short b1 = (unsigned short)(v[j + 1] >> 16);
            float w0 = (float)*(_Float16*)&b0;
            float w1 = (float)*(_Float16*)&b1;
            f2 l0 = __builtin_amdgcn_cvt_pk_f32_fp8((int)rw[j], false);
            f2 h0 = __builtin_amdgcn_cvt_pk_f32_fp8((int)rw[j], true);
            f2 l1 = __builtin_amdgcn_cvt_pk_f32_fp8((int)rw[j + 1], false);
            f2 h1 = __builtin_amdgcn_cvt_pk_f32_fp8((int)rw[j + 1], true);
            f4 f0 = {l0[0], l0[1], h0[0], h0[1]};
            f4 f1 = {l1[0], l1[1], h1[0], h1[1]};
            acc0 += w0 * f0;
            acc1 += w1 * f1;
        }
    }
    if (e < end) {
        const int rem = end - e;
        unsigned int v[8];
        unsigned int rw[8];
#pragma unroll
        for (int j = 0; j < 8; ++j) v[j] = esw[(j < rem) ? (e + j) : e];
#pragma unroll
        for (int j = 0; j < 8; ++j)
            rw[j] = *(const unsigned int*)(W8 + (size_t)(v[j] & 0xFFFF) * HH + c0);
#pragma unroll
        for (int j = 0; j < 8; j += 2) {
            unsigned short b0 = (unsigned short)(v[j] >> 16);
            unsigned short b1 = (unsigned short)(v[j + 1] >> 16);
            float w0 = (j < rem) ? (float)*(_Float16*)&b0 : 0.f;
            float w1 = (j + 1 < rem) ? (float)*(_Float16*)&b1 : 0.f;
            f2 l0 = __builtin_amdgcn_cvt_pk_f32_fp8((int)rw[j], false);
            f2 h0 = __builtin_amdgcn_cvt_pk_f32_fp8((int)rw[j], true);
            f2 l1 = __builtin_amdgcn_cvt_pk_f32_fp8((int)rw[j + 1], false);
            f2 h1 = __builtin_amdgcn_cvt_pk_f32_fp8((int)rw[j + 1], true);
            f4 f0 = {l0[0], l0[1], h0[0], h0[1]};
            f4 f1 = {l1[0], l1[1], h1[0], h1[1]};
            acc0 += w0 * f0;
            acc1 += w1 * f1;
        }
    }
    f4 b = *(const f4*)(b_edge + c0);
    f4 acc = (acc0 + acc1) * (1.f / 256.f) + b;
    h4 hv;
    hv[0] = (_Float16)acc[0]; hv[1] = (_Float16)acc[1];
    hv[2] = (_Float16)acc[2]; hv[3] = (_Float16)acc[3];
    *(h4*)(outHA + (size_t)node * HH + c0) = hv;
}

// ---------------- fused B+C (2 barriers/tile, fp16 x): ----------------
// h = relu( relu(h_a@(I+Wc1) + x@Wcomb + bB) @ W_f1 + b_f1 ) + BN stats
__global__ __launch_bounds__(512)
void k_gemmBC(const _Float16* __restrict__ x16, const _Float16* __restrict__ A1,
              const _Float16* __restrict__ pW, const float* __restrict__ bB,
              const float* __restrict__ b_f1, _Float16* __restrict__ H,
              float* __restrict__ stats) {
    __shared__ __align__(16) char sm[40960];
    const int tid = threadIdx.x;
    const int w = tid >> 6, l = tid & 63;
    const int lm = l & 15, lg = l >> 4;

    h8 w1[8][2], wc[4][2], wf[8][2];
#pragma unroll
    for (int kb = 0; kb < 8; ++kb)
#pragma unroll
        for (int n = 0; n < 2; ++n) {
            w1[kb][n] = *(const h8*)(pW + OFF_C1 + (size_t)(kb * 16 + w * 2 + n) * 512 + l * 8);
            wf[kb][n] = *(const h8*)(pW + OFF_F1 + (size_t)(kb * 16 + w * 2 + n) * 512 + l * 8);
        }
#pragma unroll
    for (int kb = 0; kb < 4; ++kb)
#pragma unroll
        for (int n = 0; n < 2; ++n)
            wc[kb][n] = *(const h8*)(pW + OFF_NODE + (size_t)(kb * 16 + w * 2 + n) * 512 + l * 8);

    float bBreg[2], bFreg[2];
#pragma unroll
    for (int n = 0; n < 2; ++n) {
        bBreg[n] = bB[w * 32 + n * 16 + lm];
        bFreg[n] = b_f1[w * 32 + n * 16 + lm];
    }
    float sS[2] = {0.f, 0.f}, sQ[2] = {0.f, 0.f};

    const int NT = (NN + 31) / 32;
    int4 pX;      // x16 tile: 32 rows x 256B -> 512 units of 16B, 1/thread
    int4 p1[2];   // A1 tile: 32 rows x 512B -> 1024 units, 2/thread
    int t = blockIdx.x;
    {
        const int rX = tid >> 4, sX_ = tid & 15;
        int grow = t * 32 + rX;
        int4 z = {0, 0, 0, 0};
        pX = (grow < NN) ? *(const int4*)(x16 + (size_t)grow * FF + sX_ * 8) : z;
#pragma unroll
        for (int j = 0; j < 2; ++j) {
            int unit = tid * 2 + j;
            int r = unit >> 5, s = unit & 31;
            int g2 = t * 32 + r;
            p1[j] = (g2 < NN) ? *(const int4*)(A1 + (size_t)g2 * HH + s * 8) : z;
        }
    }

    for (; t < NT; t += gridDim.x) {
        // staging (sX/sA1 are dead after previous b2: stage-B reads finished pre-b2,
        // stage-C touches only sOutB) -- no barrier needed here.
        {
            const int rX = tid >> 4, sX_ = tid & 15;
            *(int4*)(sm + rX * 256 + SWZ(rX, sX_ * 16)) = pX;
        }
#pragma unroll
        for (int j = 0; j < 2; ++j) {
            int unit = tid * 2 + j;
            int r = unit >> 5, s = unit & 31;
            *(int4*)(sm + 8192 + r * 512 + SWZ(r, s * 16)) = p1[j];
        }
        int tn = t + gridDim.x;
        if (tn < NT) {
            const int rX = tid >> 4, sX_ = tid & 15;
            int grow = tn * 32 + rX;
            int4 z = {0, 0, 0, 0};
            pX = (grow < NN) ? *(const int4*)(x16 + (size_t)grow * FF + sX_ * 8) : z;
#pragma unroll
            for (int j = 0; j < 2; ++j) {
                int unit = tid * 2 + j;
                int r = unit >> 5, s = unit & 31;
                int g2 = tn * 32 + r;
                p1[j] = (g2 < NN) ? *(const int4*)(A1 + (size_t)g2 * HH + s * 8) : z;
            }
        }
        __syncthreads();  // b1: sX, sA1 ready

        // ---- stage B
        f4 acc[2][2];
        const f4 z4 = {0.f, 0.f, 0.f, 0.f};
#pragma unroll
        for (int rf = 0; rf < 2; ++rf)
#pragma unroll
            for (int n = 0; n < 2; ++n) acc[rf][n] = z4;

#pragma unroll
        for (int kb = 0; kb < 8; ++kb) {
            h8 a0 = *(const h8*)(sm + 8192 + lm * 512 + SWZ(lm, kb * 64 + lg * 16));
            h8 a1 = *(const h8*)(sm + 8192 + (16 + lm) * 512 + SWZ(16 + lm, kb * 64 + lg * 16));
#pragma unroll
            for (int n = 0; n < 2; ++n) {
                acc[0][n] = __builtin_amdgcn_mfma_f32_16x16x32_f16(a0, w1[kb][n], acc[0][n], 0, 0, 0);
                acc[1][n] = __builtin_amdgcn_mfma_f32_16x16x32_f16(a1, w1[kb][n], acc[1][n], 0, 0, 0);
            }
        }
#pragma unroll
        for (int kb = 0; kb < 4; ++kb) {
            h8 a0 = *(const h8*)(sm + lm * 256 + SWZ(lm, kb * 64 + lg * 16));
            h8 a1 = *(const h8*)(sm + (16 + lm) * 256 + SWZ(16 + lm, kb * 64 + lg * 16));
#pragma unroll
            for (int n = 0; n < 2; ++n) {
                acc[0][n] = __builtin_amdgcn_mfma_f32_16x16x32_f16(a0, wc[kb][n], acc[0][n], 0, 0, 0);
                acc[1][n] = __builtin_amdgcn_mfma_f32_16x16x32_f16(a1, wc[kb][n], acc[1][n], 0, 0, 0);
            }
        }
#pragma unroll
        for (int rf = 0; rf < 2; ++rf)
#pragma unroll
            for (int n = 0; n < 2; ++n) {
                int c2 = (w * 32 + n * 16 + lm) * 2;
#pragma unroll
                for (int q = 0; q < 4; ++q) {
                    int r = rf * 16 + lg * 4 + q;
                    float v = fmaxf(acc[rf][n][q] + bBreg[n], 0.f);
                    *(_Float16*)(sm + 24576 + r * 512 + SWZ(r, c2)) = (_Float16)v;
                }
            }
        __syncthreads();  // b2: sOutB ready

        // ---- stage C
#pragma unroll
        for (int rf = 0; rf < 2; ++rf)
#pragma unroll
            for (int n = 0; n < 2; ++n) acc[rf][n] = z4;

#pragma unroll
        for (int kb = 0; kb < 8; ++kb) {
            h8 a0 = *(const h8*)(sm + 24576 + lm * 512 + SWZ(lm, kb * 64 + lg * 16));
            h8 a1 = *(const h8*)(sm + 24576 + (16 + lm) * 512 + SWZ(16 + lm, kb * 64 + lg * 16));
#pragma unroll
            for (int n = 0; n < 2; ++n) {
                acc[0][n] = __builtin_amdgcn_mfma_f32_16x16x32_f16(a0, wf[kb][n], acc[0][n], 0, 0, 0);
                acc[1][n] = __builtin_amdgcn_mfma_f32_16x16x32_f16(a1, wf[kb][n], acc[1][n], 0, 0, 0);
            }
        }

        const int row0 = t * 32;
#pragma unroll
        for (int rf = 0; rf < 2; ++rf)
#pragma unroll
            for (int n = 0; n < 2; ++n) {
                const int col = w * 32 + n * 16 + lm;
#pragma unroll
                for (int q = 0; q < 4; ++q) {
                    int grow = row0 + rf * 16 + lg * 4 + q;
                    if (grow < NN) {
                        float v = fmaxf(acc[rf][n][q] + bFreg[n], 0.f);
                        sS[n] += v;
                        sQ[n] += v * v;
                        H[(size_t)grow * HH + col] = (_Float16)v;
                    }
                }
            }
        __syncthreads();  // b3: all waves done reading sOutB before next staging overwrites sX/sA1
    }

#pragma unroll
    for (int n = 0; n < 2; ++n) {
        float s = sS[n];
        s += __shfl_xor(s, 16); s += __shfl_xor(s, 32);
        float q = sQ[n];
        q += __shfl_xor(q, 16); q += __shfl_xor(q, 32);
        if (lg == 0) {
            atomicAdd(&stats[w * 32 + n * 16 + lm], s);
            atomicAdd(&stats[HH + w * 32 + n * 16 + lm], q);
        }
    }
}

// ---------------- BN fold + pack final weights into MFMA-B fragments ----------------
__global__ __launch_bounds__(256)
void k_bnprep(const float* __restrict__ stats, const float* __restrict__ gamma,
              const float* __restrict__ beta, const float* __restrict__ W_f2,
              const float* __restrict__ b_f2, _Float16* __restrict__ pWf,
              float* __restrict__ bfold) {
    __shared__ float sh[HH];
    __shared__ float ssc[HH];
    const int tid = threadIdx.x;
    const float invN = 1.0f / (float)NN;
    {
        float mu = stats[tid] * invN;
        float var = stats[HH + tid] * invN - mu * mu;
        float scale = gamma[tid] * rsqrtf(var + BN_EPS);
        sh[tid] = beta[tid] - mu * scale;
        ssc[tid] = scale;
    }
    __syncthreads();
    if (tid < CC) {
        float b = b_f2[tid];
        for (int k = 0; k < HH; ++k) b += sh[k] * W_f2[k * CC + tid];
        bfold[tid] = b;
    }
    const int w = tid >> 6, l = tid & 63;
    const int lm = l & 15, lg = l >> 4;
#pragma unroll
    for (int i = 0; i < 6; ++i) {
        int u = w + i * 4;  // 0..23
        int kb = u / 3, nb = u % 3;
        h8 hv;
#pragma unroll
        for (int j = 0; j < 8; ++j) {
            int k = kb * 32 + lg * 8 + j;
            int c = nb * 16 + lm;
            float v = (c < CC) ? ssc[k] * W_f2[k * CC + c] : 0.f;
            hv[j] = (_Float16)v;
        }
        *(h8*)(pWf + (size_t)u * 512 + l * 8) = hv;
    }
}

// ---------------- final via MFMA: out = h @ (scale*W_f2) + bfold ----------------
__global__ __launch_bounds__(256)
void k_finalM(const _Float16* __restrict__ h, const _Float16* __restrict__ pWf,
              const float* __restrict__ bfold, float* __restrict__ out) {
    __shared__ __align__(16) char sA[64 * 512];
    const int tid = threadIdx.x;
    const int w = tid >> 6, l = tid & 63;
    const int lm = l & 15, lg = l >> 4;

    h8 wreg[8][3];
#pragma unroll
    for (int kb = 0; kb < 8; ++kb)
#pragma unroll
        for (int nb = 0; nb < 3; ++nb)
            wreg[kb][nb] = *(const h8*)(pWf + (size_t)(kb * 3 + nb) * 512 + l * 8);

    const int row0 = blockIdx.x * 64;
#pragma unroll
    for (int j = 0; j < 8; ++j) {
        int unit = tid * 8 + j;
        int r = unit >> 5, s = unit & 31;
        int grow = row0 + r;
        int4 z = {0, 0, 0, 0};
        int4 v = (grow < NN) ? *(const int4*)(h + (size_t)grow * HH + s * 8) : z;
        *(int4*)(sA + r * 512 + SWZ(r, s * 16)) = v;
    }
    __syncthreads();

    f4 acc[3];
    const f4 z4 = {0.f, 0.f, 0.f, 0.f};
#pragma unroll
    for (int nb = 0; nb < 3; ++nb) acc[nb] = z4;

    const int ar = w * 16 + lm;
#pragma unroll
    for (int kb = 0; kb < 8; ++kb) {
        h8 a = *(const h8*)(sA + ar * 512 + SWZ(ar, kb * 64 + lg * 16));
#pragma unroll
        for (int nb = 0; nb < 3; ++nb)
            acc[nb] = __builtin_amdgcn_mfma_f32_16x16x32_f16(a, wreg[kb][nb], acc[nb], 0, 0, 0);
    }

#pragma unroll
    for (int nb = 0; nb < 3; ++nb) {
        int col = nb * 16 + lm;
        if (col < CC) {
            float bb = bfold[col];
#pragma unroll
            for (int q = 0; q < 4; ++q) {
                int grow = row0 + w * 16 + lg * 4 + q;
                if (grow < NN) out[(size_t)grow * CC + col] = acc[nb][q] + bb;
            }
        }
    }
}

extern "C" void kernel_launch(void* const* d_in, const int* in_sizes, int n_in,
                              void* d_out, int out_size, void* d_ws, size_t ws_size,
                              hipStream_t stream) {
    const float* x      = (const float*)d_in[0];
    const int*   ei     = (const int*)d_in[1];
    const float* ew     = (const float*)d_in[2];
    const float* W_edge = (const float*)d_in[3];
    const float* b_edge = (const float*)d_in[4];
    const float* W_node = (const float*)d_in[5];
    const float* b_node = (const float*)d_in[6];
    const float* W_c1   = (const float*)d_in[7];
    const float* b_c1   = (const float*)d_in[8];
    const float* W_c2   = (const float*)d_in[9];
    const float* b_c2   = (const float*)d_in[10];
    const float* W_f1   = (const float*)d_in[11];
    const float* b_f1   = (const float*)d_in[12];
    const float* gamma  = (const float*)d_in[13];
    const float* beta   = (const float*)d_in[14];
    const float* W_f2   = (const float*)d_in[15];
    const float* b_f2   = (const float*)d_in[16];
    float* out = (float*)d_out;

    const size_t NNH = (size_t)NN * HH;
    _Float16* bufA = (_Float16*)d_ws;            // h_a
    _Float16* bufH = bufA + NNH;                 // h
    _Float16* x16  = bufH + NNH;                 // fp16 x (NN*FF)
    unsigned char* W8 = (unsigned char*)(x16 + (size_t)NN * FF);  // fp8 W_edge, NNH bytes
    unsigned int* esw = (unsigned int*)(W8 + NNH);     // E packed 4B
    float* stats   = (float*)(esw + EE);         // 512
    float* bB      = stats + 2 * HH;             // 256
    float* bfold   = bB + HH;                    // 64
    _Float16* pWf  = (_Float16*)(bfold + 64);    // 24*512
    _Float16* pW   = pWf + 24 * 512;             // PW_HALVES
    float* Wcomb   = (float*)(pW + PW_HALVES);   // 128*256 fp32
    uint2* tmp     = (uint2*)(Wcomb + FF * HH);  // NBUCK*BCAP uint2 (padded)
    int* rowptr    = (int*)(tmp + (size_t)NBUCK * BCAP);  // N+1
    int* btail     = rowptr + NN + 1;            // NBUCK

    hipMemsetAsync(stats, 0, 2 * HH * sizeof(float), stream);

    k_wcomb<<<9, 256, 0, stream>>>(W_node, W_c2, Wcomb, btail);
    k_prep<<<2048, 256, 0, stream>>>(W_edge, W8, x, x16);
    k_pack<<<81, 256, 0, stream>>>(Wcomb, W_c1, W_c2, W_f1, b_node, b_c1, b_c2, pW, bB);
    k_binA<<<(EE + CHK - 1) / CHK, 256, 0, stream>>>(ei, ew, btail, tmp);
    k_binB<<<NBUCK, 256, 0, stream>>>(btail, tmp, esw, rowptr);
    k_gather<<<12500, 256, 0, stream>>>(rowptr, esw, W8, b_edge, bufA);

    // fused B+C: h = relu( relu(h_a@(I+Wc1) + x@Wcomb + bB) @ W_f1 + b_f1 ) + stats
    k_gemmBC<<<256, 512, 0, stream>>>(x16, bufA, pW, bB, b_f1, bufH, stats);

    k_bnprep<<<1, 256, 0, stream>>>(stats, gamma, beta, W_f2, b_f2, pWf, bfold);
    k_finalM<<<(NN + 63) / 64, 256, 0, stream>>>(bufH, pWf, bfold, out);
}

// Round 18
// 179.333 us; speedup vs baseline: 1.5602x; 1.0238x over previous
//
#include <hip/hip_runtime.h>

#define NN 50000
#define EE 800000
#define FF 128
#define HH 256
#define CC 40
#define BN_EPS 1e-5f
#define NBUCK 196
#define CHK 3200
#define BCAP 6144

typedef float f4 __attribute__((ext_vector_type(4)));
typedef float f2 __attribute__((ext_vector_type(2)));
typedef _Float16 h8 __attribute__((ext_vector_type(8)));
typedef _Float16 h4 __attribute__((ext_vector_type(4)));

// packed units (512 halves each): [0,64) Wcomb (K=128), [64,192) I+Wc1 (K=256), [192,320) W_f1 (K=256)
#define OFF_NODE 0
#define OFF_C1   32768
#define OFF_F1   98304
#define PW_HALVES 163840

#define SWZ(row, c2) ((c2) ^ (((row) & 7) << 4))

// ---------------- Wcomb = Wn + Wn@Wc2 (fp32)  +  btail/stats init ----------------
__global__ __launch_bounds__(256)
void k_wcomb(const float* __restrict__ Wn, const float* __restrict__ Wc2,
             float* __restrict__ Wcomb, int* __restrict__ btail,
             float* __restrict__ stats) {
    if (blockIdx.x == 8) {
        if (threadIdx.x < NBUCK) btail[threadIdx.x] = threadIdx.x * BCAP;
        stats[threadIdx.x] = 0.f;
        stats[256 + threadIdx.x] = 0.f;
        return;
    }
    __shared__ float WnL[16][256];
    const int c = threadIdx.x;
    const int r0 = blockIdx.x * 16;
    for (int i = threadIdx.x; i < 16 * 256; i += 256)
        WnL[i >> 8][i & 255] = Wn[(r0 + (i >> 8)) * HH + (i & 255)];
    __syncthreads();
    float acc[16];
#pragma unroll
    for (int r = 0; r < 16; ++r) acc[r] = WnL[r][c];
    for (int k = 0; k < 256; ++k) {
        float wv = Wc2[k * HH + c];
#pragma unroll
        for (int r = 0; r < 16; ++r) acc[r] += WnL[r][k] * wv;
    }
#pragma unroll
    for (int r = 0; r < 16; ++r) Wcomb[(r0 + r) * HH + c] = acc[r];
}

// ---------------- prep: W_edge -> fp8 e4m3 (x256)  +  x -> fp16 ----------------
__global__ __launch_bounds__(256)
void k_prep(const float* __restrict__ W, unsigned char* __restrict__ W8,
            const float* __restrict__ x, _Float16* __restrict__ x16) {
    const int gsz = gridDim.x * blockDim.x;
    const int i0 = blockIdx.x * blockDim.x + threadIdx.x;
    for (int j = i0; j < NN * HH / 8; j += gsz) {
        f4 v0 = ((const f4*)W)[j * 2];
        f4 v1 = ((const f4*)W)[j * 2 + 1];
        int p0 = 0, p1 = 0;
        p0 = __builtin_amdgcn_cvt_pk_fp8_f32(v0[0] * 256.f, v0[1] * 256.f, p0, false);
        p0 = __builtin_amdgcn_cvt_pk_fp8_f32(v0[2] * 256.f, v0[3] * 256.f, p0, true);
        p1 = __builtin_amdgcn_cvt_pk_fp8_f32(v1[0] * 256.f, v1[1] * 256.f, p1, false);
        p1 = __builtin_amdgcn_cvt_pk_fp8_f32(v1[2] * 256.f, v1[3] * 256.f, p1, true);
        uint2 u;
        u.x = (unsigned int)p0;
        u.y = (unsigned int)p1;
        ((uint2*)W8)[j] = u;
    }
    for (int j = i0; j < NN * FF / 8; j += gsz) {
        f4 v0 = ((const f4*)x)[j * 2];
        f4 v1 = ((const f4*)x)[j * 2 + 1];
        h8 h;
        h[0] = (_Float16)v0[0]; h[1] = (_Float16)v0[1];
        h[2] = (_Float16)v0[2]; h[3] = (_Float16)v0[3];
        h[4] = (_Float16)v1[0]; h[5] = (_Float16)v1[1];
        h[6] = (_Float16)v1[2]; h[7] = (_Float16)v1[3];
        ((h8*)x16)[j] = h;
    }
}

// ---------------- pack weights into MFMA-B fragment layout (fp16) ----------------
__global__ __launch_bounds__(256)
void k_pack(const float* __restrict__ Wcomb, const float* __restrict__ W_c1,
            const float* __restrict__ W_c2, const float* __restrict__ W_f1,
            const float* __restrict__ b_node, const float* __restrict__ b_c1,
            const float* __restrict__ b_c2, _Float16* __restrict__ pW,
            float* __restrict__ bB) {
    const int tid = threadIdx.x;
    if (blockIdx.x == 80) {  // combined phase-B bias: b_c1+b_c2+b_node@(I+W_c2)
        int c = tid;
        if (c < HH) {
            float a = 0.f;
            for (int k = 0; k < HH; ++k) a += b_node[k] * W_c2[k * HH + c];
            bB[c] = a + b_node[c] + b_c1[c] + b_c2[c];
        }
        return;
    }
    const int unit = blockIdx.x * 4 + (tid >> 6);
    const int lane = tid & 63, lm = lane & 15, lg = lane >> 4;
    const float* Ws;
    bool addI;
    int u = unit;
    if (u < 64)       { Ws = Wcomb; addI = false; }
    else if (u < 192) { Ws = W_c1;  addI = true;  u -= 64; }
    else              { Ws = W_f1;  addI = false; u -= 192; }
    const int kb = u >> 4, nb = u & 15;
    h8 hv;
#pragma unroll
    for (int j = 0; j < 8; ++j) {
        int kr = kb * 32 + lg * 8 + j;
        int col = nb * 16 + lm;
        float v = Ws[kr * HH + col];
        if (addI && kr == col) v += 1.f;
        hv[j] = (_Float16)v;
    }
    *(h8*)(pW + (size_t)unit * 512 + lane * 8) = hv;
}

// ---------------- phase A: LDS-staged coarse binning into padded tmp ----------------
__global__ __launch_bounds__(256)
void k_binA(const int* __restrict__ ei, const float* __restrict__ ew,
            int* __restrict__ btail, uint2* __restrict__ tmp) {
    __shared__ int lcnt[NBUCK], lpre[NBUCK], lbase[NBUCK], lcnt2[NBUCK];
    __shared__ int t[256];
    __shared__ uint2 staged[CHK];
    __shared__ unsigned char bslot[CHK];
    const int tid = threadIdx.x;
    const int e0 = blockIdx.x * CHK;
    const int n = min(CHK, EE - e0);
    for (int i = tid; i < NBUCK; i += 256) { lcnt[i] = 0; lcnt2[i] = 0; }
    __syncthreads();
    for (int i = tid; i < n; i += 256) {
        int d = ei[EE + e0 + i];
        atomicAdd(&lcnt[d >> 8], 1);
    }
    __syncthreads();
    {
        int v = (tid < NBUCK) ? lcnt[tid] : 0;
        t[tid] = v;
        __syncthreads();
#pragma unroll
        for (int off = 1; off < 256; off <<= 1) {
            int u = (tid >= off) ? t[tid - off] : 0;
            __syncthreads();
            t[tid] += u;
            __syncthreads();
        }
        if (tid < NBUCK) lpre[tid] = t[tid] - v;
    }
    __syncthreads();
    if (tid < NBUCK && lcnt[tid] > 0)
        lbase[tid] = atomicAdd(&btail[tid], lcnt[tid]);
    __syncthreads();
    for (int i = tid; i < n; i += 256) {
        int e = e0 + i;
        int d = ei[EE + e];
        int b = d >> 8;
        _Float16 hw = (_Float16)ew[e];
        unsigned short hwb = *(unsigned short*)&hw;
        unsigned int lo = (unsigned int)ei[e] | ((unsigned int)hwb << 16);
        int slot = lpre[b] + atomicAdd(&lcnt2[b], 1);
        uint2 v;
        v.x = lo;
        v.y = (unsigned int)d;
        staged[slot] = v;
        bslot[slot] = (unsigned char)b;
    }
    __syncthreads();
    for (int s = tid; s < n; s += 256) {
        int b = bslot[s];
        int idx = lbase[b] + (s - lpre[b]);
        if (idx < (b + 1) * BCAP) tmp[idx] = staged[s];
    }
}

// ---------------- phase B: derive rowptr + CSR-sorted esw per bucket ----------------
__global__ __launch_bounds__(256)
void k_binB(const int* __restrict__ btail, const uint2* __restrict__ tmp,
            unsigned int* __restrict__ esw, int* __restrict__ rowptr) {
    __shared__ int lpos[256], lpre[256];
    __shared__ int t[256];
    __shared__ unsigned int sout[BCAP];
    const int tid = threadIdx.x;
    const int b = blockIdx.x;
    const int nb0 = b * 256;
    const int tb = b * BCAP;
    const int cnt = btail[b] - tb;
    t[tid] = (tid < b) ? (btail[tid] - tid * BCAP) : 0;
    __syncthreads();
#pragma unroll
    for (int off = 128; off > 0; off >>= 1) {
        if (tid < off) t[tid] += t[tid + off];
        __syncthreads();
    }
    const int gbase = t[0];
    __syncthreads();
    lpos[tid] = 0;
    __syncthreads();
    for (int i = tid; i < cnt; i += 256)
        atomicAdd(&lpos[(int)tmp[tb + i].y - nb0], 1);
    __syncthreads();
    {
        int v = lpos[tid];
        t[tid] = v;
        __syncthreads();
#pragma unroll
        for (int off = 1; off < 256; off <<= 1) {
            int u = (tid >= off) ? t[tid - off] : 0;
            __syncthreads();
            t[tid] += u;
            __syncthreads();
        }
        lpre[tid] = t[tid] - v;
    }
    __syncthreads();
    if (nb0 + tid < NN) rowptr[nb0 + tid] = gbase + lpre[tid];
    if (b == NBUCK - 1 && tid == 0) rowptr[NN] = EE;
    lpos[tid] = lpre[tid];
    __syncthreads();
    for (int i = tid; i < cnt; i += 256) {
        uint2 v = tmp[tb + i];
        int dr = (int)v.y - nb0;
        int p = atomicAdd(&lpos[dr], 1);
        sout[p] = v.x;
    }
    __syncthreads();
    for (int s = tid; s < cnt; s += 256) esw[gbase + s] = sout[s];
}

// ---------------- gather-accumulate: fp8 table, one wave per node, unroll 8 + masked tail ----------------
__global__ __launch_bounds__(256)
void k_gather(const int* __restrict__ rowptr, const unsigned int* __restrict__ esw,
              const unsigned char* __restrict__ W8, const float* __restrict__ b_edge,
              _Float16* __restrict__ outHA) {
    const int wave = threadIdx.x >> 6;
    const int lane = threadIdx.x & 63;
    const int node = blockIdx.x * 4 + wave;
    if (node >= NN) return;
    int e = rowptr[node];
    const int end = rowptr[node + 1];
    const int c0 = lane * 4;
    f4 acc0 = {0.f, 0.f, 0.f, 0.f}, acc1 = {0.f, 0.f, 0.f, 0.f};
    for (; e + 7 < end; e += 8) {
        unsigned int v[8];
        unsigned int rw[8];
#pragma unroll
        for (int j = 0; j < 8; ++j) v[j] = esw[e + j];
#pragma unroll
        for (int j = 0; j < 8; ++j)
            rw[j] = *(const unsigned int*)(W8 + (size_t)(v[j] & 0xFFFF) * HH + c0);
#pragma unroll
        for (int j = 0; j < 8; j += 2) {
            unsigned short b0 = (unsigned short)(v[j] >> 16);
            unsigned short b1 = (unsigned short)(v[j + 1] >> 16);
            float w0 = (float)*(_Float16*)&b0;
            float w1 = (float)*(_Float16*)&b1;
            f2 l0 = __builtin_amdgcn_cvt_pk_f32_fp8((int)rw[j], false);
            f2 h0 = __builtin_amdgcn_cvt_pk_f32_fp8((int)rw[j], true);
            f2 l1 = __builtin_amdgcn_cvt_pk_f32_fp8((int)rw[j + 1], false);
            f2 h1 = __builtin_amdgcn_cvt_pk_f32_fp8((int)rw[j + 1], true);
            f4 f0 = {l0[0], l0[1], h0[0], h0[1]};
            f4 f1 = {l1[0], l1[1], h1[0], h1[1]};
            acc0 += w0 * f0;
            acc1 += w1 * f1;
        }
    }
    if (e < end) {
        const int rem = end - e;
        unsigned int v[8];
        unsigned int rw[8];
#pragma unroll
        for (int j = 0; j < 8; ++j) v[j] = esw[(j < rem) ? (e + j) : e];
#pragma unroll
        for (int j = 0; j < 8; ++j)
            rw[j] = *(const unsigned int*)(W8 + (size_t)(v[j] & 0xFFFF) * HH + c0);
#pragma unroll
        for (int j = 0; j < 8; j += 2) {
            unsigned short b0 = (unsigned short)(v[j] >> 16);
            unsigned short b1 = (unsigned short)(v[j + 1] >> 16);
            float w0 = (j < rem) ? (float)*(_Float16*)&b0 : 0.f;
            float w1 = (j + 1 < rem) ? (float)*(_Float16*)&b1 : 0.f;
            f2 l0 = __builtin_amdgcn_cvt_pk_f32_fp8((int)rw[j], false);
            f2 h0 = __builtin_amdgcn_cvt_pk_f32_fp8((int)rw[j], true);
            f2 l1 = __builtin_amdgcn_cvt_pk_f32_fp8((int)rw[j + 1], false);
            f2 h1 = __builtin_amdgcn_cvt_pk_f32_fp8((int)rw[j + 1], true);
            f4 f0 = {l0[0], l0[1], h0[0], h0[1]};
            f4 f1 = {l1[0], l1[1], h1[0], h1[1]};
            acc0 += w0 * f0;
            acc1 += w1 * f1;
        }
    }
    f4 b = *(const f4*)(b_edge + c0);
    f4 acc = (acc0 + acc1) * (1.f / 256.f) + b;
    h4 hv;
    hv[0] = (_Float16)acc[0]; hv[1] = (_Float16)acc[1];
    hv[2] = (_Float16)acc[2]; hv[3] = (_Float16)acc[3];
    *(h4*)(outHA + (size_t)node * HH + c0) = hv;
}

// ---------------- fused B+C (2 barriers/tile, fp16 x) ----------------
__global__ __launch_bounds__(512)
void k_gemmBC(const _Float16* __restrict__ x16, const _Float16* __restrict__ A1,
              const _Float16* __restrict__ pW, const float* __restrict__ bB,
              const float* __restrict__ b_f1, _Float16* __restrict__ H,
              float* __restrict__ stats) {
    __shared__ __align__(16) char sm[40960];
    const int tid = threadIdx.x;
    const int w = tid >> 6, l = tid & 63;
    const int lm = l & 15, lg = l >> 4;

    h8 w1[8][2], wc[4][2], wf[8][2];
#pragma unroll
    for (int kb = 0; kb < 8; ++kb)
#pragma unroll
        for (int n = 0; n < 2; ++n) {
            w1[kb][n] = *(const h8*)(pW + OFF_C1 + (size_t)(kb * 16 + w * 2 + n) * 512 + l * 8);
            wf[kb][n] = *(const h8*)(pW + OFF_F1 + (size_t)(kb * 16 + w * 2 + n) * 512 + l * 8);
        }
#pragma unroll
    for (int kb = 0; kb < 4; ++kb)
#pragma unroll
        for (int n = 0; n < 2; ++n)
            wc[kb][n] = *(const h8*)(pW + OFF_NODE + (size_t)(kb * 16 + w * 2 + n) * 512 + l * 8);

    float bBreg[2], bFreg[2];
#pragma unroll
    for (int n = 0; n < 2; ++n) {
        bBreg[n] = bB[w * 32 + n * 16 + lm];
        bFreg[n] = b_f1[w * 32 + n * 16 + lm];
    }
    float sS[2] = {0.f, 0.f}, sQ[2] = {0.f, 0.f};

    const int NT = (NN + 31) / 32;
    int4 pX;
    int4 p1[2];
    int t = blockIdx.x;
    {
        const int rX = tid >> 4, sX_ = tid & 15;
        int grow = t * 32 + rX;
        int4 z = {0, 0, 0, 0};
        pX = (grow < NN) ? *(const int4*)(x16 + (size_t)grow * FF + sX_ * 8) : z;
#pragma unroll
        for (int j = 0; j < 2; ++j) {
            int unit = tid * 2 + j;
            int r = unit >> 5, s = unit & 31;
            int g2 = t * 32 + r;
            p1[j] = (g2 < NN) ? *(const int4*)(A1 + (size_t)g2 * HH + s * 8) : z;
        }
    }

    for (; t < NT; t += gridDim.x) {
        {
            const int rX = tid >> 4, sX_ = tid & 15;
            *(int4*)(sm + rX * 256 + SWZ(rX, sX_ * 16)) = pX;
        }
#pragma unroll
        for (int j = 0; j < 2; ++j) {
            int unit = tid * 2 + j;
            int r = unit >> 5, s = unit & 31;
            *(int4*)(sm + 8192 + r * 512 + SWZ(r, s * 16)) = p1[j];
        }
        int tn = t + gridDim.x;
        if (tn < NT) {
            const int rX = tid >> 4, sX_ = tid & 15;
            int grow = tn * 32 + rX;
            int4 z = {0, 0, 0, 0};
            pX = (grow < NN) ? *(const int4*)(x16 + (size_t)grow * FF + sX_ * 8) : z;
#pragma unroll
            for (int j = 0; j < 2; ++j) {
                int unit = tid * 2 + j;
                int r = unit >> 5, s = unit & 31;
                int g2 = tn * 32 + r;
                p1[j] = (g2 < NN) ? *(const int4*)(A1 + (size_t)g2 * HH + s * 8) : z;
            }
        }
        __syncthreads();  // b1: sX, sA1 ready

        // ---- stage B
        f4 acc[2][2];
        const f4 z4 = {0.f, 0.f, 0.f, 0.f};
#pragma unroll
        for (int rf = 0; rf < 2; ++rf)
#pragma unroll
            for (int n = 0; n < 2; ++n) acc[rf][n] = z4;

#pragma unroll
        for (int kb = 0; kb < 8; ++kb) {
            h8 a0 = *(const h8*)(sm + 8192 + lm * 512 + SWZ(lm, kb * 64 + lg * 16));
            h8 a1 = *(const h8*)(sm + 8192 + (16 + lm) * 512 + SWZ(16 + lm, kb * 64 + lg * 16));
#pragma unroll
            for (int n = 0; n < 2; ++n) {
                acc[0][n] = __builtin_amdgcn_mfma_f32_16x16x32_f16(a0, w1[kb][n], acc[0][n], 0, 0, 0);
                acc[1][n] = __builtin_amdgcn_mfma_f32_16x16x32_f16(a1, w1[kb][n], acc[1][n], 0, 0, 0);
            }
        }
#pragma unroll
        for (int kb = 0; kb < 4; ++kb) {
            h8 a0 = *(const h8*)(sm + lm * 256 + SWZ(lm, kb * 64 + lg * 16));
            h8 a1 = *(const h8*)(sm + (16 + lm) * 256 + SWZ(16 + lm, kb * 64 + lg * 16));
#pragma unroll
            for (int n = 0; n < 2; ++n) {
                acc[0][n] = __builtin_amdgcn_mfma_f32_16x16x32_f16(a0, wc[kb][n], acc[0][n], 0, 0, 0);
                acc[1][n] = __builtin_amdgcn_mfma_f32_16x16x32_f16(a1, wc[kb][n], acc[1][n], 0, 0, 0);
            }
        }
#pragma unroll
        for (int rf = 0; rf < 2; ++rf)
#pragma unroll
            for (int n = 0; n < 2; ++n) {
                int c2 = (w * 32 + n * 16 + lm) * 2;
#pragma unroll
                for (int q = 0; q < 4; ++q) {
                    int r = rf * 16 + lg * 4 + q;
                    float v = fmaxf(acc[rf][n][q] + bBreg[n], 0.f);
                    *(_Float16*)(sm + 24576 + r * 512 + SWZ(r, c2)) = (_Float16)v;
                }
            }
        __syncthreads();  // b2: sOutB ready

        // ---- stage C
#pragma unroll
        for (int rf = 0; rf < 2; ++rf)
#pragma unroll
            for (int n = 0; n < 2; ++n) acc[rf][n] = z4;

#pragma unroll
        for (int kb = 0; kb < 8; ++kb) {
            h8 a0 = *(const h8*)(sm + 24576 + lm * 512 + SWZ(lm, kb * 64 + lg * 16));
            h8 a1 = *(const h8*)(sm + 24576 + (16 + lm) * 512 + SWZ(16 + lm, kb * 64 + lg * 16));
#pragma unroll
            for (int n = 0; n < 2; ++n) {
                acc[0][n] = __builtin_amdgcn_mfma_f32_16x16x32_f16(a0, wf[kb][n], acc[0][n], 0, 0, 0);
                acc[1][n] = __builtin_amdgcn_mfma_f32_16x16x32_f16(a1, wf[kb][n], acc[1][n], 0, 0, 0);
            }
        }

        const int row0 = t * 32;
#pragma unroll
        for (int rf = 0; rf < 2; ++rf)
#pragma unroll
            for (int n = 0; n < 2; ++n) {
                const int col = w * 32 + n * 16 + lm;
#pragma unroll
                for (int q = 0; q < 4; ++q) {
                    int grow = row0 + rf * 16 + lg * 4 + q;
                    if (grow < NN) {
                        float v = fmaxf(acc[rf][n][q] + bFreg[n], 0.f);
                        sS[n] += v;
                        sQ[n] += v * v;
                        H[(size_t)grow * HH + col] = (_Float16)v;
                    }
                }
            }
        __syncthreads();  // b3: sOutB reads done before next staging
    }

#pragma unroll
    for (int n = 0; n < 2; ++n) {
        float s = sS[n];
        s += __shfl_xor(s, 16); s += __shfl_xor(s, 32);
        float q = sQ[n];
        q += __shfl_xor(q, 16); q += __shfl_xor(q, 32);
        if (lg == 0) {
            atomicAdd(&stats[w * 32 + n * 16 + lm], s);
            atomicAdd(&stats[HH + w * 32 + n * 16 + lm], q);
        }
    }
}

// ---------------- BN fold + pack final weights into MFMA-B fragments ----------------
__global__ __launch_bounds__(256)
void k_bnprep(const float* __restrict__ stats, const float* __restrict__ gamma,
              const float* __restrict__ beta, const float* __restrict__ W_f2,
              const float* __restrict__ b_f2, _Float16* __restrict__ pWf,
              float* __restrict__ bfold) {
    __shared__ float sh[HH];
    __shared__ float ssc[HH];
    const int tid = threadIdx.x;
    const float invN = 1.0f / (float)NN;
    {
        float mu = stats[tid] * invN;
        float var = stats[HH + tid] * invN - mu * mu;
        float scale = gamma[tid] * rsqrtf(var + BN_EPS);
        sh[tid] = beta[tid] - mu * scale;
        ssc[tid] = scale;
    }
    __syncthreads();
    if (tid < CC) {
        float b = b_f2[tid];
        for (int k = 0; k < HH; ++k) b += sh[k] * W_f2[k * CC + tid];
        bfold[tid] = b;
    }
    const int w = tid >> 6, l = tid & 63;
    const int lm = l & 15, lg = l >> 4;
#pragma unroll
    for (int i = 0; i < 6; ++i) {
        int u = w + i * 4;  // 0..23
        int kb = u / 3, nb = u % 3;
        h8 hv;
#pragma unroll
        for (int j = 0; j < 8; ++j) {
            int k = kb * 32 + lg * 8 + j;
            int c = nb * 16 + lm;
            float v = (c < CC) ? ssc[k] * W_f2[k * CC + c] : 0.f;
            hv[j] = (_Float16)v;
        }
        *(h8*)(pWf + (size_t)u * 512 + l * 8) = hv;
    }
}

// ---------------- final via MFMA: out = h @ (scale*W_f2) + bfold ----------------
__global__ __launch_bounds__(256)
void k_finalM(const _Float16* __restrict__ h, const _Float16* __restrict__ pWf,
              const float* __restrict__ bfold, float* __restrict__ out) {
    __shared__ __align__(16) char sA[64 * 512];
    const int tid = threadIdx.x;
    const int w = tid >> 6, l = tid & 63;
    const int lm = l & 15, lg = l >> 4;

    h8 wreg[8][3];
#pragma unroll
    for (int kb = 0; kb < 8; ++kb)
#pragma unroll
        for (int nb = 0; nb < 3; ++nb)
            wreg[kb][nb] = *(const h8*)(pWf + (size_t)(kb * 3 + nb) * 512 + l * 8);

    const int row0 = blockIdx.x * 64;
#pragma unroll
    for (int j = 0; j < 8; ++j) {
        int unit = tid * 8 + j;
        int r = unit >> 5, s = unit & 31;
        int grow = row0 + r;
        int4 z = {0, 0, 0, 0};
        int4 v = (grow < NN) ? *(const int4*)(h + (size_t)grow * HH + s * 8) : z;
        *(int4*)(sA + r * 512 + SWZ(r, s * 16)) = v;
    }
    __syncthreads();

    f4 acc[3];
    const f4 z4 = {0.f, 0.f, 0.f, 0.f};
#pragma unroll
    for (int nb = 0; nb < 3; ++nb) acc[nb] = z4;

    const int ar = w * 16 + lm;
#pragma unroll
    for (int kb = 0; kb < 8; ++kb) {
        h8 a = *(const h8*)(sA + ar * 512 + SWZ(ar, kb * 64 + lg * 16));
#pragma unroll
        for (int nb = 0; nb < 3; ++nb)
            acc[nb] = __builtin_amdgcn_mfma_f32_16x16x32_f16(a, wreg[kb][nb], acc[nb], 0, 0, 0);
    }

#pragma unroll
    for (int nb = 0; nb < 3; ++nb) {
        int col = nb * 16 + lm;
        if (col < CC) {
            float bb = bfold[col];
#pragma unroll
            for (int q = 0; q < 4; ++q) {
                int grow = row0 + w * 16 + lg * 4 + q;
                if (grow < NN) out[(size_t)grow * CC + col] = acc[nb][q] + bb;
            }
        }
    }
}

extern "C" void kernel_launch(void* const* d_in, const int* in_sizes, int n_in,
                              void* d_out, int out_size, void* d_ws, size_t ws_size,
                              hipStream_t stream) {
    const float* x      = (const float*)d_in[0];
    const int*   ei     = (const int*)d_in[1];
    const float* ew     = (const float*)d_in[2];
    const float* W_edge = (const float*)d_in[3];
    const float* b_edge = (const float*)d_in[4];
    const float* W_node = (const float*)d_in[5];
    const float* b_node = (const float*)d_in[6];
    const float* W_c1   = (const float*)d_in[7];
    const float* b_c1   = (const float*)d_in[8];
    const float* W_c2   = (const float*)d_in[9];
    const float* b_c2   = (const float*)d_in[10];
    const float* W_f1   = (const float*)d_in[11];
    const float* b_f1   = (const float*)d_in[12];
    const float* gamma  = (const float*)d_in[13];
    const float* beta   = (const float*)d_in[14];
    const float* W_f2   = (const float*)d_in[15];
    const float* b_f2   = (const float*)d_in[16];
    float* out = (float*)d_out;

    const size_t NNH = (size_t)NN * HH;
    _Float16* bufA = (_Float16*)d_ws;            // h_a
    _Float16* bufH = bufA + NNH;                 // h
    _Float16* x16  = bufH + NNH;                 // fp16 x (NN*FF)
    unsigned char* W8 = (unsigned char*)(x16 + (size_t)NN * FF);  // fp8 W_edge, NNH bytes
    unsigned int* esw = (unsigned int*)(W8 + NNH);     // E packed 4B
    float* stats   = (float*)(esw + EE);         // 512
    float* bB      = stats + 2 * HH;             // 256
    float* bfold   = bB + HH;                    // 64
    _Float16* pWf  = (_Float16*)(bfold + 64);    // 24*512
    _Float16* pW   = pWf + 24 * 512;             // PW_HALVES
    float* Wcomb   = (float*)(pW + PW_HALVES);   // 128*256 fp32
    uint2* tmp     = (uint2*)(Wcomb + FF * HH);  // NBUCK*BCAP uint2 (padded)
    int* rowptr    = (int*)(tmp + (size_t)NBUCK * BCAP);  // N+1
    int* btail     = rowptr + NN + 1;            // NBUCK

    k_wcomb<<<9, 256, 0, stream>>>(W_node, W_c2, Wcomb, btail, stats);
    k_prep<<<2048, 256, 0, stream>>>(W_edge, W8, x, x16);
    k_pack<<<81, 256, 0, stream>>>(Wcomb, W_c1, W_c2, W_f1, b_node, b_c1, b_c2, pW, bB);
    k_binA<<<(EE + CHK - 1) / CHK, 256, 0, stream>>>(ei, ew, btail, tmp);
    k_binB<<<NBUCK, 256, 0, stream>>>(btail, tmp, esw, rowptr);
    k_gather<<<12500, 256, 0, stream>>>(rowptr, esw, W8, b_edge, bufA);

    // fused B+C: h = relu( relu(h_a@(I+Wc1) + x@Wcomb + bB) @ W_f1 + b_f1 ) + stats
    k_gemmBC<<<256, 512, 0, stream>>>(x16, bufA, pW, bB, b_f1, bufH, stats);

    k_bnprep<<<1, 256, 0, stream>>>(stats, gamma, beta, W_f2, b_f2, pWf, bfold);
    k_finalM<<<(NN + 63) / 64, 256, 0, stream>>>(bufH, pWf, bfold, out);
}